// Round 7
// baseline (400.221 us; speedup 1.0000x reference)
//
#include <hip/hip_runtime.h>
#include <math.h>

#define NN 8192
#define KK 32
#define DD 256
#define PP 64
#define HH 8
#define DHH 32
#define NBATCH 32
#define NCHAIN 64

typedef __attribute__((ext_vector_type(8))) short bf16x8;
typedef __attribute__((ext_vector_type(4))) float f32x4;

// ---------------- helpers ----------------
__device__ __forceinline__ float gelu_f(float x) {
    float x3 = x * x * x;
    float z = 0.7978845608028654f * (x + 0.044715f * x3);
    z = fminf(fmaxf(z, -15.f), 15.f);
    float e = __expf(2.f * z);
    float t = (e - 1.f) / (e + 1.f);
    return 0.5f * x * (1.f + t);
}

__device__ __forceinline__ float wave_sum64(float v) {
    #pragma unroll
    for (int m = 32; m > 0; m >>= 1) v += __shfl_xor(v, m);
    return v;
}

__device__ __forceinline__ ushort f2bf(float x) {
    union { float f; unsigned int u; } v; v.f = x;
    unsigned int r = v.u + 0x7fffu + ((v.u >> 16) & 1u);
    return (ushort)(r >> 16);
}

__device__ __forceinline__ float bf2f(ushort u) {
    union { unsigned int u; float f; } v; v.u = ((unsigned int)u) << 16;
    return v.f;
}

__device__ __forceinline__ uint pk2(float a, float b) {
    return (uint)f2bf(a) | ((uint)f2bf(b) << 16);
}

// ---------------- frames ----------------
__global__ __launch_bounds__(256) void frames_kernel(const float* __restrict__ pos,
                                                     float* __restrict__ R) {
    int n = blockIdx.x * 256 + threadIdx.x;
    if (n >= NN) return;
    const float* p = pos + n * 15;
    float nx = p[0], ny = p[1], nz = p[2];
    float cax = p[3], cay = p[4], caz = p[5];
    float cx = p[6], cy = p[7], cz = p[8];
    float e1x = cx - cax, e1y = cy - cay, e1z = cz - caz;
    float inv = rsqrtf(e1x * e1x + e1y * e1y + e1z * e1z + 1e-8f);
    e1x *= inv; e1y *= inv; e1z *= inv;
    float ux = nx - cax, uy = ny - cay, uz = nz - caz;
    float dt = ux * e1x + uy * e1y + uz * e1z;
    float e2x = ux - dt * e1x, e2y = uy - dt * e1y, e2z = uz - dt * e1z;
    inv = rsqrtf(e2x * e2x + e2y * e2y + e2z * e2z + 1e-8f);
    e2x *= inv; e2y *= inv; e2z *= inv;
    float e3x = e1y * e2z - e1z * e2y;
    float e3y = e1z * e2x - e1x * e2z;
    float e3z = e1x * e2y - e1y * e2x;
    float* r = R + n * 9;
    r[0] = e1x; r[1] = e2x; r[2] = e3x;
    r[3] = e1y; r[4] = e2y; r[5] = e3y;
    r[6] = e1z; r[7] = e2z; r[8] = e3z;
}

// ---------------- raw pair features (lane = one (n,k) pair) ----------------
__global__ __launch_bounds__(256) void pair_raw_kernel(
    const float* __restrict__ pos, const int* __restrict__ nbr,
    const int* __restrict__ resi, const int* __restrict__ chain,
    const float* __restrict__ R,
    ushort* __restrict__ feat, int* __restrict__ relidx, float* __restrict__ tfeat_raw) {
    int p = blockIdx.x * 256 + threadIdx.x;
    int n = p >> 5, k = p & 31;
    int j = nbr[p];
    int same = (chain[j] == chain[n]);
    int off = min(max(resi[j] - resi[n], -32), 32) + 32;
    relidx[p] = same ? off : -1;

    float can0 = pos[n * 15 + 3], can1 = pos[n * 15 + 4], can2 = pos[n * 15 + 5];
    float cbn0 = pos[n * 15 + 12], cbn1 = pos[n * 15 + 13], cbn2 = pos[n * 15 + 14];
    float Rn[9], Rj[9];
    #pragma unroll
    for (int i = 0; i < 9; i++) Rn[i] = R[n * 9 + i];
    #pragma unroll
    for (int i = 0; i < 9; i++) Rj[i] = R[j * 9 + i];
    float pj[15];
    #pragma unroll
    for (int i = 0; i < 15; i++) pj[i] = pos[j * 15 + i];

    float fe[43];
    float d0 = pj[12] - cbn0, d1 = pj[13] - cbn1, d2 = pj[14] - cbn2;
    float dcb = sqrtf(d0 * d0 + d1 * d1 + d2 * d2 + 1e-8f);
    #pragma unroll
    for (int i = 0; i < 16; i++) {
        float c = (22.f / 15.f) * (float)i;
        float z = (dcb - c) * (1.f / 1.375f);
        fe[i] = __expf(-z * z);
    }
    #pragma unroll
    for (int a = 0; a < 5; a++) {
        float vx = pj[a * 3 + 0] - can0;
        float vy = pj[a * 3 + 1] - can1;
        float vz = pj[a * 3 + 2] - can2;
        float invv = rsqrtf(vx * vx + vy * vy + vz * vz + 1e-8f);
        fe[16 + a * 3 + 0] = vx * invv;
        fe[16 + a * 3 + 1] = vy * invv;
        fe[16 + a * 3 + 2] = vz * invv;
    }
    #pragma unroll
    for (int b = 0; b < 3; b++)
        #pragma unroll
        for (int c2 = 0; c2 < 3; c2++)
            fe[31 + b * 3 + c2] = Rn[0 + b] * Rj[0 + c2] + Rn[3 + b] * Rj[3 + c2] + Rn[6 + b] * Rj[6 + c2];
    float t0 = pj[3] - can0, t1 = pj[4] - can1, t2 = pj[5] - can2;
    #pragma unroll
    for (int b = 0; b < 3; b++)
        fe[40 + b] = Rn[0 + b] * t0 + Rn[3 + b] * t1 + Rn[6 + b] * t2;

    #pragma unroll
    for (int q = 0; q < 8; q++) {
        uint4 w;
        float v0 = (q * 8 + 0 < 43) ? fe[q * 8 + 0] : 0.f;
        float v1 = (q * 8 + 1 < 43) ? fe[q * 8 + 1] : 0.f;
        float v2 = (q * 8 + 2 < 43) ? fe[q * 8 + 2] : 0.f;
        float v3 = (q * 8 + 3 < 43) ? fe[q * 8 + 3] : 0.f;
        float v4 = (q * 8 + 4 < 43) ? fe[q * 8 + 4] : 0.f;
        float v5 = (q * 8 + 5 < 43) ? fe[q * 8 + 5] : 0.f;
        float v6 = (q * 8 + 6 < 43) ? fe[q * 8 + 6] : 0.f;
        float v7 = (q * 8 + 7 < 43) ? fe[q * 8 + 7] : 0.f;
        w.x = pk2(v0, v1); w.y = pk2(v2, v3); w.z = pk2(v4, v5); w.w = pk2(v6, v7);
        *(uint4*)&feat[(size_t)p * 64 + q * 8] = w;
    }
    float rt0 = fe[40], rt1 = fe[41], rt2 = fe[42];
    float dr2 = rt0 * rt0 + rt1 * rt1 + rt2 * rt2 + 1e-8f;
    float invdr = rsqrtf(dr2);
    float drel = dr2 * invdr;
    float* tf = tfeat_raw + (size_t)n * 608 + k * 19;
    #pragma unroll
    for (int i = 0; i < 16; i++) {
        float c = (22.f / 15.f) * (float)i;
        float z = (drel - c) * (1.f / 1.375f);
        tf[i] = __expf(-z * z);
    }
    tf[16] = rt0 * invdr;
    tf[17] = rt1 * invdr;
    tf[18] = rt2 * invdr;
}

// ---------------- pair stage0: feat-proj MFMA + relpos + LN, in-place feat -> pln ----------------
// weights in VGPR (8 frags = 32 VGPR); no LDS. In-place is safe: the stored values
// depend (via MFMA+LN) on the loaded ones, so loads have returned before stores issue,
// and each 64-ushort row is owned by exactly one wave.
__global__ __launch_bounds__(256) void pair_pre_kernel(
    ushort* feat, const int* __restrict__ relidx,
    const float* __restrict__ w_relpos,
    const float* __restrict__ w_dist, const float* __restrict__ w_dir,
    const float* __restrict__ w_rot,
    const float* __restrict__ lng, const float* __restrict__ lnb) {
    int tid = threadIdx.x;
    int wid = tid >> 6, lane = tid & 63, hi = lane >> 4, lo = lane & 15;
    union U8 { bf16x8 v; uint u[4]; };
    U8 wf[8];
    #pragma unroll
    for (int f = 0; f < 4; f++)
        #pragma unroll
        for (int s = 0; s < 2; s++)
            #pragma unroll
            for (int jj = 0; jj < 4; jj++) {
                int k0 = 32 * s + hi * 8 + 2 * jj;
                int c = 16 * f + lo;
                float v0 = (k0 < 16) ? w_dist[k0 * 64 + c] : (k0 < 31) ? w_dir[(k0 - 16) * 64 + c]
                         : (k0 < 43) ? w_rot[(k0 - 31) * 64 + c] : 0.f;
                int k1 = k0 + 1;
                float v1 = (k1 < 16) ? w_dist[k1 * 64 + c] : (k1 < 31) ? w_dir[(k1 - 16) * 64 + c]
                         : (k1 < 43) ? w_rot[(k1 - 31) * 64 + c] : 0.f;
                wf[f * 2 + s].u[jj] = pk2(v0, v1);
            }
    float sg_r[4][4], sbt_r[4][4];
    #pragma unroll
    for (int f = 0; f < 4; f++)
        #pragma unroll
        for (int r = 0; r < 4; r++) {
            int c = 16 * f + 4 * hi + r;
            sg_r[f][r] = lng[c];
            sbt_r[f][r] = lnb[c];
        }
    const f32x4 zz = {0.f, 0.f, 0.f, 0.f};
    for (int t = blockIdx.x * 4 + wid; t < (NN * KK / 16); t += 4096) {
        int r0 = t << 4;
        bf16x8 bp0 = *(const bf16x8*)(feat + (size_t)(r0 + lo) * 64 + hi * 8);
        bf16x8 bp1 = *(const bf16x8*)(feat + (size_t)(r0 + lo) * 64 + 32 + hi * 8);
        f32x4 a0f[4];
        #pragma unroll
        for (int f = 0; f < 4; f++) {
            a0f[f] = __builtin_amdgcn_mfma_f32_16x16x32_bf16(wf[f * 2 + 0].v, bp0, zz, 0, 0, 0);
            a0f[f] = __builtin_amdgcn_mfma_f32_16x16x32_bf16(wf[f * 2 + 1].v, bp1, a0f[f], 0, 0, 0);
        }
        int ridx = relidx[r0 + lo];
        float val[4][4];
        float part = 0.f;
        #pragma unroll
        for (int f = 0; f < 4; f++)
            #pragma unroll
            for (int r = 0; r < 4; r++) {
                int c = 16 * f + 4 * hi + r;
                float rv = (ridx >= 0) ? w_relpos[ridx * 64 + c] : 0.f;
                float v = a0f[f][r] + rv;
                val[f][r] = v;
                part += v;
            }
        part += __shfl_xor(part, 16);
        part += __shfl_xor(part, 32);
        float mean = part * (1.f / 64.f);
        float v2 = 0.f;
        #pragma unroll
        for (int f = 0; f < 4; f++)
            #pragma unroll
            for (int r = 0; r < 4; r++) {
                float dv = val[f][r] - mean;
                val[f][r] = dv;
                v2 += dv * dv;
            }
        v2 += __shfl_xor(v2, 16);
        v2 += __shfl_xor(v2, 32);
        float rs = rsqrtf(v2 * (1.f / 64.f) + 1e-5f);
        #pragma unroll
        for (int f = 0; f < 4; f++) {
            float v0 = val[f][0] * rs * sg_r[f][0] + sbt_r[f][0];
            float v1 = val[f][1] * rs * sg_r[f][1] + sbt_r[f][1];
            float v2b = val[f][2] * rs * sg_r[f][2] + sbt_r[f][2];
            float v3 = val[f][3] * rs * sg_r[f][3] + sbt_r[f][3];
            *(uint2*)(feat + (size_t)(r0 + lo) * 64 + 16 * f + 4 * hi) =
                make_uint2(pk2(v0, v1), pk2(v2b, v3));
        }
    }
}

// ---------------- pair MLP: pln -> 128 gelu -> 64 -> @wb -> bias; weights in VGPR ----------------
__global__ __launch_bounds__(256) void pair_mlp2_kernel(
    const ushort* __restrict__ pln,
    const float* __restrict__ w_p1, const float* __restrict__ b_p1,
    const float* __restrict__ w_p2, const float* __restrict__ b_p2,
    const float* __restrict__ wb, float* __restrict__ bias) {
    __shared__ __align__(16) ushort hx[4 * 2048];
    __shared__ float swb[512];
    __shared__ float sb2[64];
    int tid = threadIdx.x;
    for (int i = tid; i < 512; i += 256) swb[i] = wb[i];
    if (tid < 64) sb2[tid] = b_p2[tid];
    int wid = tid >> 6, lane = tid & 63, hi = lane >> 4, lo = lane & 15;
    union U8 { bf16x8 v; uint u[4]; };
    U8 w1f[16], w2f[16];
    #pragma unroll
    for (int f = 0; f < 8; f++)
        #pragma unroll
        for (int s = 0; s < 2; s++)
            #pragma unroll
            for (int jj = 0; jj < 4; jj++) {
                int k0 = 32 * s + hi * 8 + 2 * jj;
                int c = 16 * f + lo;
                w1f[f * 2 + s].u[jj] = pk2(w_p1[k0 * 128 + c], w_p1[(k0 + 1) * 128 + c]);
            }
    #pragma unroll
    for (int f2 = 0; f2 < 4; f2++)
        #pragma unroll
        for (int s2 = 0; s2 < 4; s2++)
            #pragma unroll
            for (int jj = 0; jj < 4; jj++) {
                int k0 = 32 * s2 + hi * 8 + 2 * jj;
                int c = 16 * f2 + lo;
                w2f[f2 * 4 + s2].u[jj] = pk2(w_p2[k0 * 64 + c], w_p2[(k0 + 1) * 64 + c]);
            }
    // per-lane layer1 bias (channels 16f+4hi+r)
    float sb1_r[8][4];
    #pragma unroll
    for (int f = 0; f < 8; f++)
        #pragma unroll
        for (int r = 0; r < 4; r++) sb1_r[f][r] = b_p1[16 * f + 4 * hi + r];
    __syncthreads();

    ushort* hxw = &hx[wid * 2048];
    const f32x4 zz = {0.f, 0.f, 0.f, 0.f};
    for (int t = blockIdx.x * 4 + wid; t < (NN * KK / 16); t += 4096) {
        int r0 = t << 4;
        bf16x8 bh0 = *(const bf16x8*)(pln + (size_t)(r0 + lo) * 64 + hi * 8);
        bf16x8 bh1 = *(const bf16x8*)(pln + (size_t)(r0 + lo) * 64 + 32 + hi * 8);
        // layer1 per-f: mfma x2 -> gelu -> pack to hx (only one acch live)
        #pragma unroll
        for (int f = 0; f < 8; f++) {
            f32x4 acch = __builtin_amdgcn_mfma_f32_16x16x32_bf16(w1f[f * 2 + 0].v, bh0, zz, 0, 0, 0);
            acch = __builtin_amdgcn_mfma_f32_16x16x32_bf16(w1f[f * 2 + 1].v, bh1, acch, 0, 0, 0);
            int c0 = 16 * f + 4 * hi;
            float v0 = gelu_f(acch[0] + sb1_r[f][0]);
            float v1 = gelu_f(acch[1] + sb1_r[f][1]);
            float v2b = gelu_f(acch[2] + sb1_r[f][2]);
            float v3 = gelu_f(acch[3] + sb1_r[f][3]);
            int idx = (lo * 128 + c0) ^ ((lo & 7) << 3);
            *(uint2*)&hxw[idx] = make_uint2(pk2(v0, v1), pk2(v2b, v3));
        }
        // layer2
        f32x4 accp[4] = {zz, zz, zz, zz};
        #pragma unroll
        for (int s2 = 0; s2 < 4; s2++) {
            int idx = (lo * 128 + 32 * s2 + 8 * hi) ^ ((lo & 7) << 3);
            bf16x8 bh = *(const bf16x8*)&hxw[idx];
            #pragma unroll
            for (int f2 = 0; f2 < 4; f2++)
                accp[f2] = __builtin_amdgcn_mfma_f32_16x16x32_bf16(w2f[f2 * 4 + s2].v, bh, accp[f2], 0, 0, 0);
        }
        // pair2 @ wb in-register
        float prt[8] = {0.f, 0.f, 0.f, 0.f, 0.f, 0.f, 0.f, 0.f};
        #pragma unroll
        for (int f2 = 0; f2 < 4; f2++)
            #pragma unroll
            for (int r = 0; r < 4; r++) {
                int c2 = 16 * f2 + 4 * hi + r;
                float vv = accp[f2][r] + sb2[c2];
                #pragma unroll
                for (int h = 0; h < 8; h++) prt[h] += vv * swb[c2 * 8 + h];
            }
        #pragma unroll
        for (int h = 0; h < 8; h++) {
            prt[h] += __shfl_xor(prt[h], 16);
            prt[h] += __shfl_xor(prt[h], 32);
        }
        int n = r0 >> 5, kb = (r0 & 31) + lo;
        bias[(size_t)n * 256 + (2 * hi) * 32 + kb] = prt[2 * hi];
        bias[(size_t)n * 256 + (2 * hi + 1) * 32 + kb] = prt[2 * hi + 1];
    }
}

// ---------------- shared bf16 GEMM core (BN=128) ----------------
__device__ __forceinline__ void gemm_core(
    const float* __restrict__ A, const float* __restrict__ W,
    int K, int WN, int row0, int colW0, int tid,
    ushort* sA, ushort* sB, f32x4 acc[4][4]) {
    int wid = tid >> 6, lane = tid & 63, lo = lane & 15, hi = lane >> 4;
    int wr = wid >> 1, wc = wid & 1;
    int ar = tid >> 1, akh = (tid & 1) * 16;
    int bcol = tid & 127, bks = (tid >> 7) * 16;
    for (int kt = 0; kt < K; kt += 32) {
        const float* ap = &A[(size_t)(row0 + ar) * K + kt + akh];
        float4 a0 = *(const float4*)(ap + 0);
        float4 a1 = *(const float4*)(ap + 4);
        float4 a2 = *(const float4*)(ap + 8);
        float4 a3 = *(const float4*)(ap + 12);
        float wv[16];
        #pragma unroll
        for (int i = 0; i < 16; i++) wv[i] = W[(size_t)(kt + bks + i) * WN + colW0 + bcol];
        __syncthreads();
        *(uint4*)&sA[ar * 40 + akh] = make_uint4(pk2(a0.x, a0.y), pk2(a0.z, a0.w), pk2(a1.x, a1.y), pk2(a1.z, a1.w));
        *(uint4*)&sA[ar * 40 + akh + 8] = make_uint4(pk2(a2.x, a2.y), pk2(a2.z, a2.w), pk2(a3.x, a3.y), pk2(a3.z, a3.w));
        *(uint4*)&sB[bcol * 40 + bks] = make_uint4(pk2(wv[0], wv[1]), pk2(wv[2], wv[3]), pk2(wv[4], wv[5]), pk2(wv[6], wv[7]));
        *(uint4*)&sB[bcol * 40 + bks + 8] = make_uint4(pk2(wv[8], wv[9]), pk2(wv[10], wv[11]), pk2(wv[12], wv[13]), pk2(wv[14], wv[15]));
        __syncthreads();
        bf16x8 af[4], bfr[4];
        #pragma unroll
        for (int mi = 0; mi < 4; mi++) af[mi] = *(const bf16x8*)&sA[(wr * 64 + mi * 16 + lo) * 40 + hi * 8];
        #pragma unroll
        for (int ni = 0; ni < 4; ni++) bfr[ni] = *(const bf16x8*)&sB[(wc * 64 + ni * 16 + lo) * 40 + hi * 8];
        #pragma unroll
        for (int mi = 0; mi < 4; mi++)
            #pragma unroll
            for (int ni = 0; ni < 4; ni++)
                acc[mi][ni] = __builtin_amdgcn_mfma_f32_16x16x32_bf16(af[mi], bfr[ni], acc[mi][ni], 0, 0, 0);
    }
}

// ---------------- plain GEMM (BM=128, BN=128) ----------------
__global__ __launch_bounds__(256) void gemm_plain(
    const float* __restrict__ A, const float* __restrict__ W, float* __restrict__ C,
    int M, int K, int Nc,
    const float* __restrict__ bias, const float* __restrict__ addp, int do_gelu) {
    __shared__ __align__(16) ushort sA[128 * 40];
    __shared__ __align__(16) ushort sB[128 * 40];
    int row0 = blockIdx.y * 128, col0 = blockIdx.x * 128;
    int tid = threadIdx.x;
    const f32x4 zz = {0.f, 0.f, 0.f, 0.f};
    f32x4 acc[4][4] = {{zz, zz, zz, zz}, {zz, zz, zz, zz}, {zz, zz, zz, zz}, {zz, zz, zz, zz}};
    gemm_core(A, W, K, Nc, row0, col0, tid, sA, sB, acc);
    int wid = tid >> 6, lane = tid & 63, lo = lane & 15, hi = lane >> 4;
    int wr = wid >> 1, wc = wid & 1;
    #pragma unroll
    for (int ni = 0; ni < 4; ni++) {
        int col = col0 + wc * 64 + ni * 16 + lo;
        float bc = bias ? bias[col] : 0.f;
        #pragma unroll
        for (int mi = 0; mi < 4; mi++) {
            #pragma unroll
            for (int r = 0; r < 4; r++) {
                int row = row0 + wr * 64 + mi * 16 + hi * 4 + r;
                float v = acc[mi][ni][r] + bc;
                if (do_gelu) v = gelu_f(v);
                if (addp) v += addp[(size_t)row * Nc + col];
                C[(size_t)row * Nc + col] = v;
            }
        }
    }
}

// ---------------- narrow GEMM (BM=128, BN=64) for Nc=256 outputs ----------------
__global__ __launch_bounds__(256) void gemm_n64(
    const float* __restrict__ A, const float* __restrict__ W, float* __restrict__ C,
    int M, int K, int Nc,
    const float* __restrict__ bias, const float* __restrict__ addp, int do_gelu) {
    __shared__ __align__(16) ushort sA[128 * 40];
    __shared__ __align__(16) ushort sB[64 * 40];
    int row0 = blockIdx.y * 128, col0 = blockIdx.x * 64;
    int tid = threadIdx.x;
    int wid = tid >> 6, lane = tid & 63, lo = lane & 15, hi = lane >> 4;
    int wr = wid >> 1, wc = wid & 1;
    int ar = tid >> 1, akh = (tid & 1) * 16;
    int bcol = tid & 63, bks = (tid >> 6) * 8;
    const f32x4 zz = {0.f, 0.f, 0.f, 0.f};
    f32x4 acc[4][2] = {{zz, zz}, {zz, zz}, {zz, zz}, {zz, zz}};
    for (int kt = 0; kt < K; kt += 32) {
        const float* ap = &A[(size_t)(row0 + ar) * K + kt + akh];
        float4 a0 = *(const float4*)(ap + 0);
        float4 a1 = *(const float4*)(ap + 4);
        float4 a2 = *(const float4*)(ap + 8);
        float4 a3 = *(const float4*)(ap + 12);
        float wv[8];
        #pragma unroll
        for (int i = 0; i < 8; i++) wv[i] = W[(size_t)(kt + bks + i) * Nc + col0 + bcol];
        __syncthreads();
        *(uint4*)&sA[ar * 40 + akh] = make_uint4(pk2(a0.x, a0.y), pk2(a0.z, a0.w), pk2(a1.x, a1.y), pk2(a1.z, a1.w));
        *(uint4*)&sA[ar * 40 + akh + 8] = make_uint4(pk2(a2.x, a2.y), pk2(a2.z, a2.w), pk2(a3.x, a3.y), pk2(a3.z, a3.w));
        *(uint2*)&sB[bcol * 40 + bks] = make_uint2(pk2(wv[0], wv[1]), pk2(wv[2], wv[3]));
        *(uint2*)&sB[bcol * 40 + bks + 4] = make_uint2(pk2(wv[4], wv[5]), pk2(wv[6], wv[7]));
        __syncthreads();
        bf16x8 af[4], bfr[2];
        #pragma unroll
        for (int mi = 0; mi < 4; mi++) af[mi] = *(const bf16x8*)&sA[(wr * 64 + mi * 16 + lo) * 40 + hi * 8];
        #pragma unroll
        for (int ni = 0; ni < 2; ni++) bfr[ni] = *(const bf16x8*)&sB[(wc * 32 + ni * 16 + lo) * 40 + hi * 8];
        #pragma unroll
        for (int mi = 0; mi < 4; mi++)
            #pragma unroll
            for (int ni = 0; ni < 2; ni++)
                acc[mi][ni] = __builtin_amdgcn_mfma_f32_16x16x32_bf16(af[mi], bfr[ni], acc[mi][ni], 0, 0, 0);
    }
    #pragma unroll
    for (int ni = 0; ni < 2; ni++) {
        int col = col0 + wc * 32 + ni * 16 + lo;
        float bc = bias ? bias[col] : 0.f;
        #pragma unroll
        for (int mi = 0; mi < 4; mi++) {
            #pragma unroll
            for (int r = 0; r < 4; r++) {
                int row = row0 + wr * 64 + mi * 16 + hi * 4 + r;
                float v = acc[mi][ni][r] + bc;
                if (do_gelu) v = gelu_f(v);
                if (addp) v += addp[(size_t)row * Nc + col];
                C[(size_t)row * Nc + col] = v;
            }
        }
    }
}

// ---------------- fused QKV GEMM: q fp32, k/v bf16 ----------------
__global__ __launch_bounds__(256) void gemm_qkv(
    const float* __restrict__ A, const float* __restrict__ wq, const float* __restrict__ wk,
    const float* __restrict__ wvp, float* __restrict__ qb, ushort* __restrict__ kb,
    ushort* __restrict__ vb, int K) {
    __shared__ __align__(16) ushort sA[128 * 40];
    __shared__ __align__(16) ushort sB[128 * 40];
    int row0 = blockIdx.y * 128, col0 = blockIdx.x * 128;
    int wsel = col0 >> 8, colW0 = col0 & 255;
    const float* W = (wsel == 0) ? wq : (wsel == 1) ? wk : wvp;
    int tid = threadIdx.x;
    const f32x4 zz = {0.f, 0.f, 0.f, 0.f};
    f32x4 acc[4][4] = {{zz, zz, zz, zz}, {zz, zz, zz, zz}, {zz, zz, zz, zz}, {zz, zz, zz, zz}};
    gemm_core(A, W, K, 256, row0, colW0, tid, sA, sB, acc);
    int wid = tid >> 6, lane = tid & 63, lo = lane & 15, hi = lane >> 4;
    int wr = wid >> 1, wc = wid & 1;
    #pragma unroll
    for (int ni = 0; ni < 4; ni++) {
        int colW = colW0 + wc * 64 + ni * 16 + lo;
        #pragma unroll
        for (int mi = 0; mi < 4; mi++) {
            #pragma unroll
            for (int r = 0; r < 4; r++) {
                int row = row0 + wr * 64 + mi * 16 + hi * 4 + r;
                float v = acc[mi][ni][r];
                if (wsel == 0) qb[(size_t)row * 256 + colW] = v;
                else if (wsel == 1) kb[(size_t)row * 256 + colW] = f2bf(v);
                else vb[(size_t)row * 256 + colW] = f2bf(v);
            }
        }
    }
}

// ---------------- fused FFN GEMM: up (no gelu) + lg/cg/bg (gelu) ----------------
__global__ __launch_bounds__(256) void gemm_ffn(
    const float* __restrict__ A,
    const float* __restrict__ w0, const float* __restrict__ w1,
    const float* __restrict__ w2, const float* __restrict__ w3,
    float* __restrict__ o0, float* __restrict__ o1,
    float* __restrict__ o2, float* __restrict__ o3, int K) {
    __shared__ __align__(16) ushort sA[128 * 40];
    __shared__ __align__(16) ushort sB[128 * 40];
    int row0 = blockIdx.y * 128, col0 = blockIdx.x * 128;
    int wsel = col0 >> 9, colW0 = col0 & 511;
    const float* W = (wsel == 0) ? w0 : (wsel == 1) ? w1 : (wsel == 2) ? w2 : w3;
    float* O = (wsel == 0) ? o0 : (wsel == 1) ? o1 : (wsel == 2) ? o2 : o3;
    int tid = threadIdx.x;
    const f32x4 zz = {0.f, 0.f, 0.f, 0.f};
    f32x4 acc[4][4] = {{zz, zz, zz, zz}, {zz, zz, zz, zz}, {zz, zz, zz, zz}, {zz, zz, zz, zz}};
    gemm_core(A, W, K, 512, row0, colW0, tid, sA, sB, acc);
    int wid = tid >> 6, lane = tid & 63, lo = lane & 15, hi = lane >> 4;
    int wr = wid >> 1, wc = wid & 1;
    #pragma unroll
    for (int ni = 0; ni < 4; ni++) {
        int colW = colW0 + wc * 64 + ni * 16 + lo;
        #pragma unroll
        for (int mi = 0; mi < 4; mi++) {
            #pragma unroll
            for (int r = 0; r < 4; r++) {
                int row = row0 + wr * 64 + mi * 16 + hi * 4 + r;
                float v = acc[mi][ni][r];
                if (wsel > 0) v = gelu_f(v);
                O[(size_t)row * 512 + colW] = v;
            }
        }
    }
}

// ---------------- attention: QK direct-gather + V staged through LDS ----------------
__global__ __launch_bounds__(256) void attn_kernel(
    const float* __restrict__ q, const ushort* __restrict__ kp, const ushort* __restrict__ vp,
    const float* __restrict__ bias, const int* __restrict__ nbr, float* __restrict__ o) {
    int n = blockIdx.x;
    __shared__ float qs[256];
    __shared__ int js[32];
    __shared__ float ls[256];                  // [h][k]
    __shared__ __align__(16) uint4 vs[32 * 33]; // 32 v-rows, +1 uint4 pad
    int t = threadIdx.x;
    qs[t] = q[(size_t)n * 256 + t];
    if (t < 32) js[t] = nbr[n * 32 + t];
    __syncthreads();
    // stage V gathers into registers early (latency hides under QK)
    int vrow = t >> 3, vseg = t & 7;
    const uint4* vsrc = (const uint4*)(vp + (size_t)js[vrow] * 256);
    uint4 vr0 = vsrc[vseg * 4 + 0];
    uint4 vr1 = vsrc[vseg * 4 + 1];
    uint4 vr2 = vsrc[vseg * 4 + 2];
    uint4 vr3 = vsrc[vseg * 4 + 3];
    // QK: thread (h,k)
    int h = t >> 5, k = t & 31;
    int j = js[k];
    const bf16x8* kr = (const bf16x8*)(kp + (size_t)j * 256 + h * 32);
    bf16x8 kv0 = kr[0], kv1 = kr[1], kv2 = kr[2], kv3 = kr[3];
    const float* qh = qs + h * 32;
    float dot = 0.f;
    #pragma unroll
    for (int i = 0; i < 8; i++) dot += qh[i] * bf2f((ushort)kv0[i]);
    #pragma unroll
    for (int i = 0; i < 8; i++) dot += qh[8 + i] * bf2f((ushort)kv1[i]);
    #pragma unroll
    for (int i = 0; i < 8; i++) dot += qh[16 + i] * bf2f((ushort)kv2[i]);
    #pragma unroll
    for (int i = 0; i < 8; i++) dot += qh[24 + i] * bf2f((ushort)kv3[i]);
    float l = dot * 0.17677669529663687f + bias[(size_t)n * 256 + t];
    float mx = l;
    #pragma unroll
    for (int m = 16; m > 0; m >>= 1) mx = fmaxf(mx, __shfl_xor(mx, m));
    float e = __expf(l - mx);
    float sum = e;
    #pragma unroll
    for (int m = 16; m > 0; m >>= 1) sum += __shfl_xor(sum, m);
    ls[t] = e / sum;
    // commit V to LDS
    vs[vrow * 33 + vseg * 4 + 0] = vr0;
    vs[vrow * 33 + vseg * 4 + 1] = vr1;
    vs[vrow * 33 + vseg * 4 + 2] = vr2;
    vs[vrow * 33 + vseg * 4 + 3] = vr3;
    __syncthreads();
    // PV: thread (h,d) — ls broadcast + conflict-free u16 reads
    const ushort* vsu = (const ushort*)vs;
    const float* lh = ls + h * 32;
    float acc = 0.f;
    #pragma unroll
    for (int kk = 0; kk < 32; kk++)
        acc += lh[kk] * bf2f(vsu[kk * 264 + h * 32 + k]);
    o[(size_t)n * 256 + t] = acc;
}

// ---------------- LN(a+b) with sum output ----------------
__global__ __launch_bounds__(256) void ln_add_kernel(
    const float* __restrict__ a, const float* __restrict__ b,
    const float* __restrict__ g, const float* __restrict__ be,
    float* __restrict__ xout, float* __restrict__ sout) {
    int row = blockIdx.x * 4 + (threadIdx.x >> 6);
    int lane = threadIdx.x & 63;
    size_t base = (size_t)row * 256 + lane * 4;
    float4 av = *(const float4*)(a + base);
    float4 bv = *(const float4*)(b + base);
    float s0 = av.x + bv.x, s1 = av.y + bv.y, s2 = av.z + bv.z, s3 = av.w + bv.w;
    float sum = wave_sum64(s0 + s1 + s2 + s3);
    float mean = sum * (1.f / 256.f);
    float d0 = s0 - mean, d1 = s1 - mean, d2 = s2 - mean, d3 = s3 - mean;
    float v = wave_sum64(d0 * d0 + d1 * d1 + d2 * d2 + d3 * d3);
    float rs = rsqrtf(v * (1.f / 256.f) + 1e-5f);
    float4 gv = *(const float4*)(g + lane * 4);
    float4 bev = *(const float4*)(be + lane * 4);
    float4 xo;
    xo.x = d0 * rs * gv.x + bev.x;
    xo.y = d1 * rs * gv.y + bev.y;
    xo.z = d2 * rs * gv.z + bev.z;
    xo.w = d3 * rs * gv.w + bev.w;
    *(float4*)(xout + base) = xo;
    float4 so; so.x = s0; so.y = s1; so.z = s2; so.w = s3;
    *(float4*)(sout + base) = so;
}

// ---------------- segment means ----------------
__device__ __forceinline__ int lower_bound_i(const int* a, int n, int v) {
    int lo = 0, hi = n;
    while (lo < hi) { int mid = (lo + hi) >> 1; if (a[mid] < v) lo = mid + 1; else hi = mid; }
    return lo;
}

__global__ __launch_bounds__(256) void seg_mean_kernel(
    const float* __restrict__ up, const int* __restrict__ batch, const int* __restrict__ chain,
    float* __restrict__ mb, float* __restrict__ mc) {
    int b = blockIdx.x;
    const int* arr;
    float* outp;
    int seg;
    if (b < NBATCH) { arr = batch; outp = mb; seg = b; }
    else { arr = chain; outp = mc; seg = b - NBATCH; }
    int lo = lower_bound_i(arr, NN, seg);
    int hi = lower_bound_i(arr, NN, seg + 1);
    int t = threadIdx.x;
    float a0 = 0.f, a1 = 0.f;
    for (int r = lo; r < hi; r++) {
        a0 += up[(size_t)r * 512 + t];
        a1 += up[(size_t)r * 512 + 256 + t];
    }
    float inv = 1.f / fmaxf((float)(hi - lo), 1.f);
    outp[seg * 512 + t] = a0 * inv;
    outp[seg * 512 + 256 + t] = a1 * inv;
}

// ---------------- hidden combine ----------------
__global__ __launch_bounds__(256) void hidden_kernel(
    const float* __restrict__ up, const float* __restrict__ cg, const float* __restrict__ bg,
    float* __restrict__ lg, const float* __restrict__ mb, const float* __restrict__ mc,
    const int* __restrict__ batch, const int* __restrict__ chain) {
    size_t idx = (size_t)blockIdx.x * 256 + threadIdx.x;
    int n = idx >> 9, d = idx & 511;
    float h = bg[idx] * mb[batch[n] * 512 + d] + cg[idx] * mc[chain[n] * 512 + d] + lg[idx] * up[idx];
    lg[idx] = h;
}

// ---------------- final ----------------
__global__ __launch_bounds__(256) void final_kernel(
    const float* __restrict__ x1, const float* __restrict__ y2, const float* __restrict__ inc1,
    const float* __restrict__ ug, const float* __restrict__ ub,
    const float* __restrict__ fg, const float* __restrict__ fb, float* __restrict__ out) {
    int row = blockIdx.x * 4 + (threadIdx.x >> 6);
    int lane = threadIdx.x & 63;
    size_t base = (size_t)row * 256 + lane * 4;
    float4 xv = *(const float4*)(x1 + base);
    float4 yv = *(const float4*)(y2 + base);
    float4 iv = *(const float4*)(inc1 + base);
    float s0 = xv.x + yv.x, s1 = xv.y + yv.y, s2 = xv.z + yv.z, s3 = xv.w + yv.w;
    float t0 = iv.x + yv.x, t1 = iv.y + yv.y, t2 = iv.z + yv.z, t3 = iv.w + yv.w;
    float sums = wave_sum64(s0 + s1 + s2 + s3);
    float means = sums * (1.f / 256.f);
    float sd0 = s0 - means, sd1 = s1 - means, sd2 = s2 - means, sd3 = s3 - means;
    float vs = wave_sum64(sd0 * sd0 + sd1 * sd1 + sd2 * sd2 + sd3 * sd3);
    float rss = rsqrtf(vs * (1.f / 256.f) + 1e-5f);
    float sumt = wave_sum64(t0 + t1 + t2 + t3);
    float meant = sumt * (1.f / 256.f);
    float td0 = t0 - meant, td1 = t1 - meant, td2 = t2 - meant, td3 = t3 - meant;
    float vt = wave_sum64(td0 * td0 + td1 * td1 + td2 * td2 + td3 * td3);
    float rst = rsqrtf(vt * (1.f / 256.f) + 1e-5f);
    float4 ugv = *(const float4*)(ug + lane * 4);
    float4 ubv = *(const float4*)(ub + lane * 4);
    float4 fgv = *(const float4*)(fg + lane * 4);
    float4 fbv = *(const float4*)(fb + lane * 4);
    float4 ov;
    ov.x = (sd0 * rss * ugv.x + ubv.x) + (td0 * rst * fgv.x + fbv.x);
    ov.y = (sd1 * rss * ugv.y + ubv.y) + (td1 * rst * fgv.y + fbv.y);
    ov.z = (sd2 * rss * ugv.z + ubv.z) + (td2 * rst * fgv.z + fbv.z);
    ov.w = (sd3 * rss * ugv.w + ubv.w) + (td3 * rst * fgv.w + fbv.w);
    *(float4*)(out + base) = ov;
}

// ---------------- launch ----------------
extern "C" void kernel_launch(void* const* d_in, const int* in_sizes, int n_in,
                              void* d_out, int out_size, void* d_ws, size_t ws_size,
                              hipStream_t stream) {
    const float* local    = (const float*)d_in[0];
    const float* pos      = (const float*)d_in[1];
    const int*   nbr      = (const int*)d_in[2];
    const int*   resi     = (const int*)d_in[3];
    const int*   chain    = (const int*)d_in[4];
    const int*   batch    = (const int*)d_in[5];
    const float* w_relpos = (const float*)d_in[7];
    const float* w_dist   = (const float*)d_in[8];
    const float* w_dir    = (const float*)d_in[9];
    const float* w_rot    = (const float*)d_in[10];
    const float* ln_pair_g = (const float*)d_in[11];
    const float* ln_pair_b = (const float*)d_in[12];
    const float* w_p1     = (const float*)d_in[13];
    const float* b_p1     = (const float*)d_in[14];
    const float* w_p2     = (const float*)d_in[15];
    const float* b_p2     = (const float*)d_in[16];
    const float* wq       = (const float*)d_in[17];
    const float* wk       = (const float*)d_in[18];
    const float* wv       = (const float*)d_in[19];
    const float* wb       = (const float*)d_in[20];
    const float* wo       = (const float*)d_in[21];
    const float* ln_a_g   = (const float*)d_in[22];
    const float* ln_a_b   = (const float*)d_in[23];
    const float* w_t1     = (const float*)d_in[24];
    const float* w_t2     = (const float*)d_in[25];
    const float* w_up     = (const float*)d_in[26];
    const float* w_lg     = (const float*)d_in[27];
    const float* w_cg     = (const float*)d_in[28];
    const float* w_bg     = (const float*)d_in[29];
    const float* w_out    = (const float*)d_in[30];
    const float* b_out    = (const float*)d_in[31];
    const float* ln_u_g   = (const float*)d_in[32];
    const float* ln_u_b   = (const float*)d_in[33];
    const float* ln_f_g   = (const float*)d_in[34];
    const float* ln_f_b   = (const float*)d_in[35];

    float* ws = (float*)d_ws;
    float* R         = ws + 0;             // 9N -> 73728
    float* biasb     = ws + 73728;         // N*256 -> 2170880
    float* tfeat_out = ws + 2170880;       // N*256 -> 4268032
    float* x1        = ws + 4268032;       // N*256 -> 6365184
    float* inc1      = ws + 6365184;       // N*256 -> 8462336
    ushort* featb    = (ushort*)(ws + 8462336);  // N*K*64 bf16 (phase 1; becomes pln in-place)
    int* relidx      = (int*)(ws + 16850944);    // N*K
    float* tfeat_raw = ws + 17113088;      // N*608 (phase 1)
    float* tmp512    = ws + 22093824;      // N*512 (phase 1)
    float* qb        = ws + 8462336;       // N*256 fp32 (phase 2, over featb)
    ushort* kbu      = (ushort*)(ws + 10559488); // N*256 bf16
    ushort* vbu      = (ushort*)(ws + 12656640); // N*256 bf16
    float* ob        = ws + 14753792;      // N*256
    float* yb        = ws + 22093824;      // N*256 (over tmp512 after t2)
    float* upb       = ws + 8462336;       // N*512 (phase 3)
    float* lgb       = ws + 12656640;      // N*512
    float* cgb       = ws + 17113088;      // N*512
    float* bgb       = ws + 21307392;      // N*512
    float* mb        = ws + 25501696;      // 32*512
    float* mc        = ws + 25518080;      // 64*512
    float* y2        = ws + 25550848;      // N*256

    frames_kernel<<<NN / 256, 256, 0, stream>>>(pos, R);
    pair_raw_kernel<<<NN * KK / 256, 256, 0, stream>>>(pos, nbr, resi, chain, R,
                                                       featb, relidx, tfeat_raw);
    pair_pre_kernel<<<1024, 256, 0, stream>>>(featb, relidx, w_relpos, w_dist, w_dir, w_rot,
                                              ln_pair_g, ln_pair_b);
    pair_mlp2_kernel<<<1024, 256, 0, stream>>>(featb, w_p1, b_p1, w_p2, b_p2, wb, biasb);
    // tfeat MLP
    gemm_plain<<<dim3(4, 64), 256, 0, stream>>>(tfeat_raw, w_t1, tmp512, NN, 608, 512, nullptr, nullptr, 1);
    gemm_n64<<<dim3(4, 64), 256, 0, stream>>>(tmp512, w_t2, tfeat_out, NN, 512, 256, nullptr, nullptr, 0);
    // fused qkv projection (q fp32, k/v bf16)
    gemm_qkv<<<dim3(6, 64), 256, 0, stream>>>(local, wq, wk, wv, qb, kbu, vbu, 256);
    attn_kernel<<<NN, 256, 0, stream>>>(qb, kbu, vbu, biasb, nbr, ob);
    gemm_n64<<<dim3(4, 64), 256, 0, stream>>>(ob, wo, yb, NN, 256, 256, nullptr, nullptr, 0);
    ln_add_kernel<<<NN / 4, 256, 0, stream>>>(local, yb, ln_a_g, ln_a_b, x1, inc1);
    // fused FFN projections
    gemm_ffn<<<dim3(16, 64), 256, 0, stream>>>(x1, w_up, w_lg, w_cg, w_bg,
                                               upb, lgb, cgb, bgb, 256);
    seg_mean_kernel<<<NBATCH + NCHAIN, 256, 0, stream>>>(upb, batch, chain, mb, mc);
    hidden_kernel<<<NN * 512 / 256, 256, 0, stream>>>(upb, cgb, bgb, lgb, mb, mc, batch, chain);
    gemm_n64<<<dim3(4, 64), 256, 0, stream>>>(lgb, w_out, y2, NN, 512, 256, b_out, tfeat_out, 0);
    final_kernel<<<NN / 4, 256, 0, stream>>>(x1, y2, inc1, ln_u_g, ln_u_b, ln_f_g, ln_f_b, (float*)d_out);
}

// Round 8
// 376.541 us; speedup vs baseline: 1.0629x; 1.0629x over previous
//
#include <hip/hip_runtime.h>
#include <math.h>

#define NN 8192
#define KK 32
#define DD 256
#define PP 64
#define HH 8
#define DHH 32
#define NBATCH 32
#define NCHAIN 64

typedef __attribute__((ext_vector_type(8))) short bf16x8;
typedef __attribute__((ext_vector_type(4))) float f32x4;

// ---------------- helpers ----------------
__device__ __forceinline__ float gelu_f(float x) {
    float x3 = x * x * x;
    float z = 0.7978845608028654f * (x + 0.044715f * x3);
    z = fminf(fmaxf(z, -15.f), 15.f);
    float e = __expf(2.f * z);
    float t = (e - 1.f) / (e + 1.f);
    return 0.5f * x * (1.f + t);
}

__device__ __forceinline__ float wave_sum64(float v) {
    #pragma unroll
    for (int m = 32; m > 0; m >>= 1) v += __shfl_xor(v, m);
    return v;
}

__device__ __forceinline__ ushort f2bf(float x) {
    union { float f; unsigned int u; } v; v.f = x;
    unsigned int r = v.u + 0x7fffu + ((v.u >> 16) & 1u);
    return (ushort)(r >> 16);
}

__device__ __forceinline__ float bf2f(ushort u) {
    union { unsigned int u; float f; } v; v.u = ((unsigned int)u) << 16;
    return v.f;
}

__device__ __forceinline__ uint pk2(float a, float b) {
    return (uint)f2bf(a) | ((uint)f2bf(b) << 16);
}

// ---------------- frames ----------------
__global__ __launch_bounds__(256) void frames_kernel(const float* __restrict__ pos,
                                                     float* __restrict__ R) {
    int n = blockIdx.x * 256 + threadIdx.x;
    if (n >= NN) return;
    const float* p = pos + n * 15;
    float nx = p[0], ny = p[1], nz = p[2];
    float cax = p[3], cay = p[4], caz = p[5];
    float cx = p[6], cy = p[7], cz = p[8];
    float e1x = cx - cax, e1y = cy - cay, e1z = cz - caz;
    float inv = rsqrtf(e1x * e1x + e1y * e1y + e1z * e1z + 1e-8f);
    e1x *= inv; e1y *= inv; e1z *= inv;
    float ux = nx - cax, uy = ny - cay, uz = nz - caz;
    float dt = ux * e1x + uy * e1y + uz * e1z;
    float e2x = ux - dt * e1x, e2y = uy - dt * e1y, e2z = uz - dt * e1z;
    inv = rsqrtf(e2x * e2x + e2y * e2y + e2z * e2z + 1e-8f);
    e2x *= inv; e2y *= inv; e2z *= inv;
    float e3x = e1y * e2z - e1z * e2y;
    float e3y = e1z * e2x - e1x * e2z;
    float e3z = e1x * e2y - e1y * e2x;
    float* r = R + n * 9;
    r[0] = e1x; r[1] = e2x; r[2] = e3x;
    r[3] = e1y; r[4] = e2y; r[5] = e3y;
    r[6] = e1z; r[7] = e2z; r[8] = e3z;
}

// ---------------- raw pair features (lane = one (n,k) pair) ----------------
__global__ __launch_bounds__(256) void pair_raw_kernel(
    const float* __restrict__ pos, const int* __restrict__ nbr,
    const int* __restrict__ resi, const int* __restrict__ chain,
    const float* __restrict__ R,
    ushort* __restrict__ feat, int* __restrict__ relidx, float* __restrict__ tfeat_raw) {
    int p = blockIdx.x * 256 + threadIdx.x;
    int n = p >> 5, k = p & 31;
    int j = nbr[p];
    int same = (chain[j] == chain[n]);
    int off = min(max(resi[j] - resi[n], -32), 32) + 32;
    relidx[p] = same ? off : -1;

    float can0 = pos[n * 15 + 3], can1 = pos[n * 15 + 4], can2 = pos[n * 15 + 5];
    float cbn0 = pos[n * 15 + 12], cbn1 = pos[n * 15 + 13], cbn2 = pos[n * 15 + 14];
    float Rn[9], Rj[9];
    #pragma unroll
    for (int i = 0; i < 9; i++) Rn[i] = R[n * 9 + i];
    #pragma unroll
    for (int i = 0; i < 9; i++) Rj[i] = R[j * 9 + i];
    float pj[15];
    #pragma unroll
    for (int i = 0; i < 15; i++) pj[i] = pos[j * 15 + i];

    float fe[43];
    float d0 = pj[12] - cbn0, d1 = pj[13] - cbn1, d2 = pj[14] - cbn2;
    float dcb = sqrtf(d0 * d0 + d1 * d1 + d2 * d2 + 1e-8f);
    #pragma unroll
    for (int i = 0; i < 16; i++) {
        float c = (22.f / 15.f) * (float)i;
        float z = (dcb - c) * (1.f / 1.375f);
        fe[i] = __expf(-z * z);
    }
    #pragma unroll
    for (int a = 0; a < 5; a++) {
        float vx = pj[a * 3 + 0] - can0;
        float vy = pj[a * 3 + 1] - can1;
        float vz = pj[a * 3 + 2] - can2;
        float invv = rsqrtf(vx * vx + vy * vy + vz * vz + 1e-8f);
        fe[16 + a * 3 + 0] = vx * invv;
        fe[16 + a * 3 + 1] = vy * invv;
        fe[16 + a * 3 + 2] = vz * invv;
    }
    #pragma unroll
    for (int b = 0; b < 3; b++)
        #pragma unroll
        for (int c2 = 0; c2 < 3; c2++)
            fe[31 + b * 3 + c2] = Rn[0 + b] * Rj[0 + c2] + Rn[3 + b] * Rj[3 + c2] + Rn[6 + b] * Rj[6 + c2];
    float t0 = pj[3] - can0, t1 = pj[4] - can1, t2 = pj[5] - can2;
    #pragma unroll
    for (int b = 0; b < 3; b++)
        fe[40 + b] = Rn[0 + b] * t0 + Rn[3 + b] * t1 + Rn[6 + b] * t2;

    #pragma unroll
    for (int q = 0; q < 8; q++) {
        uint4 w;
        float v0 = (q * 8 + 0 < 43) ? fe[q * 8 + 0] : 0.f;
        float v1 = (q * 8 + 1 < 43) ? fe[q * 8 + 1] : 0.f;
        float v2 = (q * 8 + 2 < 43) ? fe[q * 8 + 2] : 0.f;
        float v3 = (q * 8 + 3 < 43) ? fe[q * 8 + 3] : 0.f;
        float v4 = (q * 8 + 4 < 43) ? fe[q * 8 + 4] : 0.f;
        float v5 = (q * 8 + 5 < 43) ? fe[q * 8 + 5] : 0.f;
        float v6 = (q * 8 + 6 < 43) ? fe[q * 8 + 6] : 0.f;
        float v7 = (q * 8 + 7 < 43) ? fe[q * 8 + 7] : 0.f;
        w.x = pk2(v0, v1); w.y = pk2(v2, v3); w.z = pk2(v4, v5); w.w = pk2(v6, v7);
        *(uint4*)&feat[(size_t)p * 64 + q * 8] = w;
    }
    float rt0 = fe[40], rt1 = fe[41], rt2 = fe[42];
    float dr2 = rt0 * rt0 + rt1 * rt1 + rt2 * rt2 + 1e-8f;
    float invdr = rsqrtf(dr2);
    float drel = dr2 * invdr;
    float* tf = tfeat_raw + (size_t)n * 608 + k * 19;
    #pragma unroll
    for (int i = 0; i < 16; i++) {
        float c = (22.f / 15.f) * (float)i;
        float z = (drel - c) * (1.f / 1.375f);
        tf[i] = __expf(-z * z);
    }
    tf[16] = rt0 * invdr;
    tf[17] = rt1 * invdr;
    tf[18] = rt2 * invdr;
}

// ---------------- pair stage0: feat-proj MFMA + relpos + LN, in-place feat -> pln ----------------
__global__ __launch_bounds__(256) void pair_pre_kernel(
    ushort* feat, const int* __restrict__ relidx,
    const float* __restrict__ w_relpos,
    const float* __restrict__ w_dist, const float* __restrict__ w_dir,
    const float* __restrict__ w_rot,
    const float* __restrict__ lng, const float* __restrict__ lnb) {
    int tid = threadIdx.x;
    int wid = tid >> 6, lane = tid & 63, hi = lane >> 4, lo = lane & 15;
    union U8 { bf16x8 v; uint u[4]; };
    U8 wf[8];
    #pragma unroll
    for (int f = 0; f < 4; f++)
        #pragma unroll
        for (int s = 0; s < 2; s++)
            #pragma unroll
            for (int jj = 0; jj < 4; jj++) {
                int k0 = 32 * s + hi * 8 + 2 * jj;
                int c = 16 * f + lo;
                float v0 = (k0 < 16) ? w_dist[k0 * 64 + c] : (k0 < 31) ? w_dir[(k0 - 16) * 64 + c]
                         : (k0 < 43) ? w_rot[(k0 - 31) * 64 + c] : 0.f;
                int k1 = k0 + 1;
                float v1 = (k1 < 16) ? w_dist[k1 * 64 + c] : (k1 < 31) ? w_dir[(k1 - 16) * 64 + c]
                         : (k1 < 43) ? w_rot[(k1 - 31) * 64 + c] : 0.f;
                wf[f * 2 + s].u[jj] = pk2(v0, v1);
            }
    float sg_r[4][4], sbt_r[4][4];
    #pragma unroll
    for (int f = 0; f < 4; f++)
        #pragma unroll
        for (int r = 0; r < 4; r++) {
            int c = 16 * f + 4 * hi + r;
            sg_r[f][r] = lng[c];
            sbt_r[f][r] = lnb[c];
        }
    const f32x4 zz = {0.f, 0.f, 0.f, 0.f};
    for (int t = blockIdx.x * 4 + wid; t < (NN * KK / 16); t += 4096) {
        int r0 = t << 4;
        bf16x8 bp0 = *(const bf16x8*)(feat + (size_t)(r0 + lo) * 64 + hi * 8);
        bf16x8 bp1 = *(const bf16x8*)(feat + (size_t)(r0 + lo) * 64 + 32 + hi * 8);
        f32x4 a0f[4];
        #pragma unroll
        for (int f = 0; f < 4; f++) {
            a0f[f] = __builtin_amdgcn_mfma_f32_16x16x32_bf16(wf[f * 2 + 0].v, bp0, zz, 0, 0, 0);
            a0f[f] = __builtin_amdgcn_mfma_f32_16x16x32_bf16(wf[f * 2 + 1].v, bp1, a0f[f], 0, 0, 0);
        }
        int ridx = relidx[r0 + lo];
        float val[4][4];
        float part = 0.f;
        #pragma unroll
        for (int f = 0; f < 4; f++)
            #pragma unroll
            for (int r = 0; r < 4; r++) {
                int c = 16 * f + 4 * hi + r;
                float rv = (ridx >= 0) ? w_relpos[ridx * 64 + c] : 0.f;
                float v = a0f[f][r] + rv;
                val[f][r] = v;
                part += v;
            }
        part += __shfl_xor(part, 16);
        part += __shfl_xor(part, 32);
        float mean = part * (1.f / 64.f);
        float v2 = 0.f;
        #pragma unroll
        for (int f = 0; f < 4; f++)
            #pragma unroll
            for (int r = 0; r < 4; r++) {
                float dv = val[f][r] - mean;
                val[f][r] = dv;
                v2 += dv * dv;
            }
        v2 += __shfl_xor(v2, 16);
        v2 += __shfl_xor(v2, 32);
        float rs = rsqrtf(v2 * (1.f / 64.f) + 1e-5f);
        #pragma unroll
        for (int f = 0; f < 4; f++) {
            float v0 = val[f][0] * rs * sg_r[f][0] + sbt_r[f][0];
            float v1 = val[f][1] * rs * sg_r[f][1] + sbt_r[f][1];
            float v2b = val[f][2] * rs * sg_r[f][2] + sbt_r[f][2];
            float v3 = val[f][3] * rs * sg_r[f][3] + sbt_r[f][3];
            *(uint2*)(feat + (size_t)(r0 + lo) * 64 + 16 * f + 4 * hi) =
                make_uint2(pk2(v0, v1), pk2(v2b, v3));
        }
    }
}

// ---------------- W2B = w_p2 @ wb  [128x8], b2b = b_p2 @ wb [8] ----------------
__global__ __launch_bounds__(256) void w2b_kernel(
    const float* __restrict__ w_p2, const float* __restrict__ b_p2,
    const float* __restrict__ wb, float* __restrict__ w2b, float* __restrict__ b2b) {
    int idx = blockIdx.x * 256 + threadIdx.x;
    if (idx < 1024) {
        int c = idx >> 3, h = idx & 7;
        float s = 0.f;
        for (int q = 0; q < 64; q++) s += w_p2[c * 64 + q] * wb[q * 8 + h];
        w2b[idx] = s;
    }
    if (idx < 8) {
        float s = 0.f;
        for (int q = 0; q < 64; q++) s += b_p2[q] * wb[q * 8 + idx];
        b2b[idx] = s;
    }
}

// ---------------- pair MLP: pln -> 128 gelu -> @W2B -> bias; weights in VGPR ----------------
__global__ __launch_bounds__(256) void pair_mlp2_kernel(
    const ushort* __restrict__ pln,
    const float* __restrict__ w_p1, const float* __restrict__ b_p1,
    const float* __restrict__ w2b, const float* __restrict__ b2b,
    float* __restrict__ bias) {
    __shared__ __align__(16) ushort hx[4 * 2048];
    int tid = threadIdx.x;
    int wid = tid >> 6, lane = tid & 63, hi = lane >> 4, lo = lane & 15;
    union U8 { bf16x8 v; uint u[4]; };
    U8 w1f[16];
    #pragma unroll
    for (int f = 0; f < 8; f++)
        #pragma unroll
        for (int s = 0; s < 2; s++)
            #pragma unroll
            for (int jj = 0; jj < 4; jj++) {
                int k0 = 32 * s + hi * 8 + 2 * jj;
                int c = 16 * f + lo;
                w1f[f * 2 + s].u[jj] = pk2(w_p1[k0 * 128 + c], w_p1[(k0 + 1) * 128 + c]);
            }
    // A-frags for W2B^T (rows = h, 8 used of 16)
    U8 w2f[4];
    #pragma unroll
    for (int s2 = 0; s2 < 4; s2++)
        #pragma unroll
        for (int jj = 0; jj < 4; jj++) {
            int c0 = 32 * s2 + 8 * hi + 2 * jj;
            float v0 = (lo < 8) ? w2b[c0 * 8 + lo] : 0.f;
            float v1 = (lo < 8) ? w2b[(c0 + 1) * 8 + lo] : 0.f;
            w2f[s2].u[jj] = pk2(v0, v1);
        }
    float b2b_r[4];
    #pragma unroll
    for (int r = 0; r < 4; r++) b2b_r[r] = (hi < 2) ? b2b[4 * hi + r] : 0.f;
    float sb1_r[8][4];
    #pragma unroll
    for (int f = 0; f < 8; f++)
        #pragma unroll
        for (int r = 0; r < 4; r++) sb1_r[f][r] = b_p1[16 * f + 4 * hi + r];

    ushort* hxw = &hx[wid * 2048];
    const f32x4 zz = {0.f, 0.f, 0.f, 0.f};
    for (int t = blockIdx.x * 4 + wid; t < (NN * KK / 16); t += 4096) {
        int r0 = t << 4;
        bf16x8 bh0 = *(const bf16x8*)(pln + (size_t)(r0 + lo) * 64 + hi * 8);
        bf16x8 bh1 = *(const bf16x8*)(pln + (size_t)(r0 + lo) * 64 + 32 + hi * 8);
        // layer1 per-f: mfma x2 -> gelu -> pack to hx
        #pragma unroll
        for (int f = 0; f < 8; f++) {
            f32x4 acch = __builtin_amdgcn_mfma_f32_16x16x32_bf16(w1f[f * 2 + 0].v, bh0, zz, 0, 0, 0);
            acch = __builtin_amdgcn_mfma_f32_16x16x32_bf16(w1f[f * 2 + 1].v, bh1, acch, 0, 0, 0);
            int c0 = 16 * f + 4 * hi;
            float v0 = gelu_f(acch[0] + sb1_r[f][0]);
            float v1 = gelu_f(acch[1] + sb1_r[f][1]);
            float v2b = gelu_f(acch[2] + sb1_r[f][2]);
            float v3 = gelu_f(acch[3] + sb1_r[f][3]);
            int idx = (lo * 128 + c0) ^ ((lo & 7) << 3);
            *(uint2*)&hxw[idx] = make_uint2(pk2(v0, v1), pk2(v2b, v3));
        }
        // layer2 (fused with wb): 128 -> 8
        f32x4 acc = zz;
        #pragma unroll
        for (int s2 = 0; s2 < 4; s2++) {
            int idx = (lo * 128 + 32 * s2 + 8 * hi) ^ ((lo & 7) << 3);
            bf16x8 bh = *(const bf16x8*)&hxw[idx];
            acc = __builtin_amdgcn_mfma_f32_16x16x32_bf16(w2f[s2].v, bh, acc, 0, 0, 0);
        }
        if (hi < 2) {
            int n = r0 >> 5, kb = (r0 & 31) + lo;
            #pragma unroll
            for (int r = 0; r < 4; r++)
                bias[(size_t)n * 256 + (4 * hi + r) * 32 + kb] = acc[r] + b2b_r[r];
        }
    }
}

// ---------------- shared bf16 GEMM core (BN=128) ----------------
__device__ __forceinline__ void gemm_core(
    const float* __restrict__ A, const float* __restrict__ W,
    int K, int WN, int row0, int colW0, int tid,
    ushort* sA, ushort* sB, f32x4 acc[4][4]) {
    int wid = tid >> 6, lane = tid & 63, lo = lane & 15, hi = lane >> 4;
    int wr = wid >> 1, wc = wid & 1;
    int ar = tid >> 1, akh = (tid & 1) * 16;
    int bcol = tid & 127, bks = (tid >> 7) * 16;
    for (int kt = 0; kt < K; kt += 32) {
        const float* ap = &A[(size_t)(row0 + ar) * K + kt + akh];
        float4 a0 = *(const float4*)(ap + 0);
        float4 a1 = *(const float4*)(ap + 4);
        float4 a2 = *(const float4*)(ap + 8);
        float4 a3 = *(const float4*)(ap + 12);
        float wv[16];
        #pragma unroll
        for (int i = 0; i < 16; i++) wv[i] = W[(size_t)(kt + bks + i) * WN + colW0 + bcol];
        __syncthreads();
        *(uint4*)&sA[ar * 40 + akh] = make_uint4(pk2(a0.x, a0.y), pk2(a0.z, a0.w), pk2(a1.x, a1.y), pk2(a1.z, a1.w));
        *(uint4*)&sA[ar * 40 + akh + 8] = make_uint4(pk2(a2.x, a2.y), pk2(a2.z, a2.w), pk2(a3.x, a3.y), pk2(a3.z, a3.w));
        *(uint4*)&sB[bcol * 40 + bks] = make_uint4(pk2(wv[0], wv[1]), pk2(wv[2], wv[3]), pk2(wv[4], wv[5]), pk2(wv[6], wv[7]));
        *(uint4*)&sB[bcol * 40 + bks + 8] = make_uint4(pk2(wv[8], wv[9]), pk2(wv[10], wv[11]), pk2(wv[12], wv[13]), pk2(wv[14], wv[15]));
        __syncthreads();
        bf16x8 af[4], bfr[4];
        #pragma unroll
        for (int mi = 0; mi < 4; mi++) af[mi] = *(const bf16x8*)&sA[(wr * 64 + mi * 16 + lo) * 40 + hi * 8];
        #pragma unroll
        for (int ni = 0; ni < 4; ni++) bfr[ni] = *(const bf16x8*)&sB[(wc * 64 + ni * 16 + lo) * 40 + hi * 8];
        #pragma unroll
        for (int mi = 0; mi < 4; mi++)
            #pragma unroll
            for (int ni = 0; ni < 4; ni++)
                acc[mi][ni] = __builtin_amdgcn_mfma_f32_16x16x32_bf16(af[mi], bfr[ni], acc[mi][ni], 0, 0, 0);
    }
}

// ---------------- plain GEMM (BM=128, BN=128) ----------------
__global__ __launch_bounds__(256) void gemm_plain(
    const float* __restrict__ A, const float* __restrict__ W, float* __restrict__ C,
    int M, int K, int Nc,
    const float* __restrict__ bias, const float* __restrict__ addp, int do_gelu) {
    __shared__ __align__(16) ushort sA[128 * 40];
    __shared__ __align__(16) ushort sB[128 * 40];
    int row0 = blockIdx.y * 128, col0 = blockIdx.x * 128;
    int tid = threadIdx.x;
    const f32x4 zz = {0.f, 0.f, 0.f, 0.f};
    f32x4 acc[4][4] = {{zz, zz, zz, zz}, {zz, zz, zz, zz}, {zz, zz, zz, zz}, {zz, zz, zz, zz}};
    gemm_core(A, W, K, Nc, row0, col0, tid, sA, sB, acc);
    int wid = tid >> 6, lane = tid & 63, lo = lane & 15, hi = lane >> 4;
    int wr = wid >> 1, wc = wid & 1;
    #pragma unroll
    for (int ni = 0; ni < 4; ni++) {
        int col = col0 + wc * 64 + ni * 16 + lo;
        float bc = bias ? bias[col] : 0.f;
        #pragma unroll
        for (int mi = 0; mi < 4; mi++) {
            #pragma unroll
            for (int r = 0; r < 4; r++) {
                int row = row0 + wr * 64 + mi * 16 + hi * 4 + r;
                float v = acc[mi][ni][r] + bc;
                if (do_gelu) v = gelu_f(v);
                if (addp) v += addp[(size_t)row * Nc + col];
                C[(size_t)row * Nc + col] = v;
            }
        }
    }
}

// ---------------- narrow GEMM (BM=128, BN=64) for Nc=256 outputs ----------------
__global__ __launch_bounds__(256) void gemm_n64(
    const float* __restrict__ A, const float* __restrict__ W, float* __restrict__ C,
    int M, int K, int Nc,
    const float* __restrict__ bias, const float* __restrict__ addp, int do_gelu) {
    __shared__ __align__(16) ushort sA[128 * 40];
    __shared__ __align__(16) ushort sB[64 * 40];
    int row0 = blockIdx.y * 128, col0 = blockIdx.x * 64;
    int tid = threadIdx.x;
    int wid = tid >> 6, lane = tid & 63, lo = lane & 15, hi = lane >> 4;
    int wr = wid >> 1, wc = wid & 1;
    int ar = tid >> 1, akh = (tid & 1) * 16;
    int bcol = tid & 63, bks = (tid >> 6) * 8;
    const f32x4 zz = {0.f, 0.f, 0.f, 0.f};
    f32x4 acc[4][2] = {{zz, zz}, {zz, zz}, {zz, zz}, {zz, zz}};
    for (int kt = 0; kt < K; kt += 32) {
        const float* ap = &A[(size_t)(row0 + ar) * K + kt + akh];
        float4 a0 = *(const float4*)(ap + 0);
        float4 a1 = *(const float4*)(ap + 4);
        float4 a2 = *(const float4*)(ap + 8);
        float4 a3 = *(const float4*)(ap + 12);
        float wv[8];
        #pragma unroll
        for (int i = 0; i < 8; i++) wv[i] = W[(size_t)(kt + bks + i) * Nc + col0 + bcol];
        __syncthreads();
        *(uint4*)&sA[ar * 40 + akh] = make_uint4(pk2(a0.x, a0.y), pk2(a0.z, a0.w), pk2(a1.x, a1.y), pk2(a1.z, a1.w));
        *(uint4*)&sA[ar * 40 + akh + 8] = make_uint4(pk2(a2.x, a2.y), pk2(a2.z, a2.w), pk2(a3.x, a3.y), pk2(a3.z, a3.w));
        *(uint2*)&sB[bcol * 40 + bks] = make_uint2(pk2(wv[0], wv[1]), pk2(wv[2], wv[3]));
        *(uint2*)&sB[bcol * 40 + bks + 4] = make_uint2(pk2(wv[4], wv[5]), pk2(wv[6], wv[7]));
        __syncthreads();
        bf16x8 af[4], bfr[2];
        #pragma unroll
        for (int mi = 0; mi < 4; mi++) af[mi] = *(const bf16x8*)&sA[(wr * 64 + mi * 16 + lo) * 40 + hi * 8];
        #pragma unroll
        for (int ni = 0; ni < 2; ni++) bfr[ni] = *(const bf16x8*)&sB[(wc * 32 + ni * 16 + lo) * 40 + hi * 8];
        #pragma unroll
        for (int mi = 0; mi < 4; mi++)
            #pragma unroll
            for (int ni = 0; ni < 2; ni++)
                acc[mi][ni] = __builtin_amdgcn_mfma_f32_16x16x32_bf16(af[mi], bfr[ni], acc[mi][ni], 0, 0, 0);
    }
    #pragma unroll
    for (int ni = 0; ni < 2; ni++) {
        int col = col0 + wc * 32 + ni * 16 + lo;
        float bc = bias ? bias[col] : 0.f;
        #pragma unroll
        for (int mi = 0; mi < 4; mi++) {
            #pragma unroll
            for (int r = 0; r < 4; r++) {
                int row = row0 + wr * 64 + mi * 16 + hi * 4 + r;
                float v = acc[mi][ni][r] + bc;
                if (do_gelu) v = gelu_f(v);
                if (addp) v += addp[(size_t)row * Nc + col];
                C[(size_t)row * Nc + col] = v;
            }
        }
    }
}

// ---------------- fused QKV GEMM: q fp32, k/v bf16 ----------------
__global__ __launch_bounds__(256) void gemm_qkv(
    const float* __restrict__ A, const float* __restrict__ wq, const float* __restrict__ wk,
    const float* __restrict__ wvp, float* __restrict__ qb, ushort* __restrict__ kb,
    ushort* __restrict__ vb, int K) {
    __shared__ __align__(16) ushort sA[128 * 40];
    __shared__ __align__(16) ushort sB[128 * 40];
    int row0 = blockIdx.y * 128, col0 = blockIdx.x * 128;
    int wsel = col0 >> 8, colW0 = col0 & 255;
    const float* W = (wsel == 0) ? wq : (wsel == 1) ? wk : wvp;
    int tid = threadIdx.x;
    const f32x4 zz = {0.f, 0.f, 0.f, 0.f};
    f32x4 acc[4][4] = {{zz, zz, zz, zz}, {zz, zz, zz, zz}, {zz, zz, zz, zz}, {zz, zz, zz, zz}};
    gemm_core(A, W, K, 256, row0, colW0, tid, sA, sB, acc);
    int wid = tid >> 6, lane = tid & 63, lo = lane & 15, hi = lane >> 4;
    int wr = wid >> 1, wc = wid & 1;
    #pragma unroll
    for (int ni = 0; ni < 4; ni++) {
        int colW = colW0 + wc * 64 + ni * 16 + lo;
        #pragma unroll
        for (int mi = 0; mi < 4; mi++) {
            #pragma unroll
            for (int r = 0; r < 4; r++) {
                int row = row0 + wr * 64 + mi * 16 + hi * 4 + r;
                float v = acc[mi][ni][r];
                if (wsel == 0) qb[(size_t)row * 256 + colW] = v;
                else if (wsel == 1) kb[(size_t)row * 256 + colW] = f2bf(v);
                else vb[(size_t)row * 256 + colW] = f2bf(v);
            }
        }
    }
}

// ---------------- fused FFN GEMM: up (no gelu) + lg/cg/bg (gelu) ----------------
__global__ __launch_bounds__(256) void gemm_ffn(
    const float* __restrict__ A,
    const float* __restrict__ w0, const float* __restrict__ w1,
    const float* __restrict__ w2, const float* __restrict__ w3,
    float* __restrict__ o0, float* __restrict__ o1,
    float* __restrict__ o2, float* __restrict__ o3, int K) {
    __shared__ __align__(16) ushort sA[128 * 40];
    __shared__ __align__(16) ushort sB[128 * 40];
    int row0 = blockIdx.y * 128, col0 = blockIdx.x * 128;
    int wsel = col0 >> 9, colW0 = col0 & 511;
    const float* W = (wsel == 0) ? w0 : (wsel == 1) ? w1 : (wsel == 2) ? w2 : w3;
    float* O = (wsel == 0) ? o0 : (wsel == 1) ? o1 : (wsel == 2) ? o2 : o3;
    int tid = threadIdx.x;
    const f32x4 zz = {0.f, 0.f, 0.f, 0.f};
    f32x4 acc[4][4] = {{zz, zz, zz, zz}, {zz, zz, zz, zz}, {zz, zz, zz, zz}, {zz, zz, zz, zz}};
    gemm_core(A, W, K, 512, row0, colW0, tid, sA, sB, acc);
    int wid = tid >> 6, lane = tid & 63, lo = lane & 15, hi = lane >> 4;
    int wr = wid >> 1, wc = wid & 1;
    #pragma unroll
    for (int ni = 0; ni < 4; ni++) {
        int colW = colW0 + wc * 64 + ni * 16 + lo;
        #pragma unroll
        for (int mi = 0; mi < 4; mi++) {
            #pragma unroll
            for (int r = 0; r < 4; r++) {
                int row = row0 + wr * 64 + mi * 16 + hi * 4 + r;
                float v = acc[mi][ni][r];
                if (wsel > 0) v = gelu_f(v);
                O[(size_t)row * 512 + colW] = v;
            }
        }
    }
}

// ---------------- attention: QK direct-gather + V staged through LDS ----------------
__global__ __launch_bounds__(256) void attn_kernel(
    const float* __restrict__ q, const ushort* __restrict__ kp, const ushort* __restrict__ vp,
    const float* __restrict__ bias, const int* __restrict__ nbr, float* __restrict__ o) {
    int n = blockIdx.x;
    __shared__ float qs[256];
    __shared__ int js[32];
    __shared__ float ls[256];                  // [h][k]
    __shared__ __align__(16) uint4 vs[32 * 33]; // 32 v-rows, +1 uint4 pad
    int t = threadIdx.x;
    qs[t] = q[(size_t)n * 256 + t];
    if (t < 32) js[t] = nbr[n * 32 + t];
    __syncthreads();
    // stage V gathers into registers early (latency hides under QK)
    int vrow = t >> 3, vseg = t & 7;
    const uint4* vsrc = (const uint4*)(vp + (size_t)js[vrow] * 256);
    uint4 vr0 = vsrc[vseg * 4 + 0];
    uint4 vr1 = vsrc[vseg * 4 + 1];
    uint4 vr2 = vsrc[vseg * 4 + 2];
    uint4 vr3 = vsrc[vseg * 4 + 3];
    // QK: thread (h,k)
    int h = t >> 5, k = t & 31;
    int j = js[k];
    const bf16x8* kr = (const bf16x8*)(kp + (size_t)j * 256 + h * 32);
    bf16x8 kv0 = kr[0], kv1 = kr[1], kv2 = kr[2], kv3 = kr[3];
    const float* qh = qs + h * 32;
    float dot = 0.f;
    #pragma unroll
    for (int i = 0; i < 8; i++) dot += qh[i] * bf2f((ushort)kv0[i]);
    #pragma unroll
    for (int i = 0; i < 8; i++) dot += qh[8 + i] * bf2f((ushort)kv1[i]);
    #pragma unroll
    for (int i = 0; i < 8; i++) dot += qh[16 + i] * bf2f((ushort)kv2[i]);
    #pragma unroll
    for (int i = 0; i < 8; i++) dot += qh[24 + i] * bf2f((ushort)kv3[i]);
    float l = dot * 0.17677669529663687f + bias[(size_t)n * 256 + t];
    float mx = l;
    #pragma unroll
    for (int m = 16; m > 0; m >>= 1) mx = fmaxf(mx, __shfl_xor(mx, m));
    float e = __expf(l - mx);
    float sum = e;
    #pragma unroll
    for (int m = 16; m > 0; m >>= 1) sum += __shfl_xor(sum, m);
    ls[t] = e / sum;
    // commit V to LDS
    vs[vrow * 33 + vseg * 4 + 0] = vr0;
    vs[vrow * 33 + vseg * 4 + 1] = vr1;
    vs[vrow * 33 + vseg * 4 + 2] = vr2;
    vs[vrow * 33 + vseg * 4 + 3] = vr3;
    __syncthreads();
    // PV: thread (h,d) — ls broadcast + conflict-free u16 reads
    const ushort* vsu = (const ushort*)vs;
    const float* lh = ls + h * 32;
    float acc = 0.f;
    #pragma unroll
    for (int kk = 0; kk < 32; kk++)
        acc += lh[kk] * bf2f(vsu[kk * 264 + h * 32 + k]);
    o[(size_t)n * 256 + t] = acc;
}

// ---------------- LN(a+b) with sum output ----------------
__global__ __launch_bounds__(256) void ln_add_kernel(
    const float* __restrict__ a, const float* __restrict__ b,
    const float* __restrict__ g, const float* __restrict__ be,
    float* __restrict__ xout, float* __restrict__ sout) {
    int row = blockIdx.x * 4 + (threadIdx.x >> 6);
    int lane = threadIdx.x & 63;
    size_t base = (size_t)row * 256 + lane * 4;
    float4 av = *(const float4*)(a + base);
    float4 bv = *(const float4*)(b + base);
    float s0 = av.x + bv.x, s1 = av.y + bv.y, s2 = av.z + bv.z, s3 = av.w + bv.w;
    float sum = wave_sum64(s0 + s1 + s2 + s3);
    float mean = sum * (1.f / 256.f);
    float d0 = s0 - mean, d1 = s1 - mean, d2 = s2 - mean, d3 = s3 - mean;
    float v = wave_sum64(d0 * d0 + d1 * d1 + d2 * d2 + d3 * d3);
    float rs = rsqrtf(v * (1.f / 256.f) + 1e-5f);
    float4 gv = *(const float4*)(g + lane * 4);
    float4 bev = *(const float4*)(be + lane * 4);
    float4 xo;
    xo.x = d0 * rs * gv.x + bev.x;
    xo.y = d1 * rs * gv.y + bev.y;
    xo.z = d2 * rs * gv.z + bev.z;
    xo.w = d3 * rs * gv.w + bev.w;
    *(float4*)(xout + base) = xo;
    float4 so; so.x = s0; so.y = s1; so.z = s2; so.w = s3;
    *(float4*)(sout + base) = so;
}

// ---------------- segment means ----------------
__device__ __forceinline__ int lower_bound_i(const int* a, int n, int v) {
    int lo = 0, hi = n;
    while (lo < hi) { int mid = (lo + hi) >> 1; if (a[mid] < v) lo = mid + 1; else hi = mid; }
    return lo;
}

__global__ __launch_bounds__(256) void seg_mean_kernel(
    const float* __restrict__ up, const int* __restrict__ batch, const int* __restrict__ chain,
    float* __restrict__ mb, float* __restrict__ mc) {
    int b = blockIdx.x;
    const int* arr;
    float* outp;
    int seg;
    if (b < NBATCH) { arr = batch; outp = mb; seg = b; }
    else { arr = chain; outp = mc; seg = b - NBATCH; }
    int lo = lower_bound_i(arr, NN, seg);
    int hi = lower_bound_i(arr, NN, seg + 1);
    int t = threadIdx.x;
    float a0 = 0.f, a1 = 0.f;
    for (int r = lo; r < hi; r++) {
        a0 += up[(size_t)r * 512 + t];
        a1 += up[(size_t)r * 512 + 256 + t];
    }
    float inv = 1.f / fmaxf((float)(hi - lo), 1.f);
    outp[seg * 512 + t] = a0 * inv;
    outp[seg * 512 + 256 + t] = a1 * inv;
}

// ---------------- hidden combine ----------------
__global__ __launch_bounds__(256) void hidden_kernel(
    const float* __restrict__ up, const float* __restrict__ cg, const float* __restrict__ bg,
    float* __restrict__ lg, const float* __restrict__ mb, const float* __restrict__ mc,
    const int* __restrict__ batch, const int* __restrict__ chain) {
    size_t idx = (size_t)blockIdx.x * 256 + threadIdx.x;
    int n = idx >> 9, d = idx & 511;
    float h = bg[idx] * mb[batch[n] * 512 + d] + cg[idx] * mc[chain[n] * 512 + d] + lg[idx] * up[idx];
    lg[idx] = h;
}

// ---------------- final ----------------
__global__ __launch_bounds__(256) void final_kernel(
    const float* __restrict__ x1, const float* __restrict__ y2, const float* __restrict__ inc1,
    const float* __restrict__ ug, const float* __restrict__ ub,
    const float* __restrict__ fg, const float* __restrict__ fb, float* __restrict__ out) {
    int row = blockIdx.x * 4 + (threadIdx.x >> 6);
    int lane = threadIdx.x & 63;
    size_t base = (size_t)row * 256 + lane * 4;
    float4 xv = *(const float4*)(x1 + base);
    float4 yv = *(const float4*)(y2 + base);
    float4 iv = *(const float4*)(inc1 + base);
    float s0 = xv.x + yv.x, s1 = xv.y + yv.y, s2 = xv.z + yv.z, s3 = xv.w + yv.w;
    float t0 = iv.x + yv.x, t1 = iv.y + yv.y, t2 = iv.z + yv.z, t3 = iv.w + yv.w;
    float sums = wave_sum64(s0 + s1 + s2 + s3);
    float means = sums * (1.f / 256.f);
    float sd0 = s0 - means, sd1 = s1 - means, sd2 = s2 - means, sd3 = s3 - means;
    float vs = wave_sum64(sd0 * sd0 + sd1 * sd1 + sd2 * sd2 + sd3 * sd3);
    float rss = rsqrtf(vs * (1.f / 256.f) + 1e-5f);
    float sumt = wave_sum64(t0 + t1 + t2 + t3);
    float meant = sumt * (1.f / 256.f);
    float td0 = t0 - meant, td1 = t1 - meant, td2 = t2 - meant, td3 = t3 - meant;
    float vt = wave_sum64(td0 * td0 + td1 * td1 + td2 * td2 + td3 * td3);
    float rst = rsqrtf(vt * (1.f / 256.f) + 1e-5f);
    float4 ugv = *(const float4*)(ug + lane * 4);
    float4 ubv = *(const float4*)(ub + lane * 4);
    float4 fgv = *(const float4*)(fg + lane * 4);
    float4 fbv = *(const float4*)(fb + lane * 4);
    float4 ov;
    ov.x = (sd0 * rss * ugv.x + ubv.x) + (td0 * rst * fgv.x + fbv.x);
    ov.y = (sd1 * rss * ugv.y + ubv.y) + (td1 * rst * fgv.y + fbv.y);
    ov.z = (sd2 * rss * ugv.z + ubv.z) + (td2 * rst * fgv.z + fbv.z);
    ov.w = (sd3 * rss * ugv.w + ubv.w) + (td3 * rst * fgv.w + fbv.w);
    *(float4*)(out + base) = ov;
}

// ---------------- launch ----------------
extern "C" void kernel_launch(void* const* d_in, const int* in_sizes, int n_in,
                              void* d_out, int out_size, void* d_ws, size_t ws_size,
                              hipStream_t stream) {
    const float* local    = (const float*)d_in[0];
    const float* pos      = (const float*)d_in[1];
    const int*   nbr      = (const int*)d_in[2];
    const int*   resi     = (const int*)d_in[3];
    const int*   chain    = (const int*)d_in[4];
    const int*   batch    = (const int*)d_in[5];
    const float* w_relpos = (const float*)d_in[7];
    const float* w_dist   = (const float*)d_in[8];
    const float* w_dir    = (const float*)d_in[9];
    const float* w_rot    = (const float*)d_in[10];
    const float* ln_pair_g = (const float*)d_in[11];
    const float* ln_pair_b = (const float*)d_in[12];
    const float* w_p1     = (const float*)d_in[13];
    const float* b_p1     = (const float*)d_in[14];
    const float* w_p2     = (const float*)d_in[15];
    const float* b_p2     = (const float*)d_in[16];
    const float* wq       = (const float*)d_in[17];
    const float* wk       = (const float*)d_in[18];
    const float* wv       = (const float*)d_in[19];
    const float* wb       = (const float*)d_in[20];
    const float* wo       = (const float*)d_in[21];
    const float* ln_a_g   = (const float*)d_in[22];
    const float* ln_a_b   = (const float*)d_in[23];
    const float* w_t1     = (const float*)d_in[24];
    const float* w_t2     = (const float*)d_in[25];
    const float* w_up     = (const float*)d_in[26];
    const float* w_lg     = (const float*)d_in[27];
    const float* w_cg     = (const float*)d_in[28];
    const float* w_bg     = (const float*)d_in[29];
    const float* w_out    = (const float*)d_in[30];
    const float* b_out    = (const float*)d_in[31];
    const float* ln_u_g   = (const float*)d_in[32];
    const float* ln_u_b   = (const float*)d_in[33];
    const float* ln_f_g   = (const float*)d_in[34];
    const float* ln_f_b   = (const float*)d_in[35];

    float* ws = (float*)d_ws;
    float* R         = ws + 0;             // 9N -> 73728
    float* biasb     = ws + 73728;         // N*256 -> 2170880
    float* tfeat_out = ws + 2170880;       // N*256 -> 4268032
    float* x1        = ws + 4268032;       // N*256 -> 6365184
    float* inc1      = ws + 6365184;       // N*256 -> 8462336
    ushort* featb    = (ushort*)(ws + 8462336);  // N*K*64 bf16 (phase 1; becomes pln in-place)
    int* relidx      = (int*)(ws + 16850944);    // N*K
    float* tfeat_raw = ws + 17113088;      // N*608 (phase 1)
    float* tmp512    = ws + 22093824;      // N*512 (phase 1)
    float* qb        = ws + 8462336;       // N*256 fp32 (phase 2, over featb)
    ushort* kbu      = (ushort*)(ws + 10559488); // N*256 bf16
    ushort* vbu      = (ushort*)(ws + 12656640); // N*256 bf16
    float* ob        = ws + 14753792;      // N*256
    float* yb        = ws + 22093824;      // N*256 (over tmp512 after t2)
    float* upb       = ws + 8462336;       // N*512 (phase 3)
    float* lgb       = ws + 12656640;      // N*512
    float* cgb       = ws + 17113088;      // N*512
    float* bgb       = ws + 21307392;      // N*512
    float* mb        = ws + 25501696;      // 32*512 (phase 3)
    float* mc        = ws + 25518080;      // 64*512 (phase 3)
    float* y2        = ws + 25550848;      // N*256
    float* w2b       = ws + 25501696;      // 128*8 (phase 1; overlaps mb, used before it)
    float* b2b       = ws + 25502720;      // 8

    frames_kernel<<<NN / 256, 256, 0, stream>>>(pos, R);
    w2b_kernel<<<4, 256, 0, stream>>>(w_p2, b_p2, wb, w2b, b2b);
    pair_raw_kernel<<<NN * KK / 256, 256, 0, stream>>>(pos, nbr, resi, chain, R,
                                                       featb, relidx, tfeat_raw);
    pair_pre_kernel<<<1024, 256, 0, stream>>>(featb, relidx, w_relpos, w_dist, w_dir, w_rot,
                                              ln_pair_g, ln_pair_b);
    pair_mlp2_kernel<<<1024, 256, 0, stream>>>(featb, w_p1, b_p1, w2b, b2b, biasb);
    // tfeat MLP
    gemm_plain<<<dim3(4, 64), 256, 0, stream>>>(tfeat_raw, w_t1, tmp512, NN, 608, 512, nullptr, nullptr, 1);
    gemm_n64<<<dim3(4, 64), 256, 0, stream>>>(tmp512, w_t2, tfeat_out, NN, 512, 256, nullptr, nullptr, 0);
    // fused qkv projection (q fp32, k/v bf16)
    gemm_qkv<<<dim3(6, 64), 256, 0, stream>>>(local, wq, wk, wv, qb, kbu, vbu, 256);
    attn_kernel<<<NN, 256, 0, stream>>>(qb, kbu, vbu, biasb, nbr, ob);
    gemm_n64<<<dim3(4, 64), 256, 0, stream>>>(ob, wo, yb, NN, 256, 256, nullptr, nullptr, 0);
    ln_add_kernel<<<NN / 4, 256, 0, stream>>>(local, yb, ln_a_g, ln_a_b, x1, inc1);
    // fused FFN projections
    gemm_ffn<<<dim3(16, 64), 256, 0, stream>>>(x1, w_up, w_lg, w_cg, w_bg,
                                               upb, lgb, cgb, bgb, 256);
    seg_mean_kernel<<<NBATCH + NCHAIN, 256, 0, stream>>>(upb, batch, chain, mb, mc);
    hidden_kernel<<<NN * 512 / 256, 256, 0, stream>>>(upb, cgb, bgb, lgb, mb, mc, batch, chain);
    gemm_n64<<<dim3(4, 64), 256, 0, stream>>>(lgb, w_out, y2, NN, 512, 256, b_out, tfeat_out, 0);
    final_kernel<<<NN / 4, 256, 0, stream>>>(x1, y2, inc1, ln_u_g, ln_u_b, ln_f_g, ln_f_b, (float*)d_out);
}

// Round 9
// 322.300 us; speedup vs baseline: 1.2418x; 1.1683x over previous
//
#include <hip/hip_runtime.h>
#include <math.h>

#define NN 8192
#define KK 32
#define DD 256
#define PP 64
#define HH 8
#define DHH 32
#define NBATCH 32
#define NCHAIN 64

typedef __attribute__((ext_vector_type(8))) short bf16x8;
typedef __attribute__((ext_vector_type(4))) float f32x4;

// ---------------- helpers ----------------
__device__ __forceinline__ float gelu_f(float x) {
    float x3 = x * x * x;
    float z = 0.7978845608028654f * (x + 0.044715f * x3);
    z = fminf(fmaxf(z, -15.f), 15.f);
    float e = __expf(2.f * z);
    float t = (e - 1.f) / (e + 1.f);
    return 0.5f * x * (1.f + t);
}

__device__ __forceinline__ float wave_sum64(float v) {
    #pragma unroll
    for (int m = 32; m > 0; m >>= 1) v += __shfl_xor(v, m);
    return v;
}

__device__ __forceinline__ ushort f2bf(float x) {
    union { float f; unsigned int u; } v; v.f = x;
    unsigned int r = v.u + 0x7fffu + ((v.u >> 16) & 1u);
    return (ushort)(r >> 16);
}

__device__ __forceinline__ float bf2f(ushort u) {
    union { unsigned int u; float f; } v; v.u = ((unsigned int)u) << 16;
    return v.f;
}

__device__ __forceinline__ uint pk2(float a, float b) {
    return (uint)f2bf(a) | ((uint)f2bf(b) << 16);
}

// ---------------- frames ----------------
__global__ __launch_bounds__(256) void frames_kernel(const float* __restrict__ pos,
                                                     float* __restrict__ R) {
    int n = blockIdx.x * 256 + threadIdx.x;
    if (n >= NN) return;
    const float* p = pos + n * 15;
    float nx = p[0], ny = p[1], nz = p[2];
    float cax = p[3], cay = p[4], caz = p[5];
    float cx = p[6], cy = p[7], cz = p[8];
    float e1x = cx - cax, e1y = cy - cay, e1z = cz - caz;
    float inv = rsqrtf(e1x * e1x + e1y * e1y + e1z * e1z + 1e-8f);
    e1x *= inv; e1y *= inv; e1z *= inv;
    float ux = nx - cax, uy = ny - cay, uz = nz - caz;
    float dt = ux * e1x + uy * e1y + uz * e1z;
    float e2x = ux - dt * e1x, e2y = uy - dt * e1y, e2z = uz - dt * e1z;
    inv = rsqrtf(e2x * e2x + e2y * e2y + e2z * e2z + 1e-8f);
    e2x *= inv; e2y *= inv; e2z *= inv;
    float e3x = e1y * e2z - e1z * e2y;
    float e3y = e1z * e2x - e1x * e2z;
    float e3z = e1x * e2y - e1y * e2x;
    float* r = R + n * 9;
    r[0] = e1x; r[1] = e2x; r[2] = e3x;
    r[3] = e1y; r[4] = e2y; r[5] = e3y;
    r[6] = e1z; r[7] = e2z; r[8] = e3z;
}

// ---------------- raw pair features (lane = one (n,k) pair) ----------------
__global__ __launch_bounds__(256) void pair_raw_kernel(
    const float* __restrict__ pos, const int* __restrict__ nbr,
    const int* __restrict__ resi, const int* __restrict__ chain,
    const float* __restrict__ R,
    ushort* __restrict__ feat, int* __restrict__ relidx, float* __restrict__ tfeat_raw) {
    int p = blockIdx.x * 256 + threadIdx.x;
    int n = p >> 5, k = p & 31;
    int j = nbr[p];
    int same = (chain[j] == chain[n]);
    int off = min(max(resi[j] - resi[n], -32), 32) + 32;
    relidx[p] = same ? off : -1;

    float can0 = pos[n * 15 + 3], can1 = pos[n * 15 + 4], can2 = pos[n * 15 + 5];
    float cbn0 = pos[n * 15 + 12], cbn1 = pos[n * 15 + 13], cbn2 = pos[n * 15 + 14];
    float Rn[9], Rj[9];
    #pragma unroll
    for (int i = 0; i < 9; i++) Rn[i] = R[n * 9 + i];
    #pragma unroll
    for (int i = 0; i < 9; i++) Rj[i] = R[j * 9 + i];
    float pj[15];
    #pragma unroll
    for (int i = 0; i < 15; i++) pj[i] = pos[j * 15 + i];

    float fe[43];
    float d0 = pj[12] - cbn0, d1 = pj[13] - cbn1, d2 = pj[14] - cbn2;
    float dcb = sqrtf(d0 * d0 + d1 * d1 + d2 * d2 + 1e-8f);
    #pragma unroll
    for (int i = 0; i < 16; i++) {
        float c = (22.f / 15.f) * (float)i;
        float z = (dcb - c) * (1.f / 1.375f);
        fe[i] = __expf(-z * z);
    }
    #pragma unroll
    for (int a = 0; a < 5; a++) {
        float vx = pj[a * 3 + 0] - can0;
        float vy = pj[a * 3 + 1] - can1;
        float vz = pj[a * 3 + 2] - can2;
        float invv = rsqrtf(vx * vx + vy * vy + vz * vz + 1e-8f);
        fe[16 + a * 3 + 0] = vx * invv;
        fe[16 + a * 3 + 1] = vy * invv;
        fe[16 + a * 3 + 2] = vz * invv;
    }
    #pragma unroll
    for (int b = 0; b < 3; b++)
        #pragma unroll
        for (int c2 = 0; c2 < 3; c2++)
            fe[31 + b * 3 + c2] = Rn[0 + b] * Rj[0 + c2] + Rn[3 + b] * Rj[3 + c2] + Rn[6 + b] * Rj[6 + c2];
    float t0 = pj[3] - can0, t1 = pj[4] - can1, t2 = pj[5] - can2;
    #pragma unroll
    for (int b = 0; b < 3; b++)
        fe[40 + b] = Rn[0 + b] * t0 + Rn[3 + b] * t1 + Rn[6 + b] * t2;

    #pragma unroll
    for (int q = 0; q < 8; q++) {
        uint4 w;
        float v0 = (q * 8 + 0 < 43) ? fe[q * 8 + 0] : 0.f;
        float v1 = (q * 8 + 1 < 43) ? fe[q * 8 + 1] : 0.f;
        float v2 = (q * 8 + 2 < 43) ? fe[q * 8 + 2] : 0.f;
        float v3 = (q * 8 + 3 < 43) ? fe[q * 8 + 3] : 0.f;
        float v4 = (q * 8 + 4 < 43) ? fe[q * 8 + 4] : 0.f;
        float v5 = (q * 8 + 5 < 43) ? fe[q * 8 + 5] : 0.f;
        float v6 = (q * 8 + 6 < 43) ? fe[q * 8 + 6] : 0.f;
        float v7 = (q * 8 + 7 < 43) ? fe[q * 8 + 7] : 0.f;
        w.x = pk2(v0, v1); w.y = pk2(v2, v3); w.z = pk2(v4, v5); w.w = pk2(v6, v7);
        *(uint4*)&feat[(size_t)p * 64 + q * 8] = w;
    }
    float rt0 = fe[40], rt1 = fe[41], rt2 = fe[42];
    float dr2 = rt0 * rt0 + rt1 * rt1 + rt2 * rt2 + 1e-8f;
    float invdr = rsqrtf(dr2);
    float drel = dr2 * invdr;
    float* tf = tfeat_raw + (size_t)n * 608 + k * 19;
    #pragma unroll
    for (int i = 0; i < 16; i++) {
        float c = (22.f / 15.f) * (float)i;
        float z = (drel - c) * (1.f / 1.375f);
        tf[i] = __expf(-z * z);
    }
    tf[16] = rt0 * invdr;
    tf[17] = rt1 * invdr;
    tf[18] = rt2 * invdr;
}

// ---------------- pair stage0: feat-proj MFMA + relpos + LN, in-place feat -> pln ----------------
__global__ __launch_bounds__(256) void pair_pre_kernel(
    ushort* feat, const int* __restrict__ relidx,
    const float* __restrict__ w_relpos,
    const float* __restrict__ w_dist, const float* __restrict__ w_dir,
    const float* __restrict__ w_rot,
    const float* __restrict__ lng, const float* __restrict__ lnb) {
    int tid = threadIdx.x;
    int wid = tid >> 6, lane = tid & 63, hi = lane >> 4, lo = lane & 15;
    union U8 { bf16x8 v; uint u[4]; };
    U8 wf[8];
    #pragma unroll
    for (int f = 0; f < 4; f++)
        #pragma unroll
        for (int s = 0; s < 2; s++)
            #pragma unroll
            for (int jj = 0; jj < 4; jj++) {
                int k0 = 32 * s + hi * 8 + 2 * jj;
                int c = 16 * f + lo;
                float v0 = (k0 < 16) ? w_dist[k0 * 64 + c] : (k0 < 31) ? w_dir[(k0 - 16) * 64 + c]
                         : (k0 < 43) ? w_rot[(k0 - 31) * 64 + c] : 0.f;
                int k1 = k0 + 1;
                float v1 = (k1 < 16) ? w_dist[k1 * 64 + c] : (k1 < 31) ? w_dir[(k1 - 16) * 64 + c]
                         : (k1 < 43) ? w_rot[(k1 - 31) * 64 + c] : 0.f;
                wf[f * 2 + s].u[jj] = pk2(v0, v1);
            }
    float sg_r[4][4], sbt_r[4][4];
    #pragma unroll
    for (int f = 0; f < 4; f++)
        #pragma unroll
        for (int r = 0; r < 4; r++) {
            int c = 16 * f + 4 * hi + r;
            sg_r[f][r] = lng[c];
            sbt_r[f][r] = lnb[c];
        }
    const f32x4 zz = {0.f, 0.f, 0.f, 0.f};
    for (int t = blockIdx.x * 4 + wid; t < (NN * KK / 16); t += 4096) {
        int r0 = t << 4;
        bf16x8 bp0 = *(const bf16x8*)(feat + (size_t)(r0 + lo) * 64 + hi * 8);
        bf16x8 bp1 = *(const bf16x8*)(feat + (size_t)(r0 + lo) * 64 + 32 + hi * 8);
        f32x4 a0f[4];
        #pragma unroll
        for (int f = 0; f < 4; f++) {
            a0f[f] = __builtin_amdgcn_mfma_f32_16x16x32_bf16(wf[f * 2 + 0].v, bp0, zz, 0, 0, 0);
            a0f[f] = __builtin_amdgcn_mfma_f32_16x16x32_bf16(wf[f * 2 + 1].v, bp1, a0f[f], 0, 0, 0);
        }
        int ridx = relidx[r0 + lo];
        float val[4][4];
        float part = 0.f;
        #pragma unroll
        for (int f = 0; f < 4; f++)
            #pragma unroll
            for (int r = 0; r < 4; r++) {
                int c = 16 * f + 4 * hi + r;
                float rv = (ridx >= 0) ? w_relpos[ridx * 64 + c] : 0.f;
                float v = a0f[f][r] + rv;
                val[f][r] = v;
                part += v;
            }
        part += __shfl_xor(part, 16);
        part += __shfl_xor(part, 32);
        float mean = part * (1.f / 64.f);
        float v2 = 0.f;
        #pragma unroll
        for (int f = 0; f < 4; f++)
            #pragma unroll
            for (int r = 0; r < 4; r++) {
                float dv = val[f][r] - mean;
                val[f][r] = dv;
                v2 += dv * dv;
            }
        v2 += __shfl_xor(v2, 16);
        v2 += __shfl_xor(v2, 32);
        float rs = rsqrtf(v2 * (1.f / 64.f) + 1e-5f);
        #pragma unroll
        for (int f = 0; f < 4; f++) {
            float v0 = val[f][0] * rs * sg_r[f][0] + sbt_r[f][0];
            float v1 = val[f][1] * rs * sg_r[f][1] + sbt_r[f][1];
            float v2b = val[f][2] * rs * sg_r[f][2] + sbt_r[f][2];
            float v3 = val[f][3] * rs * sg_r[f][3] + sbt_r[f][3];
            *(uint2*)(feat + (size_t)(r0 + lo) * 64 + 16 * f + 4 * hi) =
                make_uint2(pk2(v0, v1), pk2(v2b, v3));
        }
    }
}

// ---------------- W2B = w_p2 @ wb  [128x8], b2b = b_p2 @ wb [8] ----------------
__global__ __launch_bounds__(256) void w2b_kernel(
    const float* __restrict__ w_p2, const float* __restrict__ b_p2,
    const float* __restrict__ wb, float* __restrict__ w2b, float* __restrict__ b2b) {
    int idx = blockIdx.x * 256 + threadIdx.x;
    if (idx < 1024) {
        int c = idx >> 3, h = idx & 7;
        float s = 0.f;
        for (int q = 0; q < 64; q++) s += w_p2[c * 64 + q] * wb[q * 8 + h];
        w2b[idx] = s;
    }
    if (idx < 8) {
        float s = 0.f;
        for (int q = 0; q < 64; q++) s += b_p2[q] * wb[q * 8 + idx];
        b2b[idx] = s;
    }
}

// ---------------- pair MLP: pln -> 128 gelu -> @W2B -> bias; weights in VGPR ----------------
__global__ __launch_bounds__(256) void pair_mlp2_kernel(
    const ushort* __restrict__ pln,
    const float* __restrict__ w_p1, const float* __restrict__ b_p1,
    const float* __restrict__ w2b, const float* __restrict__ b2b,
    float* __restrict__ bias) {
    __shared__ __align__(16) ushort hx[4 * 2048];
    int tid = threadIdx.x;
    int wid = tid >> 6, lane = tid & 63, hi = lane >> 4, lo = lane & 15;
    union U8 { bf16x8 v; uint u[4]; };
    U8 w1f[16];
    #pragma unroll
    for (int f = 0; f < 8; f++)
        #pragma unroll
        for (int s = 0; s < 2; s++)
            #pragma unroll
            for (int jj = 0; jj < 4; jj++) {
                int k0 = 32 * s + hi * 8 + 2 * jj;
                int c = 16 * f + lo;
                w1f[f * 2 + s].u[jj] = pk2(w_p1[k0 * 128 + c], w_p1[(k0 + 1) * 128 + c]);
            }
    U8 w2f[4];
    #pragma unroll
    for (int s2 = 0; s2 < 4; s2++)
        #pragma unroll
        for (int jj = 0; jj < 4; jj++) {
            int c0 = 32 * s2 + 8 * hi + 2 * jj;
            float v0 = (lo < 8) ? w2b[c0 * 8 + lo] : 0.f;
            float v1 = (lo < 8) ? w2b[(c0 + 1) * 8 + lo] : 0.f;
            w2f[s2].u[jj] = pk2(v0, v1);
        }
    float b2b_r[4];
    #pragma unroll
    for (int r = 0; r < 4; r++) b2b_r[r] = (hi < 2) ? b2b[4 * hi + r] : 0.f;
    float sb1_r[8][4];
    #pragma unroll
    for (int f = 0; f < 8; f++)
        #pragma unroll
        for (int r = 0; r < 4; r++) sb1_r[f][r] = b_p1[16 * f + 4 * hi + r];

    ushort* hxw = &hx[wid * 2048];
    const f32x4 zz = {0.f, 0.f, 0.f, 0.f};
    for (int t = blockIdx.x * 4 + wid; t < (NN * KK / 16); t += 4096) {
        int r0 = t << 4;
        bf16x8 bh0 = *(const bf16x8*)(pln + (size_t)(r0 + lo) * 64 + hi * 8);
        bf16x8 bh1 = *(const bf16x8*)(pln + (size_t)(r0 + lo) * 64 + 32 + hi * 8);
        #pragma unroll
        for (int f = 0; f < 8; f++) {
            f32x4 acch = __builtin_amdgcn_mfma_f32_16x16x32_bf16(w1f[f * 2 + 0].v, bh0, zz, 0, 0, 0);
            acch = __builtin_amdgcn_mfma_f32_16x16x32_bf16(w1f[f * 2 + 1].v, bh1, acch, 0, 0, 0);
            int c0 = 16 * f + 4 * hi;
            float v0 = gelu_f(acch[0] + sb1_r[f][0]);
            float v1 = gelu_f(acch[1] + sb1_r[f][1]);
            float v2b = gelu_f(acch[2] + sb1_r[f][2]);
            float v3 = gelu_f(acch[3] + sb1_r[f][3]);
            int idx = (lo * 128 + c0) ^ ((lo & 7) << 3);
            *(uint2*)&hxw[idx] = make_uint2(pk2(v0, v1), pk2(v2b, v3));
        }
        f32x4 acc = zz;
        #pragma unroll
        for (int s2 = 0; s2 < 4; s2++) {
            int idx = (lo * 128 + 32 * s2 + 8 * hi) ^ ((lo & 7) << 3);
            bf16x8 bh = *(const bf16x8*)&hxw[idx];
            acc = __builtin_amdgcn_mfma_f32_16x16x32_bf16(w2f[s2].v, bh, acc, 0, 0, 0);
        }
        if (hi < 2) {
            int n = r0 >> 5, kb = (r0 & 31) + lo;
            #pragma unroll
            for (int r = 0; r < 4; r++)
                bias[(size_t)n * 256 + (4 * hi + r) * 32 + kb] = acc[r] + b2b_r[r];
        }
    }
}

// ---------------- shared bf16 GEMM core (BN=128) ----------------
__device__ __forceinline__ void gemm_core(
    const float* __restrict__ A, const float* __restrict__ W,
    int K, int WN, int row0, int colW0, int tid,
    ushort* sA, ushort* sB, f32x4 acc[4][4]) {
    int wid = tid >> 6, lane = tid & 63, lo = lane & 15, hi = lane >> 4;
    int wr = wid >> 1, wc = wid & 1;
    int ar = tid >> 1, akh = (tid & 1) * 16;
    int bcol = tid & 127, bks = (tid >> 7) * 16;
    for (int kt = 0; kt < K; kt += 32) {
        const float* ap = &A[(size_t)(row0 + ar) * K + kt + akh];
        float4 a0 = *(const float4*)(ap + 0);
        float4 a1 = *(const float4*)(ap + 4);
        float4 a2 = *(const float4*)(ap + 8);
        float4 a3 = *(const float4*)(ap + 12);
        float wv[16];
        #pragma unroll
        for (int i = 0; i < 16; i++) wv[i] = W[(size_t)(kt + bks + i) * WN + colW0 + bcol];
        __syncthreads();
        *(uint4*)&sA[ar * 40 + akh] = make_uint4(pk2(a0.x, a0.y), pk2(a0.z, a0.w), pk2(a1.x, a1.y), pk2(a1.z, a1.w));
        *(uint4*)&sA[ar * 40 + akh + 8] = make_uint4(pk2(a2.x, a2.y), pk2(a2.z, a2.w), pk2(a3.x, a3.y), pk2(a3.z, a3.w));
        *(uint4*)&sB[bcol * 40 + bks] = make_uint4(pk2(wv[0], wv[1]), pk2(wv[2], wv[3]), pk2(wv[4], wv[5]), pk2(wv[6], wv[7]));
        *(uint4*)&sB[bcol * 40 + bks + 8] = make_uint4(pk2(wv[8], wv[9]), pk2(wv[10], wv[11]), pk2(wv[12], wv[13]), pk2(wv[14], wv[15]));
        __syncthreads();
        bf16x8 af[4], bfr[4];
        #pragma unroll
        for (int mi = 0; mi < 4; mi++) af[mi] = *(const bf16x8*)&sA[(wr * 64 + mi * 16 + lo) * 40 + hi * 8];
        #pragma unroll
        for (int ni = 0; ni < 4; ni++) bfr[ni] = *(const bf16x8*)&sB[(wc * 64 + ni * 16 + lo) * 40 + hi * 8];
        #pragma unroll
        for (int mi = 0; mi < 4; mi++)
            #pragma unroll
            for (int ni = 0; ni < 4; ni++)
                acc[mi][ni] = __builtin_amdgcn_mfma_f32_16x16x32_bf16(af[mi], bfr[ni], acc[mi][ni], 0, 0, 0);
    }
}

// ---------------- plain GEMM (BM=128, BN=128) ----------------
__global__ __launch_bounds__(256) void gemm_plain(
    const float* __restrict__ A, const float* __restrict__ W, float* __restrict__ C,
    int M, int K, int Nc,
    const float* __restrict__ bias, const float* __restrict__ addp, int do_gelu) {
    __shared__ __align__(16) ushort sA[128 * 40];
    __shared__ __align__(16) ushort sB[128 * 40];
    int row0 = blockIdx.y * 128, col0 = blockIdx.x * 128;
    int tid = threadIdx.x;
    const f32x4 zz = {0.f, 0.f, 0.f, 0.f};
    f32x4 acc[4][4] = {{zz, zz, zz, zz}, {zz, zz, zz, zz}, {zz, zz, zz, zz}, {zz, zz, zz, zz}};
    gemm_core(A, W, K, Nc, row0, col0, tid, sA, sB, acc);
    int wid = tid >> 6, lane = tid & 63, lo = lane & 15, hi = lane >> 4;
    int wr = wid >> 1, wc = wid & 1;
    #pragma unroll
    for (int ni = 0; ni < 4; ni++) {
        int col = col0 + wc * 64 + ni * 16 + lo;
        float bc = bias ? bias[col] : 0.f;
        #pragma unroll
        for (int mi = 0; mi < 4; mi++) {
            #pragma unroll
            for (int r = 0; r < 4; r++) {
                int row = row0 + wr * 64 + mi * 16 + hi * 4 + r;
                float v = acc[mi][ni][r] + bc;
                if (do_gelu) v = gelu_f(v);
                if (addp) v += addp[(size_t)row * Nc + col];
                C[(size_t)row * Nc + col] = v;
            }
        }
    }
}

// ---------------- narrow GEMM (BM=128, BN=64) for Nc=256 outputs ----------------
__global__ __launch_bounds__(256) void gemm_n64(
    const float* __restrict__ A, const float* __restrict__ W, float* __restrict__ C,
    int M, int K, int Nc,
    const float* __restrict__ bias, const float* __restrict__ addp, int do_gelu) {
    __shared__ __align__(16) ushort sA[128 * 40];
    __shared__ __align__(16) ushort sB[64 * 40];
    int row0 = blockIdx.y * 128, col0 = blockIdx.x * 64;
    int tid = threadIdx.x;
    int wid = tid >> 6, lane = tid & 63, lo = lane & 15, hi = lane >> 4;
    int wr = wid >> 1, wc = wid & 1;
    int ar = tid >> 1, akh = (tid & 1) * 16;
    int bcol = tid & 63, bks = (tid >> 6) * 8;
    const f32x4 zz = {0.f, 0.f, 0.f, 0.f};
    f32x4 acc[4][2] = {{zz, zz}, {zz, zz}, {zz, zz}, {zz, zz}};
    for (int kt = 0; kt < K; kt += 32) {
        const float* ap = &A[(size_t)(row0 + ar) * K + kt + akh];
        float4 a0 = *(const float4*)(ap + 0);
        float4 a1 = *(const float4*)(ap + 4);
        float4 a2 = *(const float4*)(ap + 8);
        float4 a3 = *(const float4*)(ap + 12);
        float wv[8];
        #pragma unroll
        for (int i = 0; i < 8; i++) wv[i] = W[(size_t)(kt + bks + i) * Nc + col0 + bcol];
        __syncthreads();
        *(uint4*)&sA[ar * 40 + akh] = make_uint4(pk2(a0.x, a0.y), pk2(a0.z, a0.w), pk2(a1.x, a1.y), pk2(a1.z, a1.w));
        *(uint4*)&sA[ar * 40 + akh + 8] = make_uint4(pk2(a2.x, a2.y), pk2(a2.z, a2.w), pk2(a3.x, a3.y), pk2(a3.z, a3.w));
        *(uint2*)&sB[bcol * 40 + bks] = make_uint2(pk2(wv[0], wv[1]), pk2(wv[2], wv[3]));
        *(uint2*)&sB[bcol * 40 + bks + 4] = make_uint2(pk2(wv[4], wv[5]), pk2(wv[6], wv[7]));
        __syncthreads();
        bf16x8 af[4], bfr[2];
        #pragma unroll
        for (int mi = 0; mi < 4; mi++) af[mi] = *(const bf16x8*)&sA[(wr * 64 + mi * 16 + lo) * 40 + hi * 8];
        #pragma unroll
        for (int ni = 0; ni < 2; ni++) bfr[ni] = *(const bf16x8*)&sB[(wc * 32 + ni * 16 + lo) * 40 + hi * 8];
        #pragma unroll
        for (int mi = 0; mi < 4; mi++)
            #pragma unroll
            for (int ni = 0; ni < 2; ni++)
                acc[mi][ni] = __builtin_amdgcn_mfma_f32_16x16x32_bf16(af[mi], bfr[ni], acc[mi][ni], 0, 0, 0);
    }
    #pragma unroll
    for (int ni = 0; ni < 2; ni++) {
        int col = col0 + wc * 32 + ni * 16 + lo;
        float bc = bias ? bias[col] : 0.f;
        #pragma unroll
        for (int mi = 0; mi < 4; mi++) {
            #pragma unroll
            for (int r = 0; r < 4; r++) {
                int row = row0 + wr * 64 + mi * 16 + hi * 4 + r;
                float v = acc[mi][ni][r] + bc;
                if (do_gelu) v = gelu_f(v);
                if (addp) v += addp[(size_t)row * Nc + col];
                C[(size_t)row * Nc + col] = v;
            }
        }
    }
}

// ---------------- fused QKV GEMM: q fp32, k/v bf16 ----------------
__global__ __launch_bounds__(256) void gemm_qkv(
    const float* __restrict__ A, const float* __restrict__ wq, const float* __restrict__ wk,
    const float* __restrict__ wvp, float* __restrict__ qb, ushort* __restrict__ kb,
    ushort* __restrict__ vb, int K) {
    __shared__ __align__(16) ushort sA[128 * 40];
    __shared__ __align__(16) ushort sB[128 * 40];
    int row0 = blockIdx.y * 128, col0 = blockIdx.x * 128;
    int wsel = col0 >> 8, colW0 = col0 & 255;
    const float* W = (wsel == 0) ? wq : (wsel == 1) ? wk : wvp;
    int tid = threadIdx.x;
    const f32x4 zz = {0.f, 0.f, 0.f, 0.f};
    f32x4 acc[4][4] = {{zz, zz, zz, zz}, {zz, zz, zz, zz}, {zz, zz, zz, zz}, {zz, zz, zz, zz}};
    gemm_core(A, W, K, 256, row0, colW0, tid, sA, sB, acc);
    int wid = tid >> 6, lane = tid & 63, lo = lane & 15, hi = lane >> 4;
    int wr = wid >> 1, wc = wid & 1;
    #pragma unroll
    for (int ni = 0; ni < 4; ni++) {
        int colW = colW0 + wc * 64 + ni * 16 + lo;
        #pragma unroll
        for (int mi = 0; mi < 4; mi++) {
            #pragma unroll
            for (int r = 0; r < 4; r++) {
                int row = row0 + wr * 64 + mi * 16 + hi * 4 + r;
                float v = acc[mi][ni][r];
                if (wsel == 0) qb[(size_t)row * 256 + colW] = v;
                else if (wsel == 1) kb[(size_t)row * 256 + colW] = f2bf(v);
                else vb[(size_t)row * 256 + colW] = f2bf(v);
            }
        }
    }
}

// ---------------- fused FFN GEMM: up (no gelu) + lg/cg/bg (gelu) ----------------
__global__ __launch_bounds__(256) void gemm_ffn(
    const float* __restrict__ A,
    const float* __restrict__ w0, const float* __restrict__ w1,
    const float* __restrict__ w2, const float* __restrict__ w3,
    float* __restrict__ o0, float* __restrict__ o1,
    float* __restrict__ o2, float* __restrict__ o3, int K) {
    __shared__ __align__(16) ushort sA[128 * 40];
    __shared__ __align__(16) ushort sB[128 * 40];
    int row0 = blockIdx.y * 128, col0 = blockIdx.x * 128;
    int wsel = col0 >> 9, colW0 = col0 & 511;
    const float* W = (wsel == 0) ? w0 : (wsel == 1) ? w1 : (wsel == 2) ? w2 : w3;
    float* O = (wsel == 0) ? o0 : (wsel == 1) ? o1 : (wsel == 2) ? o2 : o3;
    int tid = threadIdx.x;
    const f32x4 zz = {0.f, 0.f, 0.f, 0.f};
    f32x4 acc[4][4] = {{zz, zz, zz, zz}, {zz, zz, zz, zz}, {zz, zz, zz, zz}, {zz, zz, zz, zz}};
    gemm_core(A, W, K, 512, row0, colW0, tid, sA, sB, acc);
    int wid = tid >> 6, lane = tid & 63, lo = lane & 15, hi = lane >> 4;
    int wr = wid >> 1, wc = wid & 1;
    #pragma unroll
    for (int ni = 0; ni < 4; ni++) {
        int colW = colW0 + wc * 64 + ni * 16 + lo;
        #pragma unroll
        for (int mi = 0; mi < 4; mi++) {
            #pragma unroll
            for (int r = 0; r < 4; r++) {
                int row = row0 + wr * 64 + mi * 16 + hi * 4 + r;
                float v = acc[mi][ni][r];
                if (wsel > 0) v = gelu_f(v);
                O[(size_t)row * 512 + colW] = v;
            }
        }
    }
}

// ---------------- attention: QK direct-gather + V staged through LDS ----------------
__global__ __launch_bounds__(256) void attn_kernel(
    const float* __restrict__ q, const ushort* __restrict__ kp, const ushort* __restrict__ vp,
    const float* __restrict__ bias, const int* __restrict__ nbr, float* __restrict__ o) {
    int n = blockIdx.x;
    __shared__ float qs[256];
    __shared__ int js[32];
    __shared__ float ls[256];                  // [h][k]
    __shared__ __align__(16) uint4 vs[32 * 33]; // 32 v-rows, +1 uint4 pad
    int t = threadIdx.x;
    qs[t] = q[(size_t)n * 256 + t];
    if (t < 32) js[t] = nbr[n * 32 + t];
    __syncthreads();
    // stage V gathers into registers early (latency hides under QK)
    int vrow = t >> 3, vseg = t & 7;
    const uint4* vsrc = (const uint4*)(vp + (size_t)js[vrow] * 256);
    uint4 vr0 = vsrc[vseg * 4 + 0];
    uint4 vr1 = vsrc[vseg * 4 + 1];
    uint4 vr2 = vsrc[vseg * 4 + 2];
    uint4 vr3 = vsrc[vseg * 4 + 3];
    // QK: thread (h,k)
    int h = t >> 5, k = t & 31;
    int j = js[k];
    const bf16x8* kr = (const bf16x8*)(kp + (size_t)j * 256 + h * 32);
    bf16x8 kv0 = kr[0], kv1 = kr[1], kv2 = kr[2], kv3 = kr[3];
    const float* qh = qs + h * 32;
    float dot = 0.f;
    #pragma unroll
    for (int i = 0; i < 8; i++) dot += qh[i] * bf2f((ushort)kv0[i]);
    #pragma unroll
    for (int i = 0; i < 8; i++) dot += qh[8 + i] * bf2f((ushort)kv1[i]);
    #pragma unroll
    for (int i = 0; i < 8; i++) dot += qh[16 + i] * bf2f((ushort)kv2[i]);
    #pragma unroll
    for (int i = 0; i < 8; i++) dot += qh[24 + i] * bf2f((ushort)kv3[i]);
    float l = dot * 0.17677669529663687f + bias[(size_t)n * 256 + t];
    float mx = l;
    #pragma unroll
    for (int m = 16; m > 0; m >>= 1) mx = fmaxf(mx, __shfl_xor(mx, m));
    float e = __expf(l - mx);
    float sum = e;
    #pragma unroll
    for (int m = 16; m > 0; m >>= 1) sum += __shfl_xor(sum, m);
    ls[t] = e / sum;
    // commit V to LDS
    vs[vrow * 33 + vseg * 4 + 0] = vr0;
    vs[vrow * 33 + vseg * 4 + 1] = vr1;
    vs[vrow * 33 + vseg * 4 + 2] = vr2;
    vs[vrow * 33 + vseg * 4 + 3] = vr3;
    __syncthreads();
    // PV: thread (h,d) — ls broadcast + conflict-free u16 reads
    const ushort* vsu = (const ushort*)vs;
    const float* lh = ls + h * 32;
    float acc = 0.f;
    #pragma unroll
    for (int kk = 0; kk < 32; kk++)
        acc += lh[kk] * bf2f(vsu[kk * 264 + h * 32 + k]);
    o[(size_t)n * 256 + t] = acc;
}

// ---------------- LN(a+b) with sum output ----------------
__global__ __launch_bounds__(256) void ln_add_kernel(
    const float* __restrict__ a, const float* __restrict__ b,
    const float* __restrict__ g, const float* __restrict__ be,
    float* __restrict__ xout, float* __restrict__ sout) {
    int row = blockIdx.x * 4 + (threadIdx.x >> 6);
    int lane = threadIdx.x & 63;
    size_t base = (size_t)row * 256 + lane * 4;
    float4 av = *(const float4*)(a + base);
    float4 bv = *(const float4*)(b + base);
    float s0 = av.x + bv.x, s1 = av.y + bv.y, s2 = av.z + bv.z, s3 = av.w + bv.w;
    float sum = wave_sum64(s0 + s1 + s2 + s3);
    float mean = sum * (1.f / 256.f);
    float d0 = s0 - mean, d1 = s1 - mean, d2 = s2 - mean, d3 = s3 - mean;
    float v = wave_sum64(d0 * d0 + d1 * d1 + d2 * d2 + d3 * d3);
    float rs = rsqrtf(v * (1.f / 256.f) + 1e-5f);
    float4 gv = *(const float4*)(g + lane * 4);
    float4 bev = *(const float4*)(be + lane * 4);
    float4 xo;
    xo.x = d0 * rs * gv.x + bev.x;
    xo.y = d1 * rs * gv.y + bev.y;
    xo.z = d2 * rs * gv.z + bev.z;
    xo.w = d3 * rs * gv.w + bev.w;
    *(float4*)(xout + base) = xo;
    float4 so; so.x = s0; so.y = s1; so.z = s2; so.w = s3;
    *(float4*)(sout + base) = so;
}

// ---------------- segment means: phase 1 partial sums (atomic) ----------------
__global__ __launch_bounds__(256) void seg_partial_kernel(
    const float* __restrict__ up, const int* __restrict__ batch, const int* __restrict__ chain,
    float* __restrict__ mb_acc, float* __restrict__ mc_acc) {
    int r0 = blockIdx.x * 32;
    int t = threadIdx.x;
    float ab0 = 0.f, ab1 = 0.f, ac0 = 0.f, ac1 = 0.f;
    int curb = batch[r0], curc = chain[r0];
    for (int r = r0; r < r0 + 32; r++) {
        int b = batch[r], c = chain[r];
        if (b != curb) {
            atomicAdd(&mb_acc[curb * 512 + t], ab0);
            atomicAdd(&mb_acc[curb * 512 + 256 + t], ab1);
            ab0 = ab1 = 0.f; curb = b;
        }
        if (c != curc) {
            atomicAdd(&mc_acc[curc * 512 + t], ac0);
            atomicAdd(&mc_acc[curc * 512 + 256 + t], ac1);
            ac0 = ac1 = 0.f; curc = c;
        }
        float v0 = up[(size_t)r * 512 + t];
        float v1 = up[(size_t)r * 512 + 256 + t];
        ab0 += v0; ab1 += v1; ac0 += v0; ac1 += v1;
    }
    atomicAdd(&mb_acc[curb * 512 + t], ab0);
    atomicAdd(&mb_acc[curb * 512 + 256 + t], ab1);
    atomicAdd(&mc_acc[curc * 512 + t], ac0);
    atomicAdd(&mc_acc[curc * 512 + 256 + t], ac1);
}

// ---------------- segment means: phase 2 divide by counts ----------------
__device__ __forceinline__ int lower_bound_i(const int* a, int n, int v) {
    int lo = 0, hi = n;
    while (lo < hi) { int mid = (lo + hi) >> 1; if (a[mid] < v) lo = mid + 1; else hi = mid; }
    return lo;
}

__global__ __launch_bounds__(256) void seg_final_kernel(
    float* __restrict__ mb, float* __restrict__ mc,
    const int* __restrict__ batch, const int* __restrict__ chain) {
    int idx = blockIdx.x * 256 + threadIdx.x;
    if (idx < NBATCH * 512) {
        int seg = idx >> 9;
        int lo = lower_bound_i(batch, NN, seg);
        int hi = lower_bound_i(batch, NN, seg + 1);
        mb[idx] *= 1.f / fmaxf((float)(hi - lo), 1.f);
    } else {
        int i2 = idx - NBATCH * 512;
        int seg = i2 >> 9;
        int lo = lower_bound_i(chain, NN, seg);
        int hi = lower_bound_i(chain, NN, seg + 1);
        mc[i2] *= 1.f / fmaxf((float)(hi - lo), 1.f);
    }
}

// ---------------- hidden combine ----------------
__global__ __launch_bounds__(256) void hidden_kernel(
    const float* __restrict__ up, const float* __restrict__ cg, const float* __restrict__ bg,
    float* __restrict__ lg, const float* __restrict__ mb, const float* __restrict__ mc,
    const int* __restrict__ batch, const int* __restrict__ chain) {
    size_t idx = (size_t)blockIdx.x * 256 + threadIdx.x;
    int n = idx >> 9, d = idx & 511;
    float h = bg[idx] * mb[batch[n] * 512 + d] + cg[idx] * mc[chain[n] * 512 + d] + lg[idx] * up[idx];
    lg[idx] = h;
}

// ---------------- final ----------------
__global__ __launch_bounds__(256) void final_kernel(
    const float* __restrict__ x1, const float* __restrict__ y2, const float* __restrict__ inc1,
    const float* __restrict__ ug, const float* __restrict__ ub,
    const float* __restrict__ fg, const float* __restrict__ fb, float* __restrict__ out) {
    int row = blockIdx.x * 4 + (threadIdx.x >> 6);
    int lane = threadIdx.x & 63;
    size_t base = (size_t)row * 256 + lane * 4;
    float4 xv = *(const float4*)(x1 + base);
    float4 yv = *(const float4*)(y2 + base);
    float4 iv = *(const float4*)(inc1 + base);
    float s0 = xv.x + yv.x, s1 = xv.y + yv.y, s2 = xv.z + yv.z, s3 = xv.w + yv.w;
    float t0 = iv.x + yv.x, t1 = iv.y + yv.y, t2 = iv.z + yv.z, t3 = iv.w + yv.w;
    float sums = wave_sum64(s0 + s1 + s2 + s3);
    float means = sums * (1.f / 256.f);
    float sd0 = s0 - means, sd1 = s1 - means, sd2 = s2 - means, sd3 = s3 - means;
    float vs = wave_sum64(sd0 * sd0 + sd1 * sd1 + sd2 * sd2 + sd3 * sd3);
    float rss = rsqrtf(vs * (1.f / 256.f) + 1e-5f);
    float sumt = wave_sum64(t0 + t1 + t2 + t3);
    float meant = sumt * (1.f / 256.f);
    float td0 = t0 - meant, td1 = t1 - meant, td2 = t2 - meant, td3 = t3 - meant;
    float vt = wave_sum64(td0 * td0 + td1 * td1 + td2 * td2 + td3 * td3);
    float rst = rsqrtf(vt * (1.f / 256.f) + 1e-5f);
    float4 ugv = *(const float4*)(ug + lane * 4);
    float4 ubv = *(const float4*)(ub + lane * 4);
    float4 fgv = *(const float4*)(fg + lane * 4);
    float4 fbv = *(const float4*)(fb + lane * 4);
    float4 ov;
    ov.x = (sd0 * rss * ugv.x + ubv.x) + (td0 * rst * fgv.x + fbv.x);
    ov.y = (sd1 * rss * ugv.y + ubv.y) + (td1 * rst * fgv.y + fbv.y);
    ov.z = (sd2 * rss * ugv.z + ubv.z) + (td2 * rst * fgv.z + fbv.z);
    ov.w = (sd3 * rss * ugv.w + ubv.w) + (td3 * rst * fgv.w + fbv.w);
    *(float4*)(out + base) = ov;
}

// ---------------- launch ----------------
extern "C" void kernel_launch(void* const* d_in, const int* in_sizes, int n_in,
                              void* d_out, int out_size, void* d_ws, size_t ws_size,
                              hipStream_t stream) {
    const float* local    = (const float*)d_in[0];
    const float* pos      = (const float*)d_in[1];
    const int*   nbr      = (const int*)d_in[2];
    const int*   resi     = (const int*)d_in[3];
    const int*   chain    = (const int*)d_in[4];
    const int*   batch    = (const int*)d_in[5];
    const float* w_relpos = (const float*)d_in[7];
    const float* w_dist   = (const float*)d_in[8];
    const float* w_dir    = (const float*)d_in[9];
    const float* w_rot    = (const float*)d_in[10];
    const float* ln_pair_g = (const float*)d_in[11];
    const float* ln_pair_b = (const float*)d_in[12];
    const float* w_p1     = (const float*)d_in[13];
    const float* b_p1     = (const float*)d_in[14];
    const float* w_p2     = (const float*)d_in[15];
    const float* b_p2     = (const float*)d_in[16];
    const float* wq       = (const float*)d_in[17];
    const float* wk       = (const float*)d_in[18];
    const float* wv       = (const float*)d_in[19];
    const float* wb       = (const float*)d_in[20];
    const float* wo       = (const float*)d_in[21];
    const float* ln_a_g   = (const float*)d_in[22];
    const float* ln_a_b   = (const float*)d_in[23];
    const float* w_t1     = (const float*)d_in[24];
    const float* w_t2     = (const float*)d_in[25];
    const float* w_up     = (const float*)d_in[26];
    const float* w_lg     = (const float*)d_in[27];
    const float* w_cg     = (const float*)d_in[28];
    const float* w_bg     = (const float*)d_in[29];
    const float* w_out    = (const float*)d_in[30];
    const float* b_out    = (const float*)d_in[31];
    const float* ln_u_g   = (const float*)d_in[32];
    const float* ln_u_b   = (const float*)d_in[33];
    const float* ln_f_g   = (const float*)d_in[34];
    const float* ln_f_b   = (const float*)d_in[35];

    float* ws = (float*)d_ws;
    float* R         = ws + 0;             // 9N -> 73728
    float* biasb     = ws + 73728;         // N*256 -> 2170880
    float* tfeat_out = ws + 2170880;       // N*256 -> 4268032
    float* x1        = ws + 4268032;       // N*256 -> 6365184
    float* inc1      = ws + 6365184;       // N*256 -> 8462336
    ushort* featb    = (ushort*)(ws + 8462336);  // N*K*64 bf16 (phase 1; becomes pln in-place)
    int* relidx      = (int*)(ws + 16850944);    // N*K
    float* tfeat_raw = ws + 17113088;      // N*608 (phase 1)
    float* tmp512    = ws + 22093824;      // N*512 (phase 1)
    float* qb        = ws + 8462336;       // N*256 fp32 (phase 2, over featb)
    ushort* kbu      = (ushort*)(ws + 10559488); // N*256 bf16
    ushort* vbu      = (ushort*)(ws + 12656640); // N*256 bf16
    float* ob        = ws + 14753792;      // N*256
    float* yb        = ws + 22093824;      // N*256 (over tmp512 after t2)
    float* upb       = ws + 8462336;       // N*512 (phase 3)
    float* lgb       = ws + 12656640;      // N*512
    float* cgb       = ws + 17113088;      // N*512
    float* bgb       = ws + 21307392;      // N*512
    float* mb        = ws + 25501696;      // 32*512 (phase 3)
    float* mc        = ws + 25518080;      // 64*512 (phase 3)
    float* y2        = ws + 25550848;      // N*256
    float* w2b       = ws + 25501696;      // 128*8 (phase 1; overlaps mb, used before it)
    float* b2b       = ws + 25502720;      // 8

    frames_kernel<<<NN / 256, 256, 0, stream>>>(pos, R);
    w2b_kernel<<<4, 256, 0, stream>>>(w_p2, b_p2, wb, w2b, b2b);
    pair_raw_kernel<<<NN * KK / 256, 256, 0, stream>>>(pos, nbr, resi, chain, R,
                                                       featb, relidx, tfeat_raw);
    pair_pre_kernel<<<1024, 256, 0, stream>>>(featb, relidx, w_relpos, w_dist, w_dir, w_rot,
                                              ln_pair_g, ln_pair_b);
    pair_mlp2_kernel<<<1024, 256, 0, stream>>>(featb, w_p1, b_p1, w2b, b2b, biasb);
    // tfeat MLP
    gemm_plain<<<dim3(4, 64), 256, 0, stream>>>(tfeat_raw, w_t1, tmp512, NN, 608, 512, nullptr, nullptr, 1);
    gemm_n64<<<dim3(4, 64), 256, 0, stream>>>(tmp512, w_t2, tfeat_out, NN, 512, 256, nullptr, nullptr, 0);
    // fused qkv projection (q fp32, k/v bf16)
    gemm_qkv<<<dim3(6, 64), 256, 0, stream>>>(local, wq, wk, wv, qb, kbu, vbu, 256);
    attn_kernel<<<NN, 256, 0, stream>>>(qb, kbu, vbu, biasb, nbr, ob);
    gemm_n64<<<dim3(4, 64), 256, 0, stream>>>(ob, wo, yb, NN, 256, 256, nullptr, nullptr, 0);
    ln_add_kernel<<<NN / 4, 256, 0, stream>>>(local, yb, ln_a_g, ln_a_b, x1, inc1);
    // fused FFN projections
    gemm_ffn<<<dim3(16, 64), 256, 0, stream>>>(x1, w_up, w_lg, w_cg, w_bg,
                                               upb, lgb, cgb, bgb, 256);
    // segment means: zero accumulators (w2b already consumed), partial, finalize
    hipMemsetAsync(mb, 0, (NBATCH + NCHAIN) * 512 * sizeof(float), stream);
    seg_partial_kernel<<<NN / 32, 256, 0, stream>>>(upb, batch, chain, mb, mc);
    seg_final_kernel<<<(NBATCH + NCHAIN) * 512 / 256, 256, 0, stream>>>(mb, mc, batch, chain);
    hidden_kernel<<<NN * 512 / 256, 256, 0, stream>>>(upb, cgb, bgb, lgb, mb, mc, batch, chain);
    gemm_n64<<<dim3(4, 64), 256, 0, stream>>>(lgb, w_out, y2, NN, 512, 256, b_out, tfeat_out, 0);
    final_kernel<<<NN / 4, 256, 0, stream>>>(x1, y2, inc1, ln_u_g, ln_u_b, ln_f_g, ln_f_b, (float*)d_out);
}

// Round 10
// 309.948 us; speedup vs baseline: 1.2913x; 1.0399x over previous
//
#include <hip/hip_runtime.h>
#include <math.h>

#define NN 8192
#define KK 32
#define DD 256
#define PP 64
#define HH 8
#define DHH 32
#define NBATCH 32
#define NCHAIN 64

typedef __attribute__((ext_vector_type(8))) short bf16x8;
typedef __attribute__((ext_vector_type(4))) float f32x4;

// ---------------- helpers ----------------
__device__ __forceinline__ float gelu_f(float x) {
    float x3 = x * x * x;
    float z = 0.7978845608028654f * (x + 0.044715f * x3);
    z = fminf(fmaxf(z, -15.f), 15.f);
    float e = __expf(2.f * z);
    float t = (e - 1.f) / (e + 1.f);
    return 0.5f * x * (1.f + t);
}

__device__ __forceinline__ float wave_sum64(float v) {
    #pragma unroll
    for (int m = 32; m > 0; m >>= 1) v += __shfl_xor(v, m);
    return v;
}

__device__ __forceinline__ ushort f2bf(float x) {
    union { float f; unsigned int u; } v; v.f = x;
    unsigned int r = v.u + 0x7fffu + ((v.u >> 16) & 1u);
    return (ushort)(r >> 16);
}

__device__ __forceinline__ float bf2f(ushort u) {
    union { unsigned int u; float f; } v; v.u = ((unsigned int)u) << 16;
    return v.f;
}

__device__ __forceinline__ uint pk2(float a, float b) {
    return (uint)f2bf(a) | ((uint)f2bf(b) << 16);
}

// ---------------- frames ----------------
__global__ __launch_bounds__(256) void frames_kernel(const float* __restrict__ pos,
                                                     float* __restrict__ R) {
    int n = blockIdx.x * 256 + threadIdx.x;
    if (n >= NN) return;
    const float* p = pos + n * 15;
    float nx = p[0], ny = p[1], nz = p[2];
    float cax = p[3], cay = p[4], caz = p[5];
    float cx = p[6], cy = p[7], cz = p[8];
    float e1x = cx - cax, e1y = cy - cay, e1z = cz - caz;
    float inv = rsqrtf(e1x * e1x + e1y * e1y + e1z * e1z + 1e-8f);
    e1x *= inv; e1y *= inv; e1z *= inv;
    float ux = nx - cax, uy = ny - cay, uz = nz - caz;
    float dt = ux * e1x + uy * e1y + uz * e1z;
    float e2x = ux - dt * e1x, e2y = uy - dt * e1y, e2z = uz - dt * e1z;
    inv = rsqrtf(e2x * e2x + e2y * e2y + e2z * e2z + 1e-8f);
    e2x *= inv; e2y *= inv; e2z *= inv;
    float e3x = e1y * e2z - e1z * e2y;
    float e3y = e1z * e2x - e1x * e2z;
    float e3z = e1x * e2y - e1y * e2x;
    float* r = R + n * 9;
    r[0] = e1x; r[1] = e2x; r[2] = e3x;
    r[3] = e1y; r[4] = e2y; r[5] = e3y;
    r[6] = e1z; r[7] = e2z; r[8] = e3z;
}

// ---------------- raw pair features (lane = one (n,k) pair) ----------------
__global__ __launch_bounds__(256) void pair_raw_kernel(
    const float* __restrict__ pos, const int* __restrict__ nbr,
    const int* __restrict__ resi, const int* __restrict__ chain,
    const float* __restrict__ R,
    ushort* __restrict__ feat, int* __restrict__ relidx, float* __restrict__ tfeat_raw) {
    int p = blockIdx.x * 256 + threadIdx.x;
    int n = p >> 5, k = p & 31;
    int j = nbr[p];
    int same = (chain[j] == chain[n]);
    int off = min(max(resi[j] - resi[n], -32), 32) + 32;
    relidx[p] = same ? off : -1;

    float can0 = pos[n * 15 + 3], can1 = pos[n * 15 + 4], can2 = pos[n * 15 + 5];
    float cbn0 = pos[n * 15 + 12], cbn1 = pos[n * 15 + 13], cbn2 = pos[n * 15 + 14];
    float Rn[9], Rj[9];
    #pragma unroll
    for (int i = 0; i < 9; i++) Rn[i] = R[n * 9 + i];
    #pragma unroll
    for (int i = 0; i < 9; i++) Rj[i] = R[j * 9 + i];
    float pj[15];
    #pragma unroll
    for (int i = 0; i < 15; i++) pj[i] = pos[j * 15 + i];

    float fe[43];
    float d0 = pj[12] - cbn0, d1 = pj[13] - cbn1, d2 = pj[14] - cbn2;
    float dcb = sqrtf(d0 * d0 + d1 * d1 + d2 * d2 + 1e-8f);
    #pragma unroll
    for (int i = 0; i < 16; i++) {
        float c = (22.f / 15.f) * (float)i;
        float z = (dcb - c) * (1.f / 1.375f);
        fe[i] = __expf(-z * z);
    }
    #pragma unroll
    for (int a = 0; a < 5; a++) {
        float vx = pj[a * 3 + 0] - can0;
        float vy = pj[a * 3 + 1] - can1;
        float vz = pj[a * 3 + 2] - can2;
        float invv = rsqrtf(vx * vx + vy * vy + vz * vz + 1e-8f);
        fe[16 + a * 3 + 0] = vx * invv;
        fe[16 + a * 3 + 1] = vy * invv;
        fe[16 + a * 3 + 2] = vz * invv;
    }
    #pragma unroll
    for (int b = 0; b < 3; b++)
        #pragma unroll
        for (int c2 = 0; c2 < 3; c2++)
            fe[31 + b * 3 + c2] = Rn[0 + b] * Rj[0 + c2] + Rn[3 + b] * Rj[3 + c2] + Rn[6 + b] * Rj[6 + c2];
    float t0 = pj[3] - can0, t1 = pj[4] - can1, t2 = pj[5] - can2;
    #pragma unroll
    for (int b = 0; b < 3; b++)
        fe[40 + b] = Rn[0 + b] * t0 + Rn[3 + b] * t1 + Rn[6 + b] * t2;

    #pragma unroll
    for (int q = 0; q < 8; q++) {
        uint4 w;
        float v0 = (q * 8 + 0 < 43) ? fe[q * 8 + 0] : 0.f;
        float v1 = (q * 8 + 1 < 43) ? fe[q * 8 + 1] : 0.f;
        float v2 = (q * 8 + 2 < 43) ? fe[q * 8 + 2] : 0.f;
        float v3 = (q * 8 + 3 < 43) ? fe[q * 8 + 3] : 0.f;
        float v4 = (q * 8 + 4 < 43) ? fe[q * 8 + 4] : 0.f;
        float v5 = (q * 8 + 5 < 43) ? fe[q * 8 + 5] : 0.f;
        float v6 = (q * 8 + 6 < 43) ? fe[q * 8 + 6] : 0.f;
        float v7 = (q * 8 + 7 < 43) ? fe[q * 8 + 7] : 0.f;
        w.x = pk2(v0, v1); w.y = pk2(v2, v3); w.z = pk2(v4, v5); w.w = pk2(v6, v7);
        *(uint4*)&feat[(size_t)p * 64 + q * 8] = w;
    }
    float rt0 = fe[40], rt1 = fe[41], rt2 = fe[42];
    float dr2 = rt0 * rt0 + rt1 * rt1 + rt2 * rt2 + 1e-8f;
    float invdr = rsqrtf(dr2);
    float drel = dr2 * invdr;
    float* tf = tfeat_raw + (size_t)n * 608 + k * 19;
    #pragma unroll
    for (int i = 0; i < 16; i++) {
        float c = (22.f / 15.f) * (float)i;
        float z = (drel - c) * (1.f / 1.375f);
        tf[i] = __expf(-z * z);
    }
    tf[16] = rt0 * invdr;
    tf[17] = rt1 * invdr;
    tf[18] = rt2 * invdr;
}

// ---------------- pair stage0: feat-proj MFMA + relpos + LN, in-place feat -> pln ----------------
__global__ __launch_bounds__(256) void pair_pre_kernel(
    ushort* feat, const int* __restrict__ relidx,
    const float* __restrict__ w_relpos,
    const float* __restrict__ w_dist, const float* __restrict__ w_dir,
    const float* __restrict__ w_rot,
    const float* __restrict__ lng, const float* __restrict__ lnb) {
    int tid = threadIdx.x;
    int wid = tid >> 6, lane = tid & 63, hi = lane >> 4, lo = lane & 15;
    union U8 { bf16x8 v; uint u[4]; };
    U8 wf[8];
    #pragma unroll
    for (int f = 0; f < 4; f++)
        #pragma unroll
        for (int s = 0; s < 2; s++)
            #pragma unroll
            for (int jj = 0; jj < 4; jj++) {
                int k0 = 32 * s + hi * 8 + 2 * jj;
                int c = 16 * f + lo;
                float v0 = (k0 < 16) ? w_dist[k0 * 64 + c] : (k0 < 31) ? w_dir[(k0 - 16) * 64 + c]
                         : (k0 < 43) ? w_rot[(k0 - 31) * 64 + c] : 0.f;
                int k1 = k0 + 1;
                float v1 = (k1 < 16) ? w_dist[k1 * 64 + c] : (k1 < 31) ? w_dir[(k1 - 16) * 64 + c]
                         : (k1 < 43) ? w_rot[(k1 - 31) * 64 + c] : 0.f;
                wf[f * 2 + s].u[jj] = pk2(v0, v1);
            }
    float sg_r[4][4], sbt_r[4][4];
    #pragma unroll
    for (int f = 0; f < 4; f++)
        #pragma unroll
        for (int r = 0; r < 4; r++) {
            int c = 16 * f + 4 * hi + r;
            sg_r[f][r] = lng[c];
            sbt_r[f][r] = lnb[c];
        }
    const f32x4 zz = {0.f, 0.f, 0.f, 0.f};
    for (int t = blockIdx.x * 4 + wid; t < (NN * KK / 16); t += 8192) {
        int r0 = t << 4;
        bf16x8 bp0 = *(const bf16x8*)(feat + (size_t)(r0 + lo) * 64 + hi * 8);
        bf16x8 bp1 = *(const bf16x8*)(feat + (size_t)(r0 + lo) * 64 + 32 + hi * 8);
        f32x4 a0f[4];
        #pragma unroll
        for (int f = 0; f < 4; f++) {
            a0f[f] = __builtin_amdgcn_mfma_f32_16x16x32_bf16(wf[f * 2 + 0].v, bp0, zz, 0, 0, 0);
            a0f[f] = __builtin_amdgcn_mfma_f32_16x16x32_bf16(wf[f * 2 + 1].v, bp1, a0f[f], 0, 0, 0);
        }
        int ridx = relidx[r0 + lo];
        float val[4][4];
        float part = 0.f;
        #pragma unroll
        for (int f = 0; f < 4; f++)
            #pragma unroll
            for (int r = 0; r < 4; r++) {
                int c = 16 * f + 4 * hi + r;
                float rv = (ridx >= 0) ? w_relpos[ridx * 64 + c] : 0.f;
                float v = a0f[f][r] + rv;
                val[f][r] = v;
                part += v;
            }
        part += __shfl_xor(part, 16);
        part += __shfl_xor(part, 32);
        float mean = part * (1.f / 64.f);
        float v2 = 0.f;
        #pragma unroll
        for (int f = 0; f < 4; f++)
            #pragma unroll
            for (int r = 0; r < 4; r++) {
                float dv = val[f][r] - mean;
                val[f][r] = dv;
                v2 += dv * dv;
            }
        v2 += __shfl_xor(v2, 16);
        v2 += __shfl_xor(v2, 32);
        float rs = rsqrtf(v2 * (1.f / 64.f) + 1e-5f);
        #pragma unroll
        for (int f = 0; f < 4; f++) {
            float v0 = val[f][0] * rs * sg_r[f][0] + sbt_r[f][0];
            float v1 = val[f][1] * rs * sg_r[f][1] + sbt_r[f][1];
            float v2b = val[f][2] * rs * sg_r[f][2] + sbt_r[f][2];
            float v3 = val[f][3] * rs * sg_r[f][3] + sbt_r[f][3];
            *(uint2*)(feat + (size_t)(r0 + lo) * 64 + 16 * f + 4 * hi) =
                make_uint2(pk2(v0, v1), pk2(v2b, v3));
        }
    }
}

// ---------------- W2B = w_p2 @ wb  [128x8], b2b = b_p2 @ wb [8] ----------------
__global__ __launch_bounds__(256) void w2b_kernel(
    const float* __restrict__ w_p2, const float* __restrict__ b_p2,
    const float* __restrict__ wb, float* __restrict__ w2b, float* __restrict__ b2b) {
    int idx = blockIdx.x * 256 + threadIdx.x;
    if (idx < 1024) {
        int c = idx >> 3, h = idx & 7;
        float s = 0.f;
        for (int q = 0; q < 64; q++) s += w_p2[c * 64 + q] * wb[q * 8 + h];
        w2b[idx] = s;
    }
    if (idx < 8) {
        float s = 0.f;
        for (int q = 0; q < 64; q++) s += b_p2[q] * wb[q * 8 + idx];
        b2b[idx] = s;
    }
}

// ---------------- pair MLP: pln -> 128 gelu -> @W2B -> bias; weights in VGPR ----------------
__global__ __launch_bounds__(256) void pair_mlp2_kernel(
    const ushort* __restrict__ pln,
    const float* __restrict__ w_p1, const float* __restrict__ b_p1,
    const float* __restrict__ w2b, const float* __restrict__ b2b,
    float* __restrict__ bias) {
    __shared__ __align__(16) ushort hx[4 * 2048];
    int tid = threadIdx.x;
    int wid = tid >> 6, lane = tid & 63, hi = lane >> 4, lo = lane & 15;
    union U8 { bf16x8 v; uint u[4]; };
    U8 w1f[16];
    #pragma unroll
    for (int f = 0; f < 8; f++)
        #pragma unroll
        for (int s = 0; s < 2; s++)
            #pragma unroll
            for (int jj = 0; jj < 4; jj++) {
                int k0 = 32 * s + hi * 8 + 2 * jj;
                int c = 16 * f + lo;
                w1f[f * 2 + s].u[jj] = pk2(w_p1[k0 * 128 + c], w_p1[(k0 + 1) * 128 + c]);
            }
    U8 w2f[4];
    #pragma unroll
    for (int s2 = 0; s2 < 4; s2++)
        #pragma unroll
        for (int jj = 0; jj < 4; jj++) {
            int c0 = 32 * s2 + 8 * hi + 2 * jj;
            float v0 = (lo < 8) ? w2b[c0 * 8 + lo] : 0.f;
            float v1 = (lo < 8) ? w2b[(c0 + 1) * 8 + lo] : 0.f;
            w2f[s2].u[jj] = pk2(v0, v1);
        }
    float b2b_r[4];
    #pragma unroll
    for (int r = 0; r < 4; r++) b2b_r[r] = (hi < 2) ? b2b[4 * hi + r] : 0.f;
    float sb1_r[8][4];
    #pragma unroll
    for (int f = 0; f < 8; f++)
        #pragma unroll
        for (int r = 0; r < 4; r++) sb1_r[f][r] = b_p1[16 * f + 4 * hi + r];

    ushort* hxw = &hx[wid * 2048];
    const f32x4 zz = {0.f, 0.f, 0.f, 0.f};
    for (int t = blockIdx.x * 4 + wid; t < (NN * KK / 16); t += 8192) {
        int r0 = t << 4;
        bf16x8 bh0 = *(const bf16x8*)(pln + (size_t)(r0 + lo) * 64 + hi * 8);
        bf16x8 bh1 = *(const bf16x8*)(pln + (size_t)(r0 + lo) * 64 + 32 + hi * 8);
        #pragma unroll
        for (int f = 0; f < 8; f++) {
            f32x4 acch = __builtin_amdgcn_mfma_f32_16x16x32_bf16(w1f[f * 2 + 0].v, bh0, zz, 0, 0, 0);
            acch = __builtin_amdgcn_mfma_f32_16x16x32_bf16(w1f[f * 2 + 1].v, bh1, acch, 0, 0, 0);
            int c0 = 16 * f + 4 * hi;
            float v0 = gelu_f(acch[0] + sb1_r[f][0]);
            float v1 = gelu_f(acch[1] + sb1_r[f][1]);
            float v2b = gelu_f(acch[2] + sb1_r[f][2]);
            float v3 = gelu_f(acch[3] + sb1_r[f][3]);
            int idx = (lo * 128 + c0) ^ ((lo & 7) << 3);
            *(uint2*)&hxw[idx] = make_uint2(pk2(v0, v1), pk2(v2b, v3));
        }
        f32x4 acc = zz;
        #pragma unroll
        for (int s2 = 0; s2 < 4; s2++) {
            int idx = (lo * 128 + 32 * s2 + 8 * hi) ^ ((lo & 7) << 3);
            bf16x8 bh = *(const bf16x8*)&hxw[idx];
            acc = __builtin_amdgcn_mfma_f32_16x16x32_bf16(w2f[s2].v, bh, acc, 0, 0, 0);
        }
        if (hi < 2) {
            int n = r0 >> 5, kb = (r0 & 31) + lo;
            #pragma unroll
            for (int r = 0; r < 4; r++)
                bias[(size_t)n * 256 + (4 * hi + r) * 32 + kb] = acc[r] + b2b_r[r];
        }
    }
}

// ---------------- shared bf16 GEMM core (BN=128, fp32 A) ----------------
__device__ __forceinline__ void gemm_core(
    const float* __restrict__ A, const float* __restrict__ W,
    int K, int WN, int row0, int colW0, int tid,
    ushort* sA, ushort* sB, f32x4 acc[4][4]) {
    int wid = tid >> 6, lane = tid & 63, lo = lane & 15, hi = lane >> 4;
    int wr = wid >> 1, wc = wid & 1;
    int ar = tid >> 1, akh = (tid & 1) * 16;
    int bcol = tid & 127, bks = (tid >> 7) * 16;
    for (int kt = 0; kt < K; kt += 32) {
        const float* ap = &A[(size_t)(row0 + ar) * K + kt + akh];
        float4 a0 = *(const float4*)(ap + 0);
        float4 a1 = *(const float4*)(ap + 4);
        float4 a2 = *(const float4*)(ap + 8);
        float4 a3 = *(const float4*)(ap + 12);
        float wv[16];
        #pragma unroll
        for (int i = 0; i < 16; i++) wv[i] = W[(size_t)(kt + bks + i) * WN + colW0 + bcol];
        __syncthreads();
        *(uint4*)&sA[ar * 40 + akh] = make_uint4(pk2(a0.x, a0.y), pk2(a0.z, a0.w), pk2(a1.x, a1.y), pk2(a1.z, a1.w));
        *(uint4*)&sA[ar * 40 + akh + 8] = make_uint4(pk2(a2.x, a2.y), pk2(a2.z, a2.w), pk2(a3.x, a3.y), pk2(a3.z, a3.w));
        *(uint4*)&sB[bcol * 40 + bks] = make_uint4(pk2(wv[0], wv[1]), pk2(wv[2], wv[3]), pk2(wv[4], wv[5]), pk2(wv[6], wv[7]));
        *(uint4*)&sB[bcol * 40 + bks + 8] = make_uint4(pk2(wv[8], wv[9]), pk2(wv[10], wv[11]), pk2(wv[12], wv[13]), pk2(wv[14], wv[15]));
        __syncthreads();
        bf16x8 af[4], bfr[4];
        #pragma unroll
        for (int mi = 0; mi < 4; mi++) af[mi] = *(const bf16x8*)&sA[(wr * 64 + mi * 16 + lo) * 40 + hi * 8];
        #pragma unroll
        for (int ni = 0; ni < 4; ni++) bfr[ni] = *(const bf16x8*)&sB[(wc * 64 + ni * 16 + lo) * 40 + hi * 8];
        #pragma unroll
        for (int mi = 0; mi < 4; mi++)
            #pragma unroll
            for (int ni = 0; ni < 4; ni++)
                acc[mi][ni] = __builtin_amdgcn_mfma_f32_16x16x32_bf16(af[mi], bfr[ni], acc[mi][ni], 0, 0, 0);
    }
}

// ---------------- t1 GEMM (BM=128, BN=128, fp32 A, bf16 out, gelu) ----------------
__global__ __launch_bounds__(256) void gemm_t1(
    const float* __restrict__ A, const float* __restrict__ W, ushort* __restrict__ C,
    int M, int K, int Nc) {
    __shared__ __align__(16) ushort sA[128 * 40];
    __shared__ __align__(16) ushort sB[128 * 40];
    int row0 = blockIdx.y * 128, col0 = blockIdx.x * 128;
    int tid = threadIdx.x;
    const f32x4 zz = {0.f, 0.f, 0.f, 0.f};
    f32x4 acc[4][4] = {{zz, zz, zz, zz}, {zz, zz, zz, zz}, {zz, zz, zz, zz}, {zz, zz, zz, zz}};
    gemm_core(A, W, K, Nc, row0, col0, tid, sA, sB, acc);
    int wid = tid >> 6, lane = tid & 63, lo = lane & 15, hi = lane >> 4;
    int wr = wid >> 1, wc = wid & 1;
    #pragma unroll
    for (int ni = 0; ni < 4; ni++) {
        int col = col0 + wc * 64 + ni * 16 + lo;
        #pragma unroll
        for (int mi = 0; mi < 4; mi++) {
            #pragma unroll
            for (int r = 0; r < 4; r++) {
                int row = row0 + wr * 64 + mi * 16 + hi * 4 + r;
                C[(size_t)row * Nc + col] = f2bf(gelu_f(acc[mi][ni][r]));
            }
        }
    }
}

// ---------------- narrow GEMM (BM=128, BN=64) with bf16 A ----------------
__global__ __launch_bounds__(256) void gemm_n64b(
    const ushort* __restrict__ A, const float* __restrict__ W, float* __restrict__ C,
    int M, int K, int Nc,
    const float* __restrict__ bias, const float* __restrict__ addp) {
    __shared__ __align__(16) ushort sA[128 * 40];
    __shared__ __align__(16) ushort sB[64 * 40];
    int row0 = blockIdx.y * 128, col0 = blockIdx.x * 64;
    int tid = threadIdx.x;
    int wid = tid >> 6, lane = tid & 63, lo = lane & 15, hi = lane >> 4;
    int wr = wid >> 1, wc = wid & 1;
    int ar = tid >> 1, akh = (tid & 1) * 16;
    int bcol = tid & 63, bks = (tid >> 6) * 8;
    const f32x4 zz = {0.f, 0.f, 0.f, 0.f};
    f32x4 acc[4][2] = {{zz, zz}, {zz, zz}, {zz, zz}, {zz, zz}};
    for (int kt = 0; kt < K; kt += 32) {
        const ushort* ap = &A[(size_t)(row0 + ar) * K + kt + akh];
        uint4 a01 = *(const uint4*)(ap);
        uint4 a23 = *(const uint4*)(ap + 8);
        float wv[8];
        #pragma unroll
        for (int i = 0; i < 8; i++) wv[i] = W[(size_t)(kt + bks + i) * Nc + col0 + bcol];
        __syncthreads();
        *(uint4*)&sA[ar * 40 + akh] = a01;
        *(uint4*)&sA[ar * 40 + akh + 8] = a23;
        *(uint2*)&sB[bcol * 40 + bks] = make_uint2(pk2(wv[0], wv[1]), pk2(wv[2], wv[3]));
        *(uint2*)&sB[bcol * 40 + bks + 4] = make_uint2(pk2(wv[4], wv[5]), pk2(wv[6], wv[7]));
        __syncthreads();
        bf16x8 af[4], bfr[2];
        #pragma unroll
        for (int mi = 0; mi < 4; mi++) af[mi] = *(const bf16x8*)&sA[(wr * 64 + mi * 16 + lo) * 40 + hi * 8];
        #pragma unroll
        for (int ni = 0; ni < 2; ni++) bfr[ni] = *(const bf16x8*)&sB[(wc * 32 + ni * 16 + lo) * 40 + hi * 8];
        #pragma unroll
        for (int mi = 0; mi < 4; mi++)
            #pragma unroll
            for (int ni = 0; ni < 2; ni++)
                acc[mi][ni] = __builtin_amdgcn_mfma_f32_16x16x32_bf16(af[mi], bfr[ni], acc[mi][ni], 0, 0, 0);
    }
    #pragma unroll
    for (int ni = 0; ni < 2; ni++) {
        int col = col0 + wc * 32 + ni * 16 + lo;
        float bc = bias ? bias[col] : 0.f;
        #pragma unroll
        for (int mi = 0; mi < 4; mi++) {
            #pragma unroll
            for (int r = 0; r < 4; r++) {
                int row = row0 + wr * 64 + mi * 16 + hi * 4 + r;
                float v = acc[mi][ni][r] + bc;
                if (addp) v += addp[(size_t)row * Nc + col];
                C[(size_t)row * Nc + col] = v;
            }
        }
    }
}

// ---------------- fused QKV GEMM: q fp32, k/v bf16 ----------------
__global__ __launch_bounds__(256) void gemm_qkv(
    const float* __restrict__ A, const float* __restrict__ wq, const float* __restrict__ wk,
    const float* __restrict__ wvp, float* __restrict__ qb, ushort* __restrict__ kb,
    ushort* __restrict__ vb, int K) {
    __shared__ __align__(16) ushort sA[128 * 40];
    __shared__ __align__(16) ushort sB[128 * 40];
    int row0 = blockIdx.y * 128, col0 = blockIdx.x * 128;
    int wsel = col0 >> 8, colW0 = col0 & 255;
    const float* W = (wsel == 0) ? wq : (wsel == 1) ? wk : wvp;
    int tid = threadIdx.x;
    const f32x4 zz = {0.f, 0.f, 0.f, 0.f};
    f32x4 acc[4][4] = {{zz, zz, zz, zz}, {zz, zz, zz, zz}, {zz, zz, zz, zz}, {zz, zz, zz, zz}};
    gemm_core(A, W, K, 256, row0, colW0, tid, sA, sB, acc);
    int wid = tid >> 6, lane = tid & 63, lo = lane & 15, hi = lane >> 4;
    int wr = wid >> 1, wc = wid & 1;
    #pragma unroll
    for (int ni = 0; ni < 4; ni++) {
        int colW = colW0 + wc * 64 + ni * 16 + lo;
        #pragma unroll
        for (int mi = 0; mi < 4; mi++) {
            #pragma unroll
            for (int r = 0; r < 4; r++) {
                int row = row0 + wr * 64 + mi * 16 + hi * 4 + r;
                float v = acc[mi][ni][r];
                if (wsel == 0) qb[(size_t)row * 256 + colW] = v;
                else if (wsel == 1) kb[(size_t)row * 256 + colW] = f2bf(v);
                else vb[(size_t)row * 256 + colW] = f2bf(v);
            }
        }
    }
}

// ---------------- fused FFN GEMM: up (no gelu) + lg/cg/bg (gelu); bf16 outputs ----------------
__global__ __launch_bounds__(256) void gemm_ffn(
    const float* __restrict__ A,
    const float* __restrict__ w0, const float* __restrict__ w1,
    const float* __restrict__ w2, const float* __restrict__ w3,
    ushort* __restrict__ o0, ushort* __restrict__ o1,
    ushort* __restrict__ o2, ushort* __restrict__ o3, int K) {
    __shared__ __align__(16) ushort sA[128 * 40];
    __shared__ __align__(16) ushort sB[128 * 40];
    int row0 = blockIdx.y * 128, col0 = blockIdx.x * 128;
    int wsel = col0 >> 9, colW0 = col0 & 511;
    const float* W = (wsel == 0) ? w0 : (wsel == 1) ? w1 : (wsel == 2) ? w2 : w3;
    ushort* O = (wsel == 0) ? o0 : (wsel == 1) ? o1 : (wsel == 2) ? o2 : o3;
    int tid = threadIdx.x;
    const f32x4 zz = {0.f, 0.f, 0.f, 0.f};
    f32x4 acc[4][4] = {{zz, zz, zz, zz}, {zz, zz, zz, zz}, {zz, zz, zz, zz}, {zz, zz, zz, zz}};
    gemm_core(A, W, K, 512, row0, colW0, tid, sA, sB, acc);
    int wid = tid >> 6, lane = tid & 63, lo = lane & 15, hi = lane >> 4;
    int wr = wid >> 1, wc = wid & 1;
    #pragma unroll
    for (int ni = 0; ni < 4; ni++) {
        int colW = colW0 + wc * 64 + ni * 16 + lo;
        #pragma unroll
        for (int mi = 0; mi < 4; mi++) {
            #pragma unroll
            for (int r = 0; r < 4; r++) {
                int row = row0 + wr * 64 + mi * 16 + hi * 4 + r;
                float v = acc[mi][ni][r];
                if (wsel > 0) v = gelu_f(v);
                O[(size_t)row * 512 + colW] = f2bf(v);
            }
        }
    }
}

// ---------------- attention: QK direct-gather + V staged through LDS; bf16 out ----------------
__global__ __launch_bounds__(256) void attn_kernel(
    const float* __restrict__ q, const ushort* __restrict__ kp, const ushort* __restrict__ vp,
    const float* __restrict__ bias, const int* __restrict__ nbr, ushort* __restrict__ o) {
    int n = blockIdx.x;
    __shared__ float qs[256];
    __shared__ int js[32];
    __shared__ float ls[256];                  // [h][k]
    __shared__ __align__(16) uint4 vs[32 * 33]; // 32 v-rows, +1 uint4 pad
    int t = threadIdx.x;
    qs[t] = q[(size_t)n * 256 + t];
    if (t < 32) js[t] = nbr[n * 32 + t];
    __syncthreads();
    int vrow = t >> 3, vseg = t & 7;
    const uint4* vsrc = (const uint4*)(vp + (size_t)js[vrow] * 256);
    uint4 vr0 = vsrc[vseg * 4 + 0];
    uint4 vr1 = vsrc[vseg * 4 + 1];
    uint4 vr2 = vsrc[vseg * 4 + 2];
    uint4 vr3 = vsrc[vseg * 4 + 3];
    int h = t >> 5, k = t & 31;
    int j = js[k];
    const bf16x8* kr = (const bf16x8*)(kp + (size_t)j * 256 + h * 32);
    bf16x8 kv0 = kr[0], kv1 = kr[1], kv2 = kr[2], kv3 = kr[3];
    const float* qh = qs + h * 32;
    float dot = 0.f;
    #pragma unroll
    for (int i = 0; i < 8; i++) dot += qh[i] * bf2f((ushort)kv0[i]);
    #pragma unroll
    for (int i = 0; i < 8; i++) dot += qh[8 + i] * bf2f((ushort)kv1[i]);
    #pragma unroll
    for (int i = 0; i < 8; i++) dot += qh[16 + i] * bf2f((ushort)kv2[i]);
    #pragma unroll
    for (int i = 0; i < 8; i++) dot += qh[24 + i] * bf2f((ushort)kv3[i]);
    float l = dot * 0.17677669529663687f + bias[(size_t)n * 256 + t];
    float mx = l;
    #pragma unroll
    for (int m = 16; m > 0; m >>= 1) mx = fmaxf(mx, __shfl_xor(mx, m));
    float e = __expf(l - mx);
    float sum = e;
    #pragma unroll
    for (int m = 16; m > 0; m >>= 1) sum += __shfl_xor(sum, m);
    ls[t] = e / sum;
    vs[vrow * 33 + vseg * 4 + 0] = vr0;
    vs[vrow * 33 + vseg * 4 + 1] = vr1;
    vs[vrow * 33 + vseg * 4 + 2] = vr2;
    vs[vrow * 33 + vseg * 4 + 3] = vr3;
    __syncthreads();
    const ushort* vsu = (const ushort*)vs;
    const float* lh = ls + h * 32;
    float acc = 0.f;
    #pragma unroll
    for (int kk = 0; kk < 32; kk++)
        acc += lh[kk] * bf2f(vsu[kk * 264 + h * 32 + k]);
    o[(size_t)n * 256 + t] = f2bf(acc);
}

// ---------------- LN(a+b) with sum output ----------------
__global__ __launch_bounds__(256) void ln_add_kernel(
    const float* __restrict__ a, const float* __restrict__ b,
    const float* __restrict__ g, const float* __restrict__ be,
    float* __restrict__ xout, float* __restrict__ sout) {
    int row = blockIdx.x * 4 + (threadIdx.x >> 6);
    int lane = threadIdx.x & 63;
    size_t base = (size_t)row * 256 + lane * 4;
    float4 av = *(const float4*)(a + base);
    float4 bv = *(const float4*)(b + base);
    float s0 = av.x + bv.x, s1 = av.y + bv.y, s2 = av.z + bv.z, s3 = av.w + bv.w;
    float sum = wave_sum64(s0 + s1 + s2 + s3);
    float mean = sum * (1.f / 256.f);
    float d0 = s0 - mean, d1 = s1 - mean, d2 = s2 - mean, d3 = s3 - mean;
    float v = wave_sum64(d0 * d0 + d1 * d1 + d2 * d2 + d3 * d3);
    float rs = rsqrtf(v * (1.f / 256.f) + 1e-5f);
    float4 gv = *(const float4*)(g + lane * 4);
    float4 bev = *(const float4*)(be + lane * 4);
    float4 xo;
    xo.x = d0 * rs * gv.x + bev.x;
    xo.y = d1 * rs * gv.y + bev.y;
    xo.z = d2 * rs * gv.z + bev.z;
    xo.w = d3 * rs * gv.w + bev.w;
    *(float4*)(xout + base) = xo;
    float4 so; so.x = s0; so.y = s1; so.z = s2; so.w = s3;
    *(float4*)(sout + base) = so;
}

// ---------------- segment means: phase 1 partial sums (atomic, bf16 input) ----------------
__global__ __launch_bounds__(256) void seg_partial_kernel(
    const ushort* __restrict__ up, const int* __restrict__ batch, const int* __restrict__ chain,
    float* __restrict__ mb_acc, float* __restrict__ mc_acc) {
    int r0 = blockIdx.x * 32;
    int t = threadIdx.x;
    float ab0 = 0.f, ab1 = 0.f, ac0 = 0.f, ac1 = 0.f;
    int curb = batch[r0], curc = chain[r0];
    for (int r = r0; r < r0 + 32; r++) {
        int b = batch[r], c = chain[r];
        if (b != curb) {
            atomicAdd(&mb_acc[curb * 512 + t], ab0);
            atomicAdd(&mb_acc[curb * 512 + 256 + t], ab1);
            ab0 = ab1 = 0.f; curb = b;
        }
        if (c != curc) {
            atomicAdd(&mc_acc[curc * 512 + t], ac0);
            atomicAdd(&mc_acc[curc * 512 + 256 + t], ac1);
            ac0 = ac1 = 0.f; curc = c;
        }
        float v0 = bf2f(up[(size_t)r * 512 + t]);
        float v1 = bf2f(up[(size_t)r * 512 + 256 + t]);
        ab0 += v0; ab1 += v1; ac0 += v0; ac1 += v1;
    }
    atomicAdd(&mb_acc[curb * 512 + t], ab0);
    atomicAdd(&mb_acc[curb * 512 + 256 + t], ab1);
    atomicAdd(&mc_acc[curc * 512 + t], ac0);
    atomicAdd(&mc_acc[curc * 512 + 256 + t], ac1);
}

// ---------------- segment means: phase 2 divide by counts ----------------
__device__ __forceinline__ int lower_bound_i(const int* a, int n, int v) {
    int lo = 0, hi = n;
    while (lo < hi) { int mid = (lo + hi) >> 1; if (a[mid] < v) lo = mid + 1; else hi = mid; }
    return lo;
}

__global__ __launch_bounds__(256) void seg_final_kernel(
    float* __restrict__ mb, float* __restrict__ mc,
    const int* __restrict__ batch, const int* __restrict__ chain) {
    int idx = blockIdx.x * 256 + threadIdx.x;
    if (idx < NBATCH * 512) {
        int seg = idx >> 9;
        int lo = lower_bound_i(batch, NN, seg);
        int hi = lower_bound_i(batch, NN, seg + 1);
        mb[idx] *= 1.f / fmaxf((float)(hi - lo), 1.f);
    } else {
        int i2 = idx - NBATCH * 512;
        int seg = i2 >> 9;
        int lo = lower_bound_i(chain, NN, seg);
        int hi = lower_bound_i(chain, NN, seg + 1);
        mc[i2] *= 1.f / fmaxf((float)(hi - lo), 1.f);
    }
}

// ---------------- hidden combine (bf16 in/out, x4 vectorized) ----------------
__global__ __launch_bounds__(256) void hidden_kernel(
    const ushort* __restrict__ up, const ushort* __restrict__ cg, const ushort* __restrict__ bg,
    ushort* __restrict__ lg, const float* __restrict__ mb, const float* __restrict__ mc,
    const int* __restrict__ batch, const int* __restrict__ chain) {
    size_t e4 = ((size_t)blockIdx.x * 256 + threadIdx.x) * 4;
    int n = (int)(e4 >> 9), d = (int)(e4 & 511);
    float4 mbv = *(const float4*)&mb[batch[n] * 512 + d];
    float4 mcv = *(const float4*)&mc[chain[n] * 512 + d];
    uint2 u_up = *(const uint2*)&up[e4];
    uint2 u_cg = *(const uint2*)&cg[e4];
    uint2 u_bg = *(const uint2*)&bg[e4];
    uint2 u_lg = *(const uint2*)&lg[e4];
    float h0 = bf2f((ushort)u_bg.x) * mbv.x + bf2f((ushort)u_cg.x) * mcv.x
             + bf2f((ushort)u_lg.x) * bf2f((ushort)u_up.x);
    float h1 = bf2f((ushort)(u_bg.x >> 16)) * mbv.y + bf2f((ushort)(u_cg.x >> 16)) * mcv.y
             + bf2f((ushort)(u_lg.x >> 16)) * bf2f((ushort)(u_up.x >> 16));
    float h2 = bf2f((ushort)u_bg.y) * mbv.z + bf2f((ushort)u_cg.y) * mcv.z
             + bf2f((ushort)u_lg.y) * bf2f((ushort)u_up.y);
    float h3 = bf2f((ushort)(u_bg.y >> 16)) * mbv.w + bf2f((ushort)(u_cg.y >> 16)) * mcv.w
             + bf2f((ushort)(u_lg.y >> 16)) * bf2f((ushort)(u_up.y >> 16));
    *(uint2*)&lg[e4] = make_uint2(pk2(h0, h1), pk2(h2, h3));
}

// ---------------- final ----------------
__global__ __launch_bounds__(256) void final_kernel(
    const float* __restrict__ x1, const float* __restrict__ y2, const float* __restrict__ inc1,
    const float* __restrict__ ug, const float* __restrict__ ub,
    const float* __restrict__ fg, const float* __restrict__ fb, float* __restrict__ out) {
    int row = blockIdx.x * 4 + (threadIdx.x >> 6);
    int lane = threadIdx.x & 63;
    size_t base = (size_t)row * 256 + lane * 4;
    float4 xv = *(const float4*)(x1 + base);
    float4 yv = *(const float4*)(y2 + base);
    float4 iv = *(const float4*)(inc1 + base);
    float s0 = xv.x + yv.x, s1 = xv.y + yv.y, s2 = xv.z + yv.z, s3 = xv.w + yv.w;
    float t0 = iv.x + yv.x, t1 = iv.y + yv.y, t2 = iv.z + yv.z, t3 = iv.w + yv.w;
    float sums = wave_sum64(s0 + s1 + s2 + s3);
    float means = sums * (1.f / 256.f);
    float sd0 = s0 - means, sd1 = s1 - means, sd2 = s2 - means, sd3 = s3 - means;
    float vs = wave_sum64(sd0 * sd0 + sd1 * sd1 + sd2 * sd2 + sd3 * sd3);
    float rss = rsqrtf(vs * (1.f / 256.f) + 1e-5f);
    float sumt = wave_sum64(t0 + t1 + t2 + t3);
    float meant = sumt * (1.f / 256.f);
    float td0 = t0 - meant, td1 = t1 - meant, td2 = t2 - meant, td3 = t3 - meant;
    float vt = wave_sum64(td0 * td0 + td1 * td1 + td2 * td2 + td3 * td3);
    float rst = rsqrtf(vt * (1.f / 256.f) + 1e-5f);
    float4 ugv = *(const float4*)(ug + lane * 4);
    float4 ubv = *(const float4*)(ub + lane * 4);
    float4 fgv = *(const float4*)(fg + lane * 4);
    float4 fbv = *(const float4*)(fb + lane * 4);
    float4 ov;
    ov.x = (sd0 * rss * ugv.x + ubv.x) + (td0 * rst * fgv.x + fbv.x);
    ov.y = (sd1 * rss * ugv.y + ubv.y) + (td1 * rst * fgv.y + fbv.y);
    ov.z = (sd2 * rss * ugv.z + ubv.z) + (td2 * rst * fgv.z + fbv.z);
    ov.w = (sd3 * rss * ugv.w + ubv.w) + (td3 * rst * fgv.w + fbv.w);
    *(float4*)(out + base) = ov;
}

// ---------------- launch ----------------
extern "C" void kernel_launch(void* const* d_in, const int* in_sizes, int n_in,
                              void* d_out, int out_size, void* d_ws, size_t ws_size,
                              hipStream_t stream) {
    const float* local    = (const float*)d_in[0];
    const float* pos      = (const float*)d_in[1];
    const int*   nbr      = (const int*)d_in[2];
    const int*   resi     = (const int*)d_in[3];
    const int*   chain    = (const int*)d_in[4];
    const int*   batch    = (const int*)d_in[5];
    const float* w_relpos = (const float*)d_in[7];
    const float* w_dist   = (const float*)d_in[8];
    const float* w_dir    = (const float*)d_in[9];
    const float* w_rot    = (const float*)d_in[10];
    const float* ln_pair_g = (const float*)d_in[11];
    const float* ln_pair_b = (const float*)d_in[12];
    const float* w_p1     = (const float*)d_in[13];
    const float* b_p1     = (const float*)d_in[14];
    const float* w_p2     = (const float*)d_in[15];
    const float* b_p2     = (const float*)d_in[16];
    const float* wq       = (const float*)d_in[17];
    const float* wk       = (const float*)d_in[18];
    const float* wv       = (const float*)d_in[19];
    const float* wb       = (const float*)d_in[20];
    const float* wo       = (const float*)d_in[21];
    const float* ln_a_g   = (const float*)d_in[22];
    const float* ln_a_b   = (const float*)d_in[23];
    const float* w_t1     = (const float*)d_in[24];
    const float* w_t2     = (const float*)d_in[25];
    const float* w_up     = (const float*)d_in[26];
    const float* w_lg     = (const float*)d_in[27];
    const float* w_cg     = (const float*)d_in[28];
    const float* w_bg     = (const float*)d_in[29];
    const float* w_out    = (const float*)d_in[30];
    const float* b_out    = (const float*)d_in[31];
    const float* ln_u_g   = (const float*)d_in[32];
    const float* ln_u_b   = (const float*)d_in[33];
    const float* ln_f_g   = (const float*)d_in[34];
    const float* ln_f_b   = (const float*)d_in[35];

    float* ws = (float*)d_ws;
    float* R         = ws + 0;             // 9N -> 73728
    float* biasb     = ws + 73728;         // N*256 -> 2170880
    float* tfeat_out = ws + 2170880;       // N*256 fp32 -> 4268032
    float* x1        = ws + 4268032;       // N*256 -> 6365184
    float* inc1      = ws + 6365184;       // N*256 -> 8462336
    ushort* featb    = (ushort*)(ws + 8462336);  // N*K*64 bf16 (phase 1; becomes pln in-place)
    int* relidx      = (int*)(ws + 16850944);    // N*K
    float* tfeat_raw = ws + 17113088;      // N*608 fp32 (phase 1)
    ushort* tmp512u  = (ushort*)(ws + 22093824); // N*512 bf16 (phase 1)
    float* qb        = ws + 8462336;       // N*256 fp32 (phase 2, over featb)
    ushort* kbu      = (ushort*)(ws + 10559488); // N*256 bf16
    ushort* vbu      = (ushort*)(ws + 12656640); // N*256 bf16
    ushort* obu      = (ushort*)(ws + 14753792); // N*256 bf16
    float* yb        = ws + 22093824;      // N*256 fp32 (over tmp512u after t2)
    ushort* upbu     = (ushort*)(ws + 8462336);  // N*512 bf16 (phase 3)
    ushort* lgbu     = (ushort*)(ws + 12656640); // N*512 bf16
    ushort* cgbu     = (ushort*)(ws + 17113088); // N*512 bf16
    ushort* bgbu     = (ushort*)(ws + 21307392); // N*512 bf16
    float* mb        = ws + 25501696;      // 32*512 (phase 3)
    float* mc        = ws + 25518080;      // 64*512 (phase 3)
    float* y2        = ws + 25550848;      // N*256
    float* w2b       = ws + 25501696;      // 128*8 (phase 1; overlaps mb, used before it)
    float* b2b       = ws + 25502720;      // 8

    frames_kernel<<<NN / 256, 256, 0, stream>>>(pos, R);
    w2b_kernel<<<4, 256, 0, stream>>>(w_p2, b_p2, wb, w2b, b2b);
    pair_raw_kernel<<<NN * KK / 256, 256, 0, stream>>>(pos, nbr, resi, chain, R,
                                                       featb, relidx, tfeat_raw);
    pair_pre_kernel<<<2048, 256, 0, stream>>>(featb, relidx, w_relpos, w_dist, w_dir, w_rot,
                                              ln_pair_g, ln_pair_b);
    pair_mlp2_kernel<<<2048, 256, 0, stream>>>(featb, w_p1, b_p1, w2b, b2b, biasb);
    // tfeat MLP (t1 -> bf16, t2 bf16-A)
    gemm_t1<<<dim3(4, 64), 256, 0, stream>>>(tfeat_raw, w_t1, tmp512u, NN, 608, 512);
    gemm_n64b<<<dim3(4, 64), 256, 0, stream>>>(tmp512u, w_t2, tfeat_out, NN, 512, 256, nullptr, nullptr);
    // fused qkv projection (q fp32, k/v bf16)
    gemm_qkv<<<dim3(6, 64), 256, 0, stream>>>(local, wq, wk, wv, qb, kbu, vbu, 256);
    attn_kernel<<<NN, 256, 0, stream>>>(qb, kbu, vbu, biasb, nbr, obu);
    gemm_n64b<<<dim3(4, 64), 256, 0, stream>>>(obu, wo, yb, NN, 256, 256, nullptr, nullptr);
    ln_add_kernel<<<NN / 4, 256, 0, stream>>>(local, yb, ln_a_g, ln_a_b, x1, inc1);
    // fused FFN projections (bf16 outs)
    gemm_ffn<<<dim3(16, 64), 256, 0, stream>>>(x1, w_up, w_lg, w_cg, w_bg,
                                               upbu, lgbu, cgbu, bgbu, 256);
    // segment means: zero accumulators, partial (atomic), finalize
    hipMemsetAsync(mb, 0, (NBATCH + NCHAIN) * 512 * sizeof(float), stream);
    seg_partial_kernel<<<NN / 32, 256, 0, stream>>>(upbu, batch, chain, mb, mc);
    seg_final_kernel<<<(NBATCH + NCHAIN) * 512 / 256, 256, 0, stream>>>(mb, mc, batch, chain);
    hidden_kernel<<<NN * 512 / 1024, 256, 0, stream>>>(upbu, cgbu, bgbu, lgbu, mb, mc, batch, chain);
    gemm_n64b<<<dim3(4, 64), 256, 0, stream>>>(lgbu, w_out, y2, NN, 512, 256, b_out, tfeat_out);
    final_kernel<<<NN / 4, 256, 0, stream>>>(x1, y2, inc1, ln_u_g, ln_u_b, ln_f_g, ln_f_b, (float*)d_out);
}

// Round 12
// 294.523 us; speedup vs baseline: 1.3589x; 1.0524x over previous
//
#include <hip/hip_runtime.h>
#include <math.h>

#define NN 8192
#define KK 32
#define DD 256
#define PP 64
#define HH 8
#define DHH 32
#define NBATCH 32
#define NCHAIN 64

typedef __attribute__((ext_vector_type(8))) short bf16x8;
typedef __attribute__((ext_vector_type(4))) float f32x4;

// ---------------- helpers ----------------
// gelu(x) = 0.5x(1+tanh(z)) = x * sigmoid(2z), z = 0.79788456(x + 0.044715 x^3)
// e^{-2z} = exp(-1.59576912*x - 0.07135481*x^3)
__device__ __forceinline__ float gelu_f(float x) {
    float x3 = x * x * x;
    float e = __expf(fmaf(x3, -0.07135481f, x * -1.59576912f));
    return __fdividef(x, 1.f + e);
}

__device__ __forceinline__ float wave_sum64(float v) {
    #pragma unroll
    for (int m = 32; m > 0; m >>= 1) v += __shfl_xor(v, m);
    return v;
}

__device__ __forceinline__ ushort f2bf(float x) {
    union { float f; unsigned int u; } v; v.f = x;
    unsigned int r = v.u + 0x7fffu + ((v.u >> 16) & 1u);
    return (ushort)(r >> 16);
}

__device__ __forceinline__ float bf2f(ushort u) {
    union { unsigned int u; float f; } v; v.u = ((unsigned int)u) << 16;
    return v.f;
}

__device__ __forceinline__ uint pk2(float a, float b) {
    return (uint)f2bf(a) | ((uint)f2bf(b) << 16);
}

// ---------------- frames ----------------
__global__ __launch_bounds__(256) void frames_kernel(const float* __restrict__ pos,
                                                     float* __restrict__ R) {
    int n = blockIdx.x * 256 + threadIdx.x;
    if (n >= NN) return;
    const float* p = pos + n * 15;
    float nx = p[0], ny = p[1], nz = p[2];
    float cax = p[3], cay = p[4], caz = p[5];
    float cx = p[6], cy = p[7], cz = p[8];
    float e1x = cx - cax, e1y = cy - cay, e1z = cz - caz;
    float inv = rsqrtf(e1x * e1x + e1y * e1y + e1z * e1z + 1e-8f);
    e1x *= inv; e1y *= inv; e1z *= inv;
    float ux = nx - cax, uy = ny - cay, uz = nz - caz;
    float dt = ux * e1x + uy * e1y + uz * e1z;
    float e2x = ux - dt * e1x, e2y = uy - dt * e1y, e2z = uz - dt * e1z;
    inv = rsqrtf(e2x * e2x + e2y * e2y + e2z * e2z + 1e-8f);
    e2x *= inv; e2y *= inv; e2z *= inv;
    float e3x = e1y * e2z - e1z * e2y;
    float e3y = e1z * e2x - e1x * e2z;
    float e3z = e1x * e2y - e1y * e2x;
    float* r = R + n * 9;
    r[0] = e1x; r[1] = e2x; r[2] = e3x;
    r[3] = e1y; r[4] = e2y; r[5] = e3y;
    r[6] = e1z; r[7] = e2z; r[8] = e3z;
}

// ---------------- raw pair features (lane = one (n,k) pair) ----------------
__global__ __launch_bounds__(256) void pair_raw_kernel(
    const float* __restrict__ pos, const int* __restrict__ nbr,
    const int* __restrict__ resi, const int* __restrict__ chain,
    const float* __restrict__ R,
    ushort* __restrict__ feat, int* __restrict__ relidx, float* __restrict__ tfeat_raw) {
    int p = blockIdx.x * 256 + threadIdx.x;
    int n = p >> 5, k = p & 31;
    int j = nbr[p];
    int same = (chain[j] == chain[n]);
    int off = min(max(resi[j] - resi[n], -32), 32) + 32;
    relidx[p] = same ? off : -1;

    float can0 = pos[n * 15 + 3], can1 = pos[n * 15 + 4], can2 = pos[n * 15 + 5];
    float cbn0 = pos[n * 15 + 12], cbn1 = pos[n * 15 + 13], cbn2 = pos[n * 15 + 14];
    float Rn[9], Rj[9];
    #pragma unroll
    for (int i = 0; i < 9; i++) Rn[i] = R[n * 9 + i];
    #pragma unroll
    for (int i = 0; i < 9; i++) Rj[i] = R[j * 9 + i];
    float pj[15];
    #pragma unroll
    for (int i = 0; i < 15; i++) pj[i] = pos[j * 15 + i];

    float fe[43];
    float d0 = pj[12] - cbn0, d1 = pj[13] - cbn1, d2 = pj[14] - cbn2;
    float dcb = sqrtf(d0 * d0 + d1 * d1 + d2 * d2 + 1e-8f);
    #pragma unroll
    for (int i = 0; i < 16; i++) {
        float c = (22.f / 15.f) * (float)i;
        float z = (dcb - c) * (1.f / 1.375f);
        fe[i] = __expf(-z * z);
    }
    #pragma unroll
    for (int a = 0; a < 5; a++) {
        float vx = pj[a * 3 + 0] - can0;
        float vy = pj[a * 3 + 1] - can1;
        float vz = pj[a * 3 + 2] - can2;
        float invv = rsqrtf(vx * vx + vy * vy + vz * vz + 1e-8f);
        fe[16 + a * 3 + 0] = vx * invv;
        fe[16 + a * 3 + 1] = vy * invv;
        fe[16 + a * 3 + 2] = vz * invv;
    }
    #pragma unroll
    for (int b = 0; b < 3; b++)
        #pragma unroll
        for (int c2 = 0; c2 < 3; c2++)
            fe[31 + b * 3 + c2] = Rn[0 + b] * Rj[0 + c2] + Rn[3 + b] * Rj[3 + c2] + Rn[6 + b] * Rj[6 + c2];
    float t0 = pj[3] - can0, t1 = pj[4] - can1, t2 = pj[5] - can2;
    #pragma unroll
    for (int b = 0; b < 3; b++)
        fe[40 + b] = Rn[0 + b] * t0 + Rn[3 + b] * t1 + Rn[6 + b] * t2;

    #pragma unroll
    for (int q = 0; q < 8; q++) {
        uint4 w;
        float v0 = (q * 8 + 0 < 43) ? fe[q * 8 + 0] : 0.f;
        float v1 = (q * 8 + 1 < 43) ? fe[q * 8 + 1] : 0.f;
        float v2 = (q * 8 + 2 < 43) ? fe[q * 8 + 2] : 0.f;
        float v3 = (q * 8 + 3 < 43) ? fe[q * 8 + 3] : 0.f;
        float v4 = (q * 8 + 4 < 43) ? fe[q * 8 + 4] : 0.f;
        float v5 = (q * 8 + 5 < 43) ? fe[q * 8 + 5] : 0.f;
        float v6 = (q * 8 + 6 < 43) ? fe[q * 8 + 6] : 0.f;
        float v7 = (q * 8 + 7 < 43) ? fe[q * 8 + 7] : 0.f;
        w.x = pk2(v0, v1); w.y = pk2(v2, v3); w.z = pk2(v4, v5); w.w = pk2(v6, v7);
        *(uint4*)&feat[(size_t)p * 64 + q * 8] = w;
    }
    float rt0 = fe[40], rt1 = fe[41], rt2 = fe[42];
    float dr2 = rt0 * rt0 + rt1 * rt1 + rt2 * rt2 + 1e-8f;
    float invdr = rsqrtf(dr2);
    float drel = dr2 * invdr;
    float* tf = tfeat_raw + (size_t)n * 608 + k * 19;
    #pragma unroll
    for (int i = 0; i < 16; i++) {
        float c = (22.f / 15.f) * (float)i;
        float z = (drel - c) * (1.f / 1.375f);
        tf[i] = __expf(-z * z);
    }
    tf[16] = rt0 * invdr;
    tf[17] = rt1 * invdr;
    tf[18] = rt2 * invdr;
}

// ---------------- W2B = w_p2 @ wb  [128x8], b2b = b_p2 @ wb [8] ----------------
__global__ __launch_bounds__(256) void w2b_kernel(
    const float* __restrict__ w_p2, const float* __restrict__ b_p2,
    const float* __restrict__ wb, float* __restrict__ w2b, float* __restrict__ b2b) {
    int idx = blockIdx.x * 256 + threadIdx.x;
    if (idx < 1024) {
        int c = idx >> 3, h = idx & 7;
        float s = 0.f;
        for (int q = 0; q < 64; q++) s += w_p2[c * 64 + q] * wb[q * 8 + h];
        w2b[idx] = s;
    }
    if (idx < 8) {
        float s = 0.f;
        for (int q = 0; q < 64; q++) s += b_p2[q] * wb[q * 8 + idx];
        b2b[idx] = s;
    }
}

// ---------------- fmt: preformat MFMA weight fragments (bf16, final lane layout) ----------------
// pf layout (ushort): [0,8192) w1 frags fs*512+lane*8 ; [8192,10240) w2b frags s2*512+lane*8 ;
//                     [10240,14336) stage0 wf frags fs*512+lane*8
__global__ __launch_bounds__(256) void fmt_kernel(
    const float* __restrict__ w_p1,
    const float* __restrict__ w_dist, const float* __restrict__ w_dir,
    const float* __restrict__ w_rot, const float* __restrict__ w2b,
    ushort* __restrict__ pf) {
    int u = blockIdx.x * 256 + threadIdx.x;  // uint index
    uint* pfu = (uint*)pf;
    if (u < 4096) {
        int fs = u >> 8, rem = u & 255, lane = rem >> 2, jj = rem & 3;
        int hi = lane >> 4, lo = lane & 15;
        int f = fs >> 1, s = fs & 1;
        int k0 = 32 * s + hi * 8 + 2 * jj;
        int c = 16 * f + lo;
        pfu[u] = pk2(w_p1[k0 * 128 + c], w_p1[(k0 + 1) * 128 + c]);
    } else if (u < 5120) {
        int u2 = u - 4096;
        int s2 = u2 >> 8, rem = u2 & 255, lane = rem >> 2, jj = rem & 3;
        int hi = lane >> 4, lo = lane & 15;
        int c0 = 32 * s2 + 8 * hi + 2 * jj;
        float v0 = (lo < 8) ? w2b[c0 * 8 + lo] : 0.f;
        float v1 = (lo < 8) ? w2b[(c0 + 1) * 8 + lo] : 0.f;
        pfu[u] = pk2(v0, v1);
    } else if (u < 7168) {
        int u2 = u - 5120;
        int fs = u2 >> 8, rem = u2 & 255, lane = rem >> 2, jj = rem & 3;
        int hi = lane >> 4, lo = lane & 15;
        int f = fs >> 1, s = fs & 1;
        int k0 = 32 * s + hi * 8 + 2 * jj;
        int c = 16 * f + lo;
        float v0 = (k0 < 16) ? w_dist[k0 * 64 + c] : (k0 < 31) ? w_dir[(k0 - 16) * 64 + c]
                 : (k0 < 43) ? w_rot[(k0 - 31) * 64 + c] : 0.f;
        int k1 = k0 + 1;
        float v1 = (k1 < 16) ? w_dist[k1 * 64 + c] : (k1 < 31) ? w_dir[(k1 - 16) * 64 + c]
                 : (k1 < 43) ? w_rot[(k1 - 31) * 64 + c] : 0.f;
        pfu[u] = pk2(v0, v1);
    }
}

// ---------------- pair stage0: feat-proj MFMA + relpos + LN, in-place feat -> pln ----------------
__global__ __launch_bounds__(256) void pair_pre_kernel(
    ushort* feat, const int* __restrict__ relidx,
    const float* __restrict__ w_relpos, const ushort* __restrict__ pf,
    const float* __restrict__ lng, const float* __restrict__ lnb) {
    int tid = threadIdx.x;
    int wid = tid >> 6, lane = tid & 63, hi = lane >> 4, lo = lane & 15;
    bf16x8 wf[8];
    #pragma unroll
    for (int fs = 0; fs < 8; fs++) wf[fs] = *(const bf16x8*)&pf[10240 + fs * 512 + lane * 8];
    float sg_r[4][4], sbt_r[4][4];
    #pragma unroll
    for (int f = 0; f < 4; f++)
        #pragma unroll
        for (int r = 0; r < 4; r++) {
            int c = 16 * f + 4 * hi + r;
            sg_r[f][r] = lng[c];
            sbt_r[f][r] = lnb[c];
        }
    const f32x4 zz = {0.f, 0.f, 0.f, 0.f};
    for (int t = blockIdx.x * 4 + wid; t < (NN * KK / 16); t += 16384) {
        int r0 = t << 4;
        bf16x8 bp0 = *(const bf16x8*)(feat + (size_t)(r0 + lo) * 64 + hi * 8);
        bf16x8 bp1 = *(const bf16x8*)(feat + (size_t)(r0 + lo) * 64 + 32 + hi * 8);
        f32x4 a0f[4];
        #pragma unroll
        for (int f = 0; f < 4; f++) {
            a0f[f] = __builtin_amdgcn_mfma_f32_16x16x32_bf16(wf[f * 2 + 0], bp0, zz, 0, 0, 0);
            a0f[f] = __builtin_amdgcn_mfma_f32_16x16x32_bf16(wf[f * 2 + 1], bp1, a0f[f], 0, 0, 0);
        }
        int ridx = relidx[r0 + lo];
        float val[4][4];
        float part = 0.f;
        #pragma unroll
        for (int f = 0; f < 4; f++)
            #pragma unroll
            for (int r = 0; r < 4; r++) {
                int c = 16 * f + 4 * hi + r;
                float rv = (ridx >= 0) ? w_relpos[ridx * 64 + c] : 0.f;
                float v = a0f[f][r] + rv;
                val[f][r] = v;
                part += v;
            }
        part += __shfl_xor(part, 16);
        part += __shfl_xor(part, 32);
        float mean = part * (1.f / 64.f);
        float v2 = 0.f;
        #pragma unroll
        for (int f = 0; f < 4; f++)
            #pragma unroll
            for (int r = 0; r < 4; r++) {
                float dv = val[f][r] - mean;
                val[f][r] = dv;
                v2 += dv * dv;
            }
        v2 += __shfl_xor(v2, 16);
        v2 += __shfl_xor(v2, 32);
        float rs = rsqrtf(v2 * (1.f / 64.f) + 1e-5f);
        #pragma unroll
        for (int f = 0; f < 4; f++) {
            float v0 = val[f][0] * rs * sg_r[f][0] + sbt_r[f][0];
            float v1 = val[f][1] * rs * sg_r[f][1] + sbt_r[f][1];
            float v2b = val[f][2] * rs * sg_r[f][2] + sbt_r[f][2];
            float v3 = val[f][3] * rs * sg_r[f][3] + sbt_r[f][3];
            *(uint2*)(feat + (size_t)(r0 + lo) * 64 + 16 * f + 4 * hi) =
                make_uint2(pk2(v0, v1), pk2(v2b, v3));
        }
    }
}

// ---------------- pair MLP: pln -> 128 gelu -> @W2B -> bias; frags preformatted ----------------
__global__ __launch_bounds__(256) void pair_mlp2_kernel(
    const ushort* __restrict__ pln, const ushort* __restrict__ pf,
    const float* __restrict__ b_p1, const float* __restrict__ b2b,
    float* __restrict__ bias) {
    __shared__ __align__(16) ushort hx[4 * 2048];
    int tid = threadIdx.x;
    int wid = tid >> 6, lane = tid & 63, hi = lane >> 4, lo = lane & 15;
    bf16x8 w1f[16];
    #pragma unroll
    for (int fs = 0; fs < 16; fs++) w1f[fs] = *(const bf16x8*)&pf[fs * 512 + lane * 8];
    bf16x8 w2f[4];
    #pragma unroll
    for (int s2 = 0; s2 < 4; s2++) w2f[s2] = *(const bf16x8*)&pf[8192 + s2 * 512 + lane * 8];
    float b2b_r[4];
    #pragma unroll
    for (int r = 0; r < 4; r++) b2b_r[r] = (hi < 2) ? b2b[4 * hi + r] : 0.f;
    float sb1_r[8][4];
    #pragma unroll
    for (int f = 0; f < 8; f++)
        #pragma unroll
        for (int r = 0; r < 4; r++) sb1_r[f][r] = b_p1[16 * f + 4 * hi + r];

    ushort* hxw = &hx[wid * 2048];
    const f32x4 zz = {0.f, 0.f, 0.f, 0.f};
    for (int t = blockIdx.x * 4 + wid; t < (NN * KK / 16); t += 16384) {
        int r0 = t << 4;
        bf16x8 bh0 = *(const bf16x8*)(pln + (size_t)(r0 + lo) * 64 + hi * 8);
        bf16x8 bh1 = *(const bf16x8*)(pln + (size_t)(r0 + lo) * 64 + 32 + hi * 8);
        #pragma unroll
        for (int f = 0; f < 8; f++) {
            f32x4 acch = __builtin_amdgcn_mfma_f32_16x16x32_bf16(w1f[f * 2 + 0], bh0, zz, 0, 0, 0);
            acch = __builtin_amdgcn_mfma_f32_16x16x32_bf16(w1f[f * 2 + 1], bh1, acch, 0, 0, 0);
            int c0 = 16 * f + 4 * hi;
            float v0 = gelu_f(acch[0] + sb1_r[f][0]);
            float v1 = gelu_f(acch[1] + sb1_r[f][1]);
            float v2b = gelu_f(acch[2] + sb1_r[f][2]);
            float v3 = gelu_f(acch[3] + sb1_r[f][3]);
            int idx = (lo * 128 + c0) ^ ((lo & 7) << 3);
            *(uint2*)&hxw[idx] = make_uint2(pk2(v0, v1), pk2(v2b, v3));
        }
        f32x4 acc = zz;
        #pragma unroll
        for (int s2 = 0; s2 < 4; s2++) {
            int idx = (lo * 128 + 32 * s2 + 8 * hi) ^ ((lo & 7) << 3);
            bf16x8 bh = *(const bf16x8*)&hxw[idx];
            acc = __builtin_amdgcn_mfma_f32_16x16x32_bf16(w2f[s2], bh, acc, 0, 0, 0);
        }
        if (hi < 2) {
            int n = r0 >> 5, kb = (r0 & 31) + lo;
            #pragma unroll
            for (int r = 0; r < 4; r++)
                bias[(size_t)n * 256 + (4 * hi + r) * 32 + kb] = acc[r] + b2b_r[r];
        }
    }
}

// ---------------- shared bf16 GEMM core (BN=128, fp32 A) ----------------
__device__ __forceinline__ void gemm_core(
    const float* __restrict__ A, const float* __restrict__ W,
    int K, int WN, int row0, int colW0, int tid,
    ushort* sA, ushort* sB, f32x4 acc[4][4]) {
    int wid = tid >> 6, lane = tid & 63, lo = lane & 15, hi = lane >> 4;
    int wr = wid >> 1, wc = wid & 1;
    int ar = tid >> 1, akh = (tid & 1) * 16;
    int bcol = tid & 127, bks = (tid >> 7) * 16;
    for (int kt = 0; kt < K; kt += 32) {
        const float* ap = &A[(size_t)(row0 + ar) * K + kt + akh];
        float4 a0 = *(const float4*)(ap + 0);
        float4 a1 = *(const float4*)(ap + 4);
        float4 a2 = *(const float4*)(ap + 8);
        float4 a3 = *(const float4*)(ap + 12);
        float wv[16];
        #pragma unroll
        for (int i = 0; i < 16; i++) wv[i] = W[(size_t)(kt + bks + i) * WN + colW0 + bcol];
        __syncthreads();
        *(uint4*)&sA[ar * 40 + akh] = make_uint4(pk2(a0.x, a0.y), pk2(a0.z, a0.w), pk2(a1.x, a1.y), pk2(a1.z, a1.w));
        *(uint4*)&sA[ar * 40 + akh + 8] = make_uint4(pk2(a2.x, a2.y), pk2(a2.z, a2.w), pk2(a3.x, a3.y), pk2(a3.z, a3.w));
        *(uint4*)&sB[bcol * 40 + bks] = make_uint4(pk2(wv[0], wv[1]), pk2(wv[2], wv[3]), pk2(wv[4], wv[5]), pk2(wv[6], wv[7]));
        *(uint4*)&sB[bcol * 40 + bks + 8] = make_uint4(pk2(wv[8], wv[9]), pk2(wv[10], wv[11]), pk2(wv[12], wv[13]), pk2(wv[14], wv[15]));
        __syncthreads();
        bf16x8 af[4], bfr[4];
        #pragma unroll
        for (int mi = 0; mi < 4; mi++) af[mi] = *(const bf16x8*)&sA[(wr * 64 + mi * 16 + lo) * 40 + hi * 8];
        #pragma unroll
        for (int ni = 0; ni < 4; ni++) bfr[ni] = *(const bf16x8*)&sB[(wc * 64 + ni * 16 + lo) * 40 + hi * 8];
        #pragma unroll
        for (int mi = 0; mi < 4; mi++)
            #pragma unroll
            for (int ni = 0; ni < 4; ni++)
                acc[mi][ni] = __builtin_amdgcn_mfma_f32_16x16x32_bf16(af[mi], bfr[ni], acc[mi][ni], 0, 0, 0);
    }
}

// ---------------- t1 GEMM (fp32 A, bf16 out, gelu) ----------------
__global__ __launch_bounds__(256) void gemm_t1(
    const float* __restrict__ A, const float* __restrict__ W, ushort* __restrict__ C,
    int M, int K, int Nc) {
    __shared__ __align__(16) ushort sA[128 * 40];
    __shared__ __align__(16) ushort sB[128 * 40];
    int row0 = blockIdx.y * 128, col0 = blockIdx.x * 128;
    int tid = threadIdx.x;
    const f32x4 zz = {0.f, 0.f, 0.f, 0.f};
    f32x4 acc[4][4] = {{zz, zz, zz, zz}, {zz, zz, zz, zz}, {zz, zz, zz, zz}, {zz, zz, zz, zz}};
    gemm_core(A, W, K, Nc, row0, col0, tid, sA, sB, acc);
    int wid = tid >> 6, lane = tid & 63, lo = lane & 15, hi = lane >> 4;
    int wr = wid >> 1, wc = wid & 1;
    #pragma unroll
    for (int ni = 0; ni < 4; ni++) {
        int col = col0 + wc * 64 + ni * 16 + lo;
        #pragma unroll
        for (int mi = 0; mi < 4; mi++) {
            #pragma unroll
            for (int r = 0; r < 4; r++) {
                int row = row0 + wr * 64 + mi * 16 + hi * 4 + r;
                C[(size_t)row * Nc + col] = f2bf(gelu_f(acc[mi][ni][r]));
            }
        }
    }
}

// ---------------- narrow GEMM (BM=128, BN=64) with bf16 A ----------------
__global__ __launch_bounds__(256) void gemm_n64b(
    const ushort* __restrict__ A, const float* __restrict__ W, float* __restrict__ C,
    int M, int K, int Nc,
    const float* __restrict__ bias, const float* __restrict__ addp) {
    __shared__ __align__(16) ushort sA[128 * 40];
    __shared__ __align__(16) ushort sB[64 * 40];
    int row0 = blockIdx.y * 128, col0 = blockIdx.x * 64;
    int tid = threadIdx.x;
    int wid = tid >> 6, lane = tid & 63, lo = lane & 15, hi = lane >> 4;
    int wr = wid >> 1, wc = wid & 1;
    int ar = tid >> 1, akh = (tid & 1) * 16;
    int bcol = tid & 63, bks = (tid >> 6) * 8;
    const f32x4 zz = {0.f, 0.f, 0.f, 0.f};
    f32x4 acc[4][2] = {{zz, zz}, {zz, zz}, {zz, zz}, {zz, zz}};
    for (int kt = 0; kt < K; kt += 32) {
        const ushort* ap = &A[(size_t)(row0 + ar) * K + kt + akh];
        uint4 a01 = *(const uint4*)(ap);
        uint4 a23 = *(const uint4*)(ap + 8);
        float wv[8];
        #pragma unroll
        for (int i = 0; i < 8; i++) wv[i] = W[(size_t)(kt + bks + i) * Nc + col0 + bcol];
        __syncthreads();
        *(uint4*)&sA[ar * 40 + akh] = a01;
        *(uint4*)&sA[ar * 40 + akh + 8] = a23;
        *(uint2*)&sB[bcol * 40 + bks] = make_uint2(pk2(wv[0], wv[1]), pk2(wv[2], wv[3]));
        *(uint2*)&sB[bcol * 40 + bks + 4] = make_uint2(pk2(wv[4], wv[5]), pk2(wv[6], wv[7]));
        __syncthreads();
        bf16x8 af[4], bfr[2];
        #pragma unroll
        for (int mi = 0; mi < 4; mi++) af[mi] = *(const bf16x8*)&sA[(wr * 64 + mi * 16 + lo) * 40 + hi * 8];
        #pragma unroll
        for (int ni = 0; ni < 2; ni++) bfr[ni] = *(const bf16x8*)&sB[(wc * 32 + ni * 16 + lo) * 40 + hi * 8];
        #pragma unroll
        for (int mi = 0; mi < 4; mi++)
            #pragma unroll
            for (int ni = 0; ni < 2; ni++)
                acc[mi][ni] = __builtin_amdgcn_mfma_f32_16x16x32_bf16(af[mi], bfr[ni], acc[mi][ni], 0, 0, 0);
    }
    #pragma unroll
    for (int ni = 0; ni < 2; ni++) {
        int col = col0 + wc * 32 + ni * 16 + lo;
        float bc = bias ? bias[col] : 0.f;
        #pragma unroll
        for (int mi = 0; mi < 4; mi++) {
            #pragma unroll
            for (int r = 0; r < 4; r++) {
                int row = row0 + wr * 64 + mi * 16 + hi * 4 + r;
                float v = acc[mi][ni][r] + bc;
                if (addp) v += addp[(size_t)row * Nc + col];
                C[(size_t)row * Nc + col] = v;
            }
        }
    }
}

// ---------------- fused QKV GEMM: q fp32, k/v bf16 ----------------
__global__ __launch_bounds__(256) void gemm_qkv(
    const float* __restrict__ A, const float* __restrict__ wq, const float* __restrict__ wk,
    const float* __restrict__ wvp, float* __restrict__ qb, ushort* __restrict__ kb,
    ushort* __restrict__ vb, int K) {
    __shared__ __align__(16) ushort sA[128 * 40];
    __shared__ __align__(16) ushort sB[128 * 40];
    int row0 = blockIdx.y * 128, col0 = blockIdx.x * 128;
    int wsel = col0 >> 8, colW0 = col0 & 255;
    const float* W = (wsel == 0) ? wq : (wsel == 1) ? wk : wvp;
    int tid = threadIdx.x;
    const f32x4 zz = {0.f, 0.f, 0.f, 0.f};
    f32x4 acc[4][4] = {{zz, zz, zz, zz}, {zz, zz, zz, zz}, {zz, zz, zz, zz}, {zz, zz, zz, zz}};
    gemm_core(A, W, K, 256, row0, colW0, tid, sA, sB, acc);
    int wid = tid >> 6, lane = tid & 63, lo = lane & 15, hi = lane >> 4;
    int wr = wid >> 1, wc = wid & 1;
    #pragma unroll
    for (int ni = 0; ni < 4; ni++) {
        int colW = colW0 + wc * 64 + ni * 16 + lo;
        #pragma unroll
        for (int mi = 0; mi < 4; mi++) {
            #pragma unroll
            for (int r = 0; r < 4; r++) {
                int row = row0 + wr * 64 + mi * 16 + hi * 4 + r;
                float v = acc[mi][ni][r];
                if (wsel == 0) qb[(size_t)row * 256 + colW] = v;
                else if (wsel == 1) kb[(size_t)row * 256 + colW] = f2bf(v);
                else vb[(size_t)row * 256 + colW] = f2bf(v);
            }
        }
    }
}

// ---------------- fused FFN GEMM: up (no gelu) + lg/cg/bg (gelu); bf16 outputs ----------------
__global__ __launch_bounds__(256) void gemm_ffn(
    const float* __restrict__ A,
    const float* __restrict__ w0, const float* __restrict__ w1,
    const float* __restrict__ w2, const float* __restrict__ w3,
    ushort* __restrict__ o0, ushort* __restrict__ o1,
    ushort* __restrict__ o2, ushort* __restrict__ o3, int K) {
    __shared__ __align__(16) ushort sA[128 * 40];
    __shared__ __align__(16) ushort sB[128 * 40];
    int row0 = blockIdx.y * 128, col0 = blockIdx.x * 128;
    int wsel = col0 >> 9, colW0 = col0 & 511;
    const float* W = (wsel == 0) ? w0 : (wsel == 1) ? w1 : (wsel == 2) ? w2 : w3;
    ushort* O = (wsel == 0) ? o0 : (wsel == 1) ? o1 : (wsel == 2) ? o2 : o3;
    int tid = threadIdx.x;
    const f32x4 zz = {0.f, 0.f, 0.f, 0.f};
    f32x4 acc[4][4] = {{zz, zz, zz, zz}, {zz, zz, zz, zz}, {zz, zz, zz, zz}, {zz, zz, zz, zz}};
    gemm_core(A, W, K, 512, row0, colW0, tid, sA, sB, acc);
    int wid = tid >> 6, lane = tid & 63, lo = lane & 15, hi = lane >> 4;
    int wr = wid >> 1, wc = wid & 1;
    #pragma unroll
    for (int ni = 0; ni < 4; ni++) {
        int colW = colW0 + wc * 64 + ni * 16 + lo;
        #pragma unroll
        for (int mi = 0; mi < 4; mi++) {
            #pragma unroll
            for (int r = 0; r < 4; r++) {
                int row = row0 + wr * 64 + mi * 16 + hi * 4 + r;
                float v = acc[mi][ni][r];
                if (wsel > 0) v = gelu_f(v);
                O[(size_t)row * 512 + colW] = f2bf(v);
            }
        }
    }
}

// ---------------- attention: QK direct-gather + V staged through LDS; bf16 out ----------------
__global__ __launch_bounds__(256) void attn_kernel(
    const float* __restrict__ q, const ushort* __restrict__ kp, const ushort* __restrict__ vp,
    const float* __restrict__ bias, const int* __restrict__ nbr, ushort* __restrict__ o) {
    int n = blockIdx.x;
    __shared__ float qs[256];
    __shared__ int js[32];
    __shared__ float ls[256];
    __shared__ __align__(16) uint4 vs[32 * 33];
    int t = threadIdx.x;
    qs[t] = q[(size_t)n * 256 + t];
    if (t < 32) js[t] = nbr[n * 32 + t];
    __syncthreads();
    int vrow = t >> 3, vseg = t & 7;
    const uint4* vsrc = (const uint4*)(vp + (size_t)js[vrow] * 256);
    uint4 vr0 = vsrc[vseg * 4 + 0];
    uint4 vr1 = vsrc[vseg * 4 + 1];
    uint4 vr2 = vsrc[vseg * 4 + 2];
    uint4 vr3 = vsrc[vseg * 4 + 3];
    int h = t >> 5, k = t & 31;
    int j = js[k];
    const bf16x8* kr = (const bf16x8*)(kp + (size_t)j * 256 + h * 32);
    bf16x8 kv0 = kr[0], kv1 = kr[1], kv2 = kr[2], kv3 = kr[3];
    const float* qh = qs + h * 32;
    float dot = 0.f;
    #pragma unroll
    for (int i = 0; i < 8; i++) dot += qh[i] * bf2f((ushort)kv0[i]);
    #pragma unroll
    for (int i = 0; i < 8; i++) dot += qh[8 + i] * bf2f((ushort)kv1[i]);
    #pragma unroll
    for (int i = 0; i < 8; i++) dot += qh[16 + i] * bf2f((ushort)kv2[i]);
    #pragma unroll
    for (int i = 0; i < 8; i++) dot += qh[24 + i] * bf2f((ushort)kv3[i]);
    float l = dot * 0.17677669529663687f + bias[(size_t)n * 256 + t];
    float mx = l;
    #pragma unroll
    for (int m = 16; m > 0; m >>= 1) mx = fmaxf(mx, __shfl_xor(mx, m));
    float e = __expf(l - mx);
    float sum = e;
    #pragma unroll
    for (int m = 16; m > 0; m >>= 1) sum += __shfl_xor(sum, m);
    ls[t] = e / sum;
    vs[vrow * 33 + vseg * 4 + 0] = vr0;
    vs[vrow * 33 + vseg * 4 + 1] = vr1;
    vs[vrow * 33 + vseg * 4 + 2] = vr2;
    vs[vrow * 33 + vseg * 4 + 3] = vr3;
    __syncthreads();
    const ushort* vsu = (const ushort*)vs;
    const float* lh = ls + h * 32;
    float acc = 0.f;
    #pragma unroll
    for (int kk = 0; kk < 32; kk++)
        acc += lh[kk] * bf2f(vsu[kk * 264 + h * 32 + k]);
    o[(size_t)n * 256 + t] = f2bf(acc);
}

// ---------------- LN(a+b) with sum output ----------------
__global__ __launch_bounds__(256) void ln_add_kernel(
    const float* __restrict__ a, const float* __restrict__ b,
    const float* __restrict__ g, const float* __restrict__ be,
    float* __restrict__ xout, float* __restrict__ sout) {
    int row = blockIdx.x * 4 + (threadIdx.x >> 6);
    int lane = threadIdx.x & 63;
    size_t base = (size_t)row * 256 + lane * 4;
    float4 av = *(const float4*)(a + base);
    float4 bv = *(const float4*)(b + base);
    float s0 = av.x + bv.x, s1 = av.y + bv.y, s2 = av.z + bv.z, s3 = av.w + bv.w;
    float sum = wave_sum64(s0 + s1 + s2 + s3);
    float mean = sum * (1.f / 256.f);
    float d0 = s0 - mean, d1 = s1 - mean, d2 = s2 - mean, d3 = s3 - mean;
    float v = wave_sum64(d0 * d0 + d1 * d1 + d2 * d2 + d3 * d3);
    float rs = rsqrtf(v * (1.f / 256.f) + 1e-5f);
    float4 gv = *(const float4*)(g + lane * 4);
    float4 bev = *(const float4*)(be + lane * 4);
    float4 xo;
    xo.x = d0 * rs * gv.x + bev.x;
    xo.y = d1 * rs * gv.y + bev.y;
    xo.z = d2 * rs * gv.z + bev.z;
    xo.w = d3 * rs * gv.w + bev.w;
    *(float4*)(xout + base) = xo;
    float4 so; so.x = s0; so.y = s1; so.z = s2; so.w = s3;
    *(float4*)(sout + base) = so;
}

// ---------------- segment means: phase 1 partial sums (atomic, bf16 input) ----------------
__global__ __launch_bounds__(256) void seg_partial_kernel(
    const ushort* __restrict__ up, const int* __restrict__ batch, const int* __restrict__ chain,
    float* __restrict__ mb_acc, float* __restrict__ mc_acc) {
    int r0 = blockIdx.x * 32;
    int t = threadIdx.x;
    float ab0 = 0.f, ab1 = 0.f, ac0 = 0.f, ac1 = 0.f;
    int curb = batch[r0], curc = chain[r0];
    for (int r = r0; r < r0 + 32; r++) {
        int b = batch[r], c = chain[r];
        if (b != curb) {
            atomicAdd(&mb_acc[curb * 512 + t], ab0);
            atomicAdd(&mb_acc[curb * 512 + 256 + t], ab1);
            ab0 = ab1 = 0.f; curb = b;
        }
        if (c != curc) {
            atomicAdd(&mc_acc[curc * 512 + t], ac0);
            atomicAdd(&mc_acc[curc * 512 + 256 + t], ac1);
            ac0 = ac1 = 0.f; curc = c;
        }
        float v0 = bf2f(up[(size_t)r * 512 + t]);
        float v1 = bf2f(up[(size_t)r * 512 + 256 + t]);
        ab0 += v0; ab1 += v1; ac0 += v0; ac1 += v1;
    }
    atomicAdd(&mb_acc[curb * 512 + t], ab0);
    atomicAdd(&mb_acc[curb * 512 + 256 + t], ab1);
    atomicAdd(&mc_acc[curc * 512 + t], ac0);
    atomicAdd(&mc_acc[curc * 512 + 256 + t], ac1);
}

// ---------------- segment means: phase 2 divide by counts ----------------
__device__ __forceinline__ int lower_bound_i(const int* a, int n, int v) {
    int lo = 0, hi = n;
    while (lo < hi) { int mid = (lo + hi) >> 1; if (a[mid] < v) lo = mid + 1; else hi = mid; }
    return lo;
}

__global__ __launch_bounds__(256) void seg_final_kernel(
    float* __restrict__ mb, float* __restrict__ mc,
    const int* __restrict__ batch, const int* __restrict__ chain) {
    int idx = blockIdx.x * 256 + threadIdx.x;
    if (idx < NBATCH * 512) {
        int seg = idx >> 9;
        int lo = lower_bound_i(batch, NN, seg);
        int hi = lower_bound_i(batch, NN, seg + 1);
        mb[idx] *= 1.f / fmaxf((float)(hi - lo), 1.f);
    } else {
        int i2 = idx - NBATCH * 512;
        int seg = i2 >> 9;
        int lo = lower_bound_i(chain, NN, seg);
        int hi = lower_bound_i(chain, NN, seg + 1);
        mc[i2] *= 1.f / fmaxf((float)(hi - lo), 1.f);
    }
}

// ---------------- hidden combine (bf16 in/out, x4 vectorized) ----------------
__global__ __launch_bounds__(256) void hidden_kernel(
    const ushort* __restrict__ up, const ushort* __restrict__ cg, const ushort* __restrict__ bg,
    ushort* __restrict__ lg, const float* __restrict__ mb, const float* __restrict__ mc,
    const int* __restrict__ batch, const int* __restrict__ chain) {
    size_t e4 = ((size_t)blockIdx.x * 256 + threadIdx.x) * 4;
    int n = (int)(e4 >> 9), d = (int)(e4 & 511);
    float4 mbv = *(const float4*)&mb[batch[n] * 512 + d];
    float4 mcv = *(const float4*)&mc[chain[n] * 512 + d];
    uint2 u_up = *(const uint2*)&up[e4];
    uint2 u_cg = *(const uint2*)&cg[e4];
    uint2 u_bg = *(const uint2*)&bg[e4];
    uint2 u_lg = *(const uint2*)&lg[e4];
    float h0 = bf2f((ushort)u_bg.x) * mbv.x + bf2f((ushort)u_cg.x) * mcv.x
             + bf2f((ushort)u_lg.x) * bf2f((ushort)u_up.x);
    float h1 = bf2f((ushort)(u_bg.x >> 16)) * mbv.y + bf2f((ushort)(u_cg.x >> 16)) * mcv.y
             + bf2f((ushort)(u_lg.x >> 16)) * bf2f((ushort)(u_up.x >> 16));
    float h2 = bf2f((ushort)u_bg.y) * mbv.z + bf2f((ushort)u_cg.y) * mcv.z
             + bf2f((ushort)u_lg.y) * bf2f((ushort)u_up.y);
    float h3 = bf2f((ushort)(u_bg.y >> 16)) * mbv.w + bf2f((ushort)(u_cg.y >> 16)) * mcv.w
             + bf2f((ushort)(u_lg.y >> 16)) * bf2f((ushort)(u_up.y >> 16));
    *(uint2*)&lg[e4] = make_uint2(pk2(h0, h1), pk2(h2, h3));
}

// ---------------- final ----------------
__global__ __launch_bounds__(256) void final_kernel(
    const float* __restrict__ x1, const float* __restrict__ y2, const float* __restrict__ inc1,
    const float* __restrict__ ug, const float* __restrict__ ub,
    const float* __restrict__ fg, const float* __restrict__ fb, float* __restrict__ out) {
    int row = blockIdx.x * 4 + (threadIdx.x >> 6);
    int lane = threadIdx.x & 63;
    size_t base = (size_t)row * 256 + lane * 4;
    float4 xv = *(const float4*)(x1 + base);
    float4 yv = *(const float4*)(y2 + base);
    float4 iv = *(const float4*)(inc1 + base);
    float s0 = xv.x + yv.x, s1 = xv.y + yv.y, s2 = xv.z + yv.z, s3 = xv.w + yv.w;
    float t0 = iv.x + yv.x, t1 = iv.y + yv.y, t2 = iv.z + yv.z, t3 = iv.w + yv.w;
    float sums = wave_sum64(s0 + s1 + s2 + s3);
    float means = sums * (1.f / 256.f);
    float sd0 = s0 - means, sd1 = s1 - means, sd2 = s2 - means, sd3 = s3 - means;
    float vs = wave_sum64(sd0 * sd0 + sd1 * sd1 + sd2 * sd2 + sd3 * sd3);
    float rss = rsqrtf(vs * (1.f / 256.f) + 1e-5f);
    float sumt = wave_sum64(t0 + t1 + t2 + t3);
    float meant = sumt * (1.f / 256.f);
    float td0 = t0 - meant, td1 = t1 - meant, td2 = t2 - meant, td3 = t3 - meant;
    float vt = wave_sum64(td0 * td0 + td1 * td1 + td2 * td2 + td3 * td3);
    float rst = rsqrtf(vt * (1.f / 256.f) + 1e-5f);
    float4 ugv = *(const float4*)(ug + lane * 4);
    float4 ubv = *(const float4*)(ub + lane * 4);
    float4 fgv = *(const float4*)(fg + lane * 4);
    float4 fbv = *(const float4*)(fb + lane * 4);
    float4 ov;
    ov.x = (sd0 * rss * ugv.x + ubv.x) + (td0 * rst * fgv.x + fbv.x);
    ov.y = (sd1 * rss * ugv.y + ubv.y) + (td1 * rst * fgv.y + fbv.y);
    ov.z = (sd2 * rss * ugv.z + ubv.z) + (td2 * rst * fgv.z + fbv.z);
    ov.w = (sd3 * rss * ugv.w + ubv.w) + (td3 * rst * fgv.w + fbv.w);
    *(float4*)(out + base) = ov;
}

// ---------------- launch ----------------
extern "C" void kernel_launch(void* const* d_in, const int* in_sizes, int n_in,
                              void* d_out, int out_size, void* d_ws, size_t ws_size,
                              hipStream_t stream) {
    const float* local    = (const float*)d_in[0];
    const float* pos      = (const float*)d_in[1];
    const int*   nbr      = (const int*)d_in[2];
    const int*   resi     = (const int*)d_in[3];
    const int*   chain    = (const int*)d_in[4];
    const int*   batch    = (const int*)d_in[5];
    const float* w_relpos = (const float*)d_in[7];
    const float* w_dist   = (const float*)d_in[8];
    const float* w_dir    = (const float*)d_in[9];
    const float* w_rot    = (const float*)d_in[10];
    const float* ln_pair_g = (const float*)d_in[11];
    const float* ln_pair_b = (const float*)d_in[12];
    const float* w_p1     = (const float*)d_in[13];
    const float* b_p1     = (const float*)d_in[14];
    const float* w_p2     = (const float*)d_in[15];
    const float* b_p2     = (const float*)d_in[16];
    const float* wq       = (const float*)d_in[17];
    const float* wk       = (const float*)d_in[18];
    const float* wv       = (const float*)d_in[19];
    const float* wb       = (const float*)d_in[20];
    const float* wo       = (const float*)d_in[21];
    const float* ln_a_g   = (const float*)d_in[22];
    const float* ln_a_b   = (const float*)d_in[23];
    const float* w_t1     = (const float*)d_in[24];
    const float* w_t2     = (const float*)d_in[25];
    const float* w_up     = (const float*)d_in[26];
    const float* w_lg     = (const float*)d_in[27];
    const float* w_cg     = (const float*)d_in[28];
    const float* w_bg     = (const float*)d_in[29];
    const float* w_out    = (const float*)d_in[30];
    const float* b_out    = (const float*)d_in[31];
    const float* ln_u_g   = (const float*)d_in[32];
    const float* ln_u_b   = (const float*)d_in[33];
    const float* ln_f_g   = (const float*)d_in[34];
    const float* ln_f_b   = (const float*)d_in[35];

    float* ws = (float*)d_ws;
    float* R         = ws + 0;             // 9N -> 73728
    float* biasb     = ws + 73728;         // N*256 -> 2170880
    float* tfeat_out = ws + 2170880;       // N*256 fp32 -> 4268032
    float* x1        = ws + 4268032;       // N*256 -> 6365184
    float* inc1      = ws + 6365184;       // N*256 -> 8462336
    ushort* featb    = (ushort*)(ws + 8462336);  // N*K*64 bf16 (phase 1; becomes pln in-place)
    int* relidx      = (int*)(ws + 16850944);    // N*K
    float* tfeat_raw = ws + 17113088;      // N*608 fp32 (phase 1)
    ushort* pfmt     = (ushort*)(ws + 22093824); // 14336 ushorts (phase 1a; consumed before t1)
    ushort* tmp512u  = (ushort*)(ws + 22101824); // N*512 bf16 (phase 1b, after pfmt region)
    float* qb        = ws + 8462336;       // N*256 fp32 (phase 2, over featb)
    ushort* kbu      = (ushort*)(ws + 10559488); // N*256 bf16
    ushort* vbu      = (ushort*)(ws + 12656640); // N*256 bf16
    ushort* obu      = (ushort*)(ws + 14753792); // N*256 bf16
    float* yb        = ws + 24199232;      // N*256 fp32 (after tmp512u region)
    ushort* upbu     = (ushort*)(ws + 8462336);  // N*512 bf16 (phase 3)
    ushort* lgbu     = (ushort*)(ws + 12656640); // N*512 bf16
    ushort* cgbu     = (ushort*)(ws + 17113088); // N*512 bf16
    ushort* bgbu     = (ushort*)(ws + 21307392); // N*512 bf16
    float* mb        = ws + 26296384;      // 32*512 (phase 3)
    float* mc        = ws + 26312768;      // 64*512 (phase 3)
    float* y2        = ws + 26345536;      // N*256
    float* w2b       = ws + 26296384;      // 128*8 (phase 1; overlaps mb, consumed before memset)
    float* b2b       = ws + 26297408;      // 8

    frames_kernel<<<NN / 256, 256, 0, stream>>>(pos, R);
    w2b_kernel<<<4, 256, 0, stream>>>(w_p2, b_p2, wb, w2b, b2b);
    fmt_kernel<<<28, 256, 0, stream>>>(w_p1, w_dist, w_dir, w_rot, w2b, pfmt);
    pair_raw_kernel<<<NN * KK / 256, 256, 0, stream>>>(pos, nbr, resi, chain, R,
                                                       featb, relidx, tfeat_raw);
    pair_pre_kernel<<<4096, 256, 0, stream>>>(featb, relidx, w_relpos, pfmt,
                                              ln_pair_g, ln_pair_b);
    pair_mlp2_kernel<<<4096, 256, 0, stream>>>(featb, pfmt, b_p1, b2b, biasb);
    // tfeat MLP (t1 -> bf16, t2 bf16-A)
    gemm_t1<<<dim3(4, 64), 256, 0, stream>>>(tfeat_raw, w_t1, tmp512u, NN, 608, 512);
    gemm_n64b<<<dim3(4, 64), 256, 0, stream>>>(tmp512u, w_t2, tfeat_out, NN, 512, 256, nullptr, nullptr);
    // fused qkv projection (q fp32, k/v bf16)
    gemm_qkv<<<dim3(6, 64), 256, 0, stream>>>(local, wq, wk, wv, qb, kbu, vbu, 256);
    attn_kernel<<<NN, 256, 0, stream>>>(qb, kbu, vbu, biasb, nbr, obu);
    gemm_n64b<<<dim3(4, 64), 256, 0, stream>>>(obu, wo, yb, NN, 256, 256, nullptr, nullptr);
    ln_add_kernel<<<NN / 4, 256, 0, stream>>>(local, yb, ln_a_g, ln_a_b, x1, inc1);
    // fused FFN projections (bf16 outs)
    gemm_ffn<<<dim3(16, 64), 256, 0, stream>>>(x1, w_up, w_lg, w_cg, w_bg,
                                               upbu, lgbu, cgbu, bgbu, 256);
    // segment means: zero accumulators, partial (atomic), finalize
    (void)hipMemsetAsync(mb, 0, (NBATCH + NCHAIN) * 512 * sizeof(float), stream);
    seg_partial_kernel<<<NN / 32, 256, 0, stream>>>(upbu, batch, chain, mb, mc);
    seg_final_kernel<<<(NBATCH + NCHAIN) * 512 / 256, 256, 0, stream>>>(mb, mc, batch, chain);
    hidden_kernel<<<NN * 512 / 1024, 256, 0, stream>>>(upbu, cgbu, bgbu, lgbu, mb, mc, batch, chain);
    gemm_n64b<<<dim3(4, 64), 256, 0, stream>>>(lgbu, w_out, y2, NN, 512, 256, b_out, tfeat_out);
    final_kernel<<<NN / 4, 256, 0, stream>>>(x1, y2, inc1, ln_u_g, ln_u_b, ln_f_g, ln_f_b, (float*)d_out);
}

// Round 13
// 269.302 us; speedup vs baseline: 1.4861x; 1.0937x over previous
//
#include <hip/hip_runtime.h>
#include <math.h>

#define NN 8192
#define KK 32
#define DD 256
#define PP 64
#define HH 8
#define DHH 32
#define NBATCH 32
#define NCHAIN 64

typedef __attribute__((ext_vector_type(8))) short bf16x8;
typedef __attribute__((ext_vector_type(4))) float f32x4;

// ---------------- helpers ----------------
__device__ __forceinline__ float gelu_f(float x) {
    float x3 = x * x * x;
    float e = __expf(fmaf(x3, -0.07135481f, x * -1.59576912f));
    return __fdividef(x, 1.f + e);
}

__device__ __forceinline__ float wave_sum64(float v) {
    #pragma unroll
    for (int m = 32; m > 0; m >>= 1) v += __shfl_xor(v, m);
    return v;
}

__device__ __forceinline__ ushort f2bf(float x) {
    union { float f; unsigned int u; } v; v.f = x;
    unsigned int r = v.u + 0x7fffu + ((v.u >> 16) & 1u);
    return (ushort)(r >> 16);
}

__device__ __forceinline__ float bf2f(ushort u) {
    union { unsigned int u; float f; } v; v.u = ((unsigned int)u) << 16;
    return v.f;
}

__device__ __forceinline__ uint pk2(float a, float b) {
    return (uint)f2bf(a) | ((uint)f2bf(b) << 16);
}

// ---------------- frames ----------------
__global__ __launch_bounds__(256) void frames_kernel(const float* __restrict__ pos,
                                                     float* __restrict__ R) {
    int n = blockIdx.x * 256 + threadIdx.x;
    if (n >= NN) return;
    const float* p = pos + n * 15;
    float nx = p[0], ny = p[1], nz = p[2];
    float cax = p[3], cay = p[4], caz = p[5];
    float cx = p[6], cy = p[7], cz = p[8];
    float e1x = cx - cax, e1y = cy - cay, e1z = cz - caz;
    float inv = rsqrtf(e1x * e1x + e1y * e1y + e1z * e1z + 1e-8f);
    e1x *= inv; e1y *= inv; e1z *= inv;
    float ux = nx - cax, uy = ny - cay, uz = nz - caz;
    float dt = ux * e1x + uy * e1y + uz * e1z;
    float e2x = ux - dt * e1x, e2y = uy - dt * e1y, e2z = uz - dt * e1z;
    inv = rsqrtf(e2x * e2x + e2y * e2y + e2z * e2z + 1e-8f);
    e2x *= inv; e2y *= inv; e2z *= inv;
    float e3x = e1y * e2z - e1z * e2y;
    float e3y = e1z * e2x - e1x * e2z;
    float e3z = e1x * e2y - e1y * e2x;
    float* r = R + n * 9;
    r[0] = e1x; r[1] = e2x; r[2] = e3x;
    r[3] = e1y; r[4] = e2y; r[5] = e3y;
    r[6] = e1z; r[7] = e2z; r[8] = e3z;
}

// ---------------- raw pair features (lane = one (n,k) pair); tfeat bf16 ----------------
__global__ __launch_bounds__(256) void pair_raw_kernel(
    const float* __restrict__ pos, const int* __restrict__ nbr,
    const int* __restrict__ resi, const int* __restrict__ chain,
    const float* __restrict__ R,
    ushort* __restrict__ feat, int* __restrict__ relidx, ushort* __restrict__ tfb) {
    int p = blockIdx.x * 256 + threadIdx.x;
    int n = p >> 5, k = p & 31;
    int j = nbr[p];
    int same = (chain[j] == chain[n]);
    int off = min(max(resi[j] - resi[n], -32), 32) + 32;
    relidx[p] = same ? off : -1;

    float can0 = pos[n * 15 + 3], can1 = pos[n * 15 + 4], can2 = pos[n * 15 + 5];
    float cbn0 = pos[n * 15 + 12], cbn1 = pos[n * 15 + 13], cbn2 = pos[n * 15 + 14];
    float Rn[9], Rj[9];
    #pragma unroll
    for (int i = 0; i < 9; i++) Rn[i] = R[n * 9 + i];
    #pragma unroll
    for (int i = 0; i < 9; i++) Rj[i] = R[j * 9 + i];
    float pj[15];
    #pragma unroll
    for (int i = 0; i < 15; i++) pj[i] = pos[j * 15 + i];

    float fe[43];
    float d0 = pj[12] - cbn0, d1 = pj[13] - cbn1, d2 = pj[14] - cbn2;
    float dcb = sqrtf(d0 * d0 + d1 * d1 + d2 * d2 + 1e-8f);
    #pragma unroll
    for (int i = 0; i < 16; i++) {
        float c = (22.f / 15.f) * (float)i;
        float z = (dcb - c) * (1.f / 1.375f);
        fe[i] = __expf(-z * z);
    }
    #pragma unroll
    for (int a = 0; a < 5; a++) {
        float vx = pj[a * 3 + 0] - can0;
        float vy = pj[a * 3 + 1] - can1;
        float vz = pj[a * 3 + 2] - can2;
        float invv = rsqrtf(vx * vx + vy * vy + vz * vz + 1e-8f);
        fe[16 + a * 3 + 0] = vx * invv;
        fe[16 + a * 3 + 1] = vy * invv;
        fe[16 + a * 3 + 2] = vz * invv;
    }
    #pragma unroll
    for (int b = 0; b < 3; b++)
        #pragma unroll
        for (int c2 = 0; c2 < 3; c2++)
            fe[31 + b * 3 + c2] = Rn[0 + b] * Rj[0 + c2] + Rn[3 + b] * Rj[3 + c2] + Rn[6 + b] * Rj[6 + c2];
    float t0 = pj[3] - can0, t1 = pj[4] - can1, t2 = pj[5] - can2;
    #pragma unroll
    for (int b = 0; b < 3; b++)
        fe[40 + b] = Rn[0 + b] * t0 + Rn[3 + b] * t1 + Rn[6 + b] * t2;

    #pragma unroll
    for (int q = 0; q < 8; q++) {
        uint4 w;
        float v0 = (q * 8 + 0 < 43) ? fe[q * 8 + 0] : 0.f;
        float v1 = (q * 8 + 1 < 43) ? fe[q * 8 + 1] : 0.f;
        float v2 = (q * 8 + 2 < 43) ? fe[q * 8 + 2] : 0.f;
        float v3 = (q * 8 + 3 < 43) ? fe[q * 8 + 3] : 0.f;
        float v4 = (q * 8 + 4 < 43) ? fe[q * 8 + 4] : 0.f;
        float v5 = (q * 8 + 5 < 43) ? fe[q * 8 + 5] : 0.f;
        float v6 = (q * 8 + 6 < 43) ? fe[q * 8 + 6] : 0.f;
        float v7 = (q * 8 + 7 < 43) ? fe[q * 8 + 7] : 0.f;
        w.x = pk2(v0, v1); w.y = pk2(v2, v3); w.z = pk2(v4, v5); w.w = pk2(v6, v7);
        *(uint4*)&feat[(size_t)p * 64 + q * 8] = w;
    }
    float rt0 = fe[40], rt1 = fe[41], rt2 = fe[42];
    float dr2 = rt0 * rt0 + rt1 * rt1 + rt2 * rt2 + 1e-8f;
    float invdr = rsqrtf(dr2);
    float drel = dr2 * invdr;
    ushort* tf = tfb + (size_t)n * 608 + k * 19;
    #pragma unroll
    for (int i = 0; i < 16; i++) {
        float c = (22.f / 15.f) * (float)i;
        float z = (drel - c) * (1.f / 1.375f);
        tf[i] = f2bf(__expf(-z * z));
    }
    tf[16] = f2bf(rt0 * invdr);
    tf[17] = f2bf(rt1 * invdr);
    tf[18] = f2bf(rt2 * invdr);
}

// ---------------- W2B = w_p2 @ wb  [128x8], b2b = b_p2 @ wb [8] ----------------
__global__ __launch_bounds__(256) void w2b_kernel(
    const float* __restrict__ w_p2, const float* __restrict__ b_p2,
    const float* __restrict__ wb, float* __restrict__ w2b, float* __restrict__ b2b) {
    int idx = blockIdx.x * 256 + threadIdx.x;
    if (idx < 1024) {
        int c = idx >> 3, h = idx & 7;
        float s = 0.f;
        for (int q = 0; q < 64; q++) s += w_p2[c * 64 + q] * wb[q * 8 + h];
        w2b[idx] = s;
    }
    if (idx < 8) {
        float s = 0.f;
        for (int q = 0; q < 64; q++) s += b_p2[q] * wb[q * 8 + idx];
        b2b[idx] = s;
    }
}

// ---------------- fmt: preformat pair MFMA weight fragments ----------------
__global__ __launch_bounds__(256) void fmt_kernel(
    const float* __restrict__ w_p1,
    const float* __restrict__ w_dist, const float* __restrict__ w_dir,
    const float* __restrict__ w_rot, const float* __restrict__ w2b,
    ushort* __restrict__ pf) {
    int u = blockIdx.x * 256 + threadIdx.x;
    uint* pfu = (uint*)pf;
    if (u < 4096) {
        int fs = u >> 8, rem = u & 255, lane = rem >> 2, jj = rem & 3;
        int hi = lane >> 4, lo = lane & 15;
        int f = fs >> 1, s = fs & 1;
        int k0 = 32 * s + hi * 8 + 2 * jj;
        int c = 16 * f + lo;
        pfu[u] = pk2(w_p1[k0 * 128 + c], w_p1[(k0 + 1) * 128 + c]);
    } else if (u < 5120) {
        int u2 = u - 4096;
        int s2 = u2 >> 8, rem = u2 & 255, lane = rem >> 2, jj = rem & 3;
        int hi = lane >> 4, lo = lane & 15;
        int c0 = 32 * s2 + 8 * hi + 2 * jj;
        float v0 = (lo < 8) ? w2b[c0 * 8 + lo] : 0.f;
        float v1 = (lo < 8) ? w2b[(c0 + 1) * 8 + lo] : 0.f;
        pfu[u] = pk2(v0, v1);
    } else if (u < 7168) {
        int u2 = u - 5120;
        int fs = u2 >> 8, rem = u2 & 255, lane = rem >> 2, jj = rem & 3;
        int hi = lane >> 4, lo = lane & 15;
        int f = fs >> 1, s = fs & 1;
        int k0 = 32 * s + hi * 8 + 2 * jj;
        int c = 16 * f + lo;
        float v0 = (k0 < 16) ? w_dist[k0 * 64 + c] : (k0 < 31) ? w_dir[(k0 - 16) * 64 + c]
                 : (k0 < 43) ? w_rot[(k0 - 31) * 64 + c] : 0.f;
        int k1 = k0 + 1;
        float v1 = (k1 < 16) ? w_dist[k1 * 64 + c] : (k1 < 31) ? w_dir[(k1 - 16) * 64 + c]
                 : (k1 < 43) ? w_rot[(k1 - 31) * 64 + c] : 0.f;
        pfu[u] = pk2(v0, v1);
    }
}

// ---------------- fmt_wt: convert all GEMM weights to bf16 transposed Wt[n][k] ----------------
__global__ __launch_bounds__(256) void fmt_wt_kernel(
    const float* __restrict__ w0, const float* __restrict__ w1,
    const float* __restrict__ w2, const float* __restrict__ w3,
    const float* __restrict__ w4, const float* __restrict__ w5,
    const float* __restrict__ w6, const float* __restrict__ w7,
    const float* __restrict__ w8, const float* __restrict__ w9,
    const float* __restrict__ w10, ushort* __restrict__ wt) {
    __shared__ ushort tile[32][33];
    int z = blockIdx.z;
    const float* W; int K, N; size_t off;
    switch (z) {
        case 0:  W = w0;  K = 256; N = 512; off = 0;       break;
        case 1:  W = w1;  K = 256; N = 512; off = 131072;  break;
        case 2:  W = w2;  K = 256; N = 512; off = 262144;  break;
        case 3:  W = w3;  K = 256; N = 512; off = 393216;  break;
        case 4:  W = w4;  K = 256; N = 256; off = 524288;  break;
        case 5:  W = w5;  K = 256; N = 256; off = 589824;  break;
        case 6:  W = w6;  K = 256; N = 256; off = 655360;  break;
        case 7:  W = w7;  K = 608; N = 512; off = 720896;  break;
        case 8:  W = w8;  K = 512; N = 256; off = 1032192; break;
        case 9:  W = w9;  K = 256; N = 256; off = 1163264; break;
        default: W = w10; K = 512; N = 256; off = 1228800; break;
    }
    int bk = blockIdx.y * 32, bn = blockIdx.x * 32;
    if (bk >= K || bn >= N) return;
    int tx = threadIdx.x & 31, ty = threadIdx.x >> 5;
    #pragma unroll
    for (int i = 0; i < 32; i += 8)
        tile[ty + i][tx] = f2bf(W[(size_t)(bk + ty + i) * N + bn + tx]);
    __syncthreads();
    #pragma unroll
    for (int i = 0; i < 32; i += 8)
        wt[off + (size_t)(bn + ty + i) * K + bk + tx] = tile[tx][ty + i];
}

// ---------------- convert fp32 -> bf16 (x4) ----------------
__global__ __launch_bounds__(256) void convb_kernel(const float* __restrict__ src,
                                                    ushort* __restrict__ dst) {
    size_t i4 = ((size_t)blockIdx.x * 256 + threadIdx.x) * 4;
    float4 v = *(const float4*)&src[i4];
    *(uint2*)&dst[i4] = make_uint2(pk2(v.x, v.y), pk2(v.z, v.w));
}

// ---------------- pair stage0 ----------------
__global__ __launch_bounds__(256) void pair_pre_kernel(
    ushort* feat, const int* __restrict__ relidx,
    const float* __restrict__ w_relpos, const ushort* __restrict__ pf,
    const float* __restrict__ lng, const float* __restrict__ lnb) {
    int tid = threadIdx.x;
    int wid = tid >> 6, lane = tid & 63, hi = lane >> 4, lo = lane & 15;
    bf16x8 wf[8];
    #pragma unroll
    for (int fs = 0; fs < 8; fs++) wf[fs] = *(const bf16x8*)&pf[10240 + fs * 512 + lane * 8];
    float sg_r[4][4], sbt_r[4][4];
    #pragma unroll
    for (int f = 0; f < 4; f++)
        #pragma unroll
        for (int r = 0; r < 4; r++) {
            int c = 16 * f + 4 * hi + r;
            sg_r[f][r] = lng[c];
            sbt_r[f][r] = lnb[c];
        }
    const f32x4 zz = {0.f, 0.f, 0.f, 0.f};
    for (int t = blockIdx.x * 4 + wid; t < (NN * KK / 16); t += 16384) {
        int r0 = t << 4;
        bf16x8 bp0 = *(const bf16x8*)(feat + (size_t)(r0 + lo) * 64 + hi * 8);
        bf16x8 bp1 = *(const bf16x8*)(feat + (size_t)(r0 + lo) * 64 + 32 + hi * 8);
        f32x4 a0f[4];
        #pragma unroll
        for (int f = 0; f < 4; f++) {
            a0f[f] = __builtin_amdgcn_mfma_f32_16x16x32_bf16(wf[f * 2 + 0], bp0, zz, 0, 0, 0);
            a0f[f] = __builtin_amdgcn_mfma_f32_16x16x32_bf16(wf[f * 2 + 1], bp1, a0f[f], 0, 0, 0);
        }
        int ridx = relidx[r0 + lo];
        float val[4][4];
        float part = 0.f;
        #pragma unroll
        for (int f = 0; f < 4; f++)
            #pragma unroll
            for (int r = 0; r < 4; r++) {
                int c = 16 * f + 4 * hi + r;
                float rv = (ridx >= 0) ? w_relpos[ridx * 64 + c] : 0.f;
                float v = a0f[f][r] + rv;
                val[f][r] = v;
                part += v;
            }
        part += __shfl_xor(part, 16);
        part += __shfl_xor(part, 32);
        float mean = part * (1.f / 64.f);
        float v2 = 0.f;
        #pragma unroll
        for (int f = 0; f < 4; f++)
            #pragma unroll
            for (int r = 0; r < 4; r++) {
                float dv = val[f][r] - mean;
                val[f][r] = dv;
                v2 += dv * dv;
            }
        v2 += __shfl_xor(v2, 16);
        v2 += __shfl_xor(v2, 32);
        float rs = rsqrtf(v2 * (1.f / 64.f) + 1e-5f);
        #pragma unroll
        for (int f = 0; f < 4; f++) {
            float v0 = val[f][0] * rs * sg_r[f][0] + sbt_r[f][0];
            float v1 = val[f][1] * rs * sg_r[f][1] + sbt_r[f][1];
            float v2b = val[f][2] * rs * sg_r[f][2] + sbt_r[f][2];
            float v3 = val[f][3] * rs * sg_r[f][3] + sbt_r[f][3];
            *(uint2*)(feat + (size_t)(r0 + lo) * 64 + 16 * f + 4 * hi) =
                make_uint2(pk2(v0, v1), pk2(v2b, v3));
        }
    }
}

// ---------------- pair MLP ----------------
__global__ __launch_bounds__(256) void pair_mlp2_kernel(
    const ushort* __restrict__ pln, const ushort* __restrict__ pf,
    const float* __restrict__ b_p1, const float* __restrict__ b2b,
    float* __restrict__ bias) {
    __shared__ __align__(16) ushort hx[4 * 2048];
    int tid = threadIdx.x;
    int wid = tid >> 6, lane = tid & 63, hi = lane >> 4, lo = lane & 15;
    bf16x8 w1f[16];
    #pragma unroll
    for (int fs = 0; fs < 16; fs++) w1f[fs] = *(const bf16x8*)&pf[fs * 512 + lane * 8];
    bf16x8 w2f[4];
    #pragma unroll
    for (int s2 = 0; s2 < 4; s2++) w2f[s2] = *(const bf16x8*)&pf[8192 + s2 * 512 + lane * 8];
    float b2b_r[4];
    #pragma unroll
    for (int r = 0; r < 4; r++) b2b_r[r] = (hi < 2) ? b2b[4 * hi + r] : 0.f;
    float sb1_r[8][4];
    #pragma unroll
    for (int f = 0; f < 8; f++)
        #pragma unroll
        for (int r = 0; r < 4; r++) sb1_r[f][r] = b_p1[16 * f + 4 * hi + r];

    ushort* hxw = &hx[wid * 2048];
    const f32x4 zz = {0.f, 0.f, 0.f, 0.f};
    for (int t = blockIdx.x * 4 + wid; t < (NN * KK / 16); t += 16384) {
        int r0 = t << 4;
        bf16x8 bh0 = *(const bf16x8*)(pln + (size_t)(r0 + lo) * 64 + hi * 8);
        bf16x8 bh1 = *(const bf16x8*)(pln + (size_t)(r0 + lo) * 64 + 32 + hi * 8);
        #pragma unroll
        for (int f = 0; f < 8; f++) {
            f32x4 acch = __builtin_amdgcn_mfma_f32_16x16x32_bf16(w1f[f * 2 + 0], bh0, zz, 0, 0, 0);
            acch = __builtin_amdgcn_mfma_f32_16x16x32_bf16(w1f[f * 2 + 1], bh1, acch, 0, 0, 0);
            int c0 = 16 * f + 4 * hi;
            float v0 = gelu_f(acch[0] + sb1_r[f][0]);
            float v1 = gelu_f(acch[1] + sb1_r[f][1]);
            float v2b = gelu_f(acch[2] + sb1_r[f][2]);
            float v3 = gelu_f(acch[3] + sb1_r[f][3]);
            int idx = (lo * 128 + c0) ^ ((lo & 7) << 3);
            *(uint2*)&hxw[idx] = make_uint2(pk2(v0, v1), pk2(v2b, v3));
        }
        f32x4 acc = zz;
        #pragma unroll
        for (int s2 = 0; s2 < 4; s2++) {
            int idx = (lo * 128 + 32 * s2 + 8 * hi) ^ ((lo & 7) << 3);
            bf16x8 bh = *(const bf16x8*)&hxw[idx];
            acc = __builtin_amdgcn_mfma_f32_16x16x32_bf16(w2f[s2], bh, acc, 0, 0, 0);
        }
        if (hi < 2) {
            int n = r0 >> 5, kb = (r0 & 31) + lo;
            #pragma unroll
            for (int r = 0; r < 4; r++)
                bias[(size_t)n * 256 + (4 * hi + r) * 32 + kb] = acc[r] + b2b_r[r];
        }
    }
}

// ---------------- GEMM core T: A bf16 [M][K], Wt bf16 [WN][K]; BM=128,BN=128 ----------------
__device__ __forceinline__ void gemm_coreT(
    const ushort* __restrict__ A, const ushort* __restrict__ Wt,
    int K, int row0, int colW0, int tid,
    ushort* sA, ushort* sB, f32x4 acc[4][4]) {
    int wid = tid >> 6, lane = tid & 63, lo = lane & 15, hi = lane >> 4;
    int wr = wid >> 1, wc = wid & 1;
    int ar = tid >> 1, akh = (tid & 1) * 16;
    for (int kt = 0; kt < K; kt += 32) {
        const ushort* ap = &A[(size_t)(row0 + ar) * K + kt + akh];
        uint4 a01 = *(const uint4*)ap;
        uint4 a23 = *(const uint4*)(ap + 8);
        const ushort* bp = &Wt[(size_t)(colW0 + ar) * K + kt + akh];
        uint4 b01 = *(const uint4*)bp;
        uint4 b23 = *(const uint4*)(bp + 8);
        __syncthreads();
        *(uint4*)&sA[ar * 40 + akh] = a01;
        *(uint4*)&sA[ar * 40 + akh + 8] = a23;
        *(uint4*)&sB[ar * 40 + akh] = b01;
        *(uint4*)&sB[ar * 40 + akh + 8] = b23;
        __syncthreads();
        bf16x8 af[4], bfr[4];
        #pragma unroll
        for (int mi = 0; mi < 4; mi++) af[mi] = *(const bf16x8*)&sA[(wr * 64 + mi * 16 + lo) * 40 + hi * 8];
        #pragma unroll
        for (int ni = 0; ni < 4; ni++) bfr[ni] = *(const bf16x8*)&sB[(wc * 64 + ni * 16 + lo) * 40 + hi * 8];
        #pragma unroll
        for (int mi = 0; mi < 4; mi++)
            #pragma unroll
            for (int ni = 0; ni < 4; ni++)
                acc[mi][ni] = __builtin_amdgcn_mfma_f32_16x16x32_bf16(af[mi], bfr[ni], acc[mi][ni], 0, 0, 0);
    }
}

// ---------------- t1 GEMM (bf16 A, Wt, bf16 out, gelu) ----------------
__global__ __launch_bounds__(256) void gemm_t1T(
    const ushort* __restrict__ A, const ushort* __restrict__ Wt, ushort* __restrict__ C,
    int K, int Nc) {
    __shared__ __align__(16) ushort sA[128 * 40];
    __shared__ __align__(16) ushort sB[128 * 40];
    int row0 = blockIdx.y * 128, col0 = blockIdx.x * 128;
    int tid = threadIdx.x;
    const f32x4 zz = {0.f, 0.f, 0.f, 0.f};
    f32x4 acc[4][4] = {{zz, zz, zz, zz}, {zz, zz, zz, zz}, {zz, zz, zz, zz}, {zz, zz, zz, zz}};
    gemm_coreT(A, Wt, K, row0, col0, tid, sA, sB, acc);
    int wid = tid >> 6, lane = tid & 63, lo = lane & 15, hi = lane >> 4;
    int wr = wid >> 1, wc = wid & 1;
    #pragma unroll
    for (int ni = 0; ni < 4; ni++) {
        int col = col0 + wc * 64 + ni * 16 + lo;
        #pragma unroll
        for (int mi = 0; mi < 4; mi++) {
            #pragma unroll
            for (int r = 0; r < 4; r++) {
                int row = row0 + wr * 64 + mi * 16 + hi * 4 + r;
                C[(size_t)row * Nc + col] = f2bf(gelu_f(acc[mi][ni][r]));
            }
        }
    }
}

// ---------------- narrow GEMM T (BM=128, BN=64): bf16 A, Wt; fp32 out ----------------
__global__ __launch_bounds__(256) void gemm_n64T(
    const ushort* __restrict__ A, const ushort* __restrict__ Wt, float* __restrict__ C,
    int K, int Nc, const float* __restrict__ bias, const float* __restrict__ addp) {
    __shared__ __align__(16) ushort sA[128 * 40];
    __shared__ __align__(16) ushort sB[64 * 40];
    int row0 = blockIdx.y * 128, col0 = blockIdx.x * 64;
    int tid = threadIdx.x;
    int wid = tid >> 6, lane = tid & 63, lo = lane & 15, hi = lane >> 4;
    int wr = wid >> 1, wc = wid & 1;
    int ar = tid >> 1, akh = (tid & 1) * 16;
    int br = tid >> 2, bkh = (tid & 3) * 8;
    const f32x4 zz = {0.f, 0.f, 0.f, 0.f};
    f32x4 acc[4][2] = {{zz, zz}, {zz, zz}, {zz, zz}, {zz, zz}};
    for (int kt = 0; kt < K; kt += 32) {
        const ushort* ap = &A[(size_t)(row0 + ar) * K + kt + akh];
        uint4 a01 = *(const uint4*)ap;
        uint4 a23 = *(const uint4*)(ap + 8);
        uint4 b0 = *(const uint4*)&Wt[(size_t)(col0 + br) * K + kt + bkh];
        __syncthreads();
        *(uint4*)&sA[ar * 40 + akh] = a01;
        *(uint4*)&sA[ar * 40 + akh + 8] = a23;
        *(uint4*)&sB[br * 40 + bkh] = b0;
        __syncthreads();
        bf16x8 af[4], bfr[2];
        #pragma unroll
        for (int mi = 0; mi < 4; mi++) af[mi] = *(const bf16x8*)&sA[(wr * 64 + mi * 16 + lo) * 40 + hi * 8];
        #pragma unroll
        for (int ni = 0; ni < 2; ni++) bfr[ni] = *(const bf16x8*)&sB[(wc * 32 + ni * 16 + lo) * 40 + hi * 8];
        #pragma unroll
        for (int mi = 0; mi < 4; mi++)
            #pragma unroll
            for (int ni = 0; ni < 2; ni++)
                acc[mi][ni] = __builtin_amdgcn_mfma_f32_16x16x32_bf16(af[mi], bfr[ni], acc[mi][ni], 0, 0, 0);
    }
    #pragma unroll
    for (int ni = 0; ni < 2; ni++) {
        int col = col0 + wc * 32 + ni * 16 + lo;
        float bc = bias ? bias[col] : 0.f;
        #pragma unroll
        for (int mi = 0; mi < 4; mi++) {
            #pragma unroll
            for (int r = 0; r < 4; r++) {
                int row = row0 + wr * 64 + mi * 16 + hi * 4 + r;
                float v = acc[mi][ni][r] + bc;
                if (addp) v += addp[(size_t)row * Nc + col];
                C[(size_t)row * Nc + col] = v;
            }
        }
    }
}

// ---------------- fused QKV GEMM T: A=localb, Wt3 [768][256] ----------------
__global__ __launch_bounds__(256) void gemm_qkvT(
    const ushort* __restrict__ A, const ushort* __restrict__ Wt3,
    float* __restrict__ qb, ushort* __restrict__ kb, ushort* __restrict__ vb) {
    __shared__ __align__(16) ushort sA[128 * 40];
    __shared__ __align__(16) ushort sB[128 * 40];
    int row0 = blockIdx.y * 128, col0 = blockIdx.x * 128;
    int wsel = col0 >> 8, colW = col0 & 255;
    int tid = threadIdx.x;
    const f32x4 zz = {0.f, 0.f, 0.f, 0.f};
    f32x4 acc[4][4] = {{zz, zz, zz, zz}, {zz, zz, zz, zz}, {zz, zz, zz, zz}, {zz, zz, zz, zz}};
    gemm_coreT(A, Wt3, 256, row0, col0, tid, sA, sB, acc);
    int wid = tid >> 6, lane = tid & 63, lo = lane & 15, hi = lane >> 4;
    int wr = wid >> 1, wc = wid & 1;
    #pragma unroll
    for (int ni = 0; ni < 4; ni++) {
        int colo = colW + wc * 64 + ni * 16 + lo;
        #pragma unroll
        for (int mi = 0; mi < 4; mi++) {
            #pragma unroll
            for (int r = 0; r < 4; r++) {
                int row = row0 + wr * 64 + mi * 16 + hi * 4 + r;
                float v = acc[mi][ni][r];
                if (wsel == 0) qb[(size_t)row * 256 + colo] = v;
                else if (wsel == 1) kb[(size_t)row * 256 + colo] = f2bf(v);
                else vb[(size_t)row * 256 + colo] = f2bf(v);
            }
        }
    }
}

// ---------------- fused FFN GEMM T: A=x1b, Wt4 [2048][256]; bf16 outs ----------------
__global__ __launch_bounds__(256) void gemm_ffnT(
    const ushort* __restrict__ A, const ushort* __restrict__ Wt4,
    ushort* __restrict__ o0, ushort* __restrict__ o1,
    ushort* __restrict__ o2, ushort* __restrict__ o3) {
    __shared__ __align__(16) ushort sA[128 * 40];
    __shared__ __align__(16) ushort sB[128 * 40];
    int row0 = blockIdx.y * 128, col0 = blockIdx.x * 128;
    int wsel = col0 >> 9, colW = col0 & 511;
    ushort* O = (wsel == 0) ? o0 : (wsel == 1) ? o1 : (wsel == 2) ? o2 : o3;
    int tid = threadIdx.x;
    const f32x4 zz = {0.f, 0.f, 0.f, 0.f};
    f32x4 acc[4][4] = {{zz, zz, zz, zz}, {zz, zz, zz, zz}, {zz, zz, zz, zz}, {zz, zz, zz, zz}};
    gemm_coreT(A, Wt4, 256, row0, col0, tid, sA, sB, acc);
    int wid = tid >> 6, lane = tid & 63, lo = lane & 15, hi = lane >> 4;
    int wr = wid >> 1, wc = wid & 1;
    #pragma unroll
    for (int ni = 0; ni < 4; ni++) {
        int colo = colW + wc * 64 + ni * 16 + lo;
        #pragma unroll
        for (int mi = 0; mi < 4; mi++) {
            #pragma unroll
            for (int r = 0; r < 4; r++) {
                int row = row0 + wr * 64 + mi * 16 + hi * 4 + r;
                float v = acc[mi][ni][r];
                if (wsel > 0) v = gelu_f(v);
                O[(size_t)row * 512 + colo] = f2bf(v);
            }
        }
    }
}

// ---------------- attention ----------------
__global__ __launch_bounds__(256) void attn_kernel(
    const float* __restrict__ q, const ushort* __restrict__ kp, const ushort* __restrict__ vp,
    const float* __restrict__ bias, const int* __restrict__ nbr, ushort* __restrict__ o) {
    int n = blockIdx.x;
    __shared__ float qs[256];
    __shared__ int js[32];
    __shared__ float ls[256];
    __shared__ __align__(16) uint4 vs[32 * 33];
    int t = threadIdx.x;
    qs[t] = q[(size_t)n * 256 + t];
    if (t < 32) js[t] = nbr[n * 32 + t];
    __syncthreads();
    int vrow = t >> 3, vseg = t & 7;
    const uint4* vsrc = (const uint4*)(vp + (size_t)js[vrow] * 256);
    uint4 vr0 = vsrc[vseg * 4 + 0];
    uint4 vr1 = vsrc[vseg * 4 + 1];
    uint4 vr2 = vsrc[vseg * 4 + 2];
    uint4 vr3 = vsrc[vseg * 4 + 3];
    int h = t >> 5, k = t & 31;
    int j = js[k];
    const bf16x8* kr = (const bf16x8*)(kp + (size_t)j * 256 + h * 32);
    bf16x8 kv0 = kr[0], kv1 = kr[1], kv2 = kr[2], kv3 = kr[3];
    const float* qh = qs + h * 32;
    float dot = 0.f;
    #pragma unroll
    for (int i = 0; i < 8; i++) dot += qh[i] * bf2f((ushort)kv0[i]);
    #pragma unroll
    for (int i = 0; i < 8; i++) dot += qh[8 + i] * bf2f((ushort)kv1[i]);
    #pragma unroll
    for (int i = 0; i < 8; i++) dot += qh[16 + i] * bf2f((ushort)kv2[i]);
    #pragma unroll
    for (int i = 0; i < 8; i++) dot += qh[24 + i] * bf2f((ushort)kv3[i]);
    float l = dot * 0.17677669529663687f + bias[(size_t)n * 256 + t];
    float mx = l;
    #pragma unroll
    for (int m = 16; m > 0; m >>= 1) mx = fmaxf(mx, __shfl_xor(mx, m));
    float e = __expf(l - mx);
    float sum = e;
    #pragma unroll
    for (int m = 16; m > 0; m >>= 1) sum += __shfl_xor(sum, m);
    ls[t] = e / sum;
    vs[vrow * 33 + vseg * 4 + 0] = vr0;
    vs[vrow * 33 + vseg * 4 + 1] = vr1;
    vs[vrow * 33 + vseg * 4 + 2] = vr2;
    vs[vrow * 33 + vseg * 4 + 3] = vr3;
    __syncthreads();
    const ushort* vsu = (const ushort*)vs;
    const float* lh = ls + h * 32;
    float acc = 0.f;
    #pragma unroll
    for (int kk = 0; kk < 32; kk++)
        acc += lh[kk] * bf2f(vsu[kk * 264 + h * 32 + k]);
    o[(size_t)n * 256 + t] = f2bf(acc);
}

// ---------------- LN(a+b): x fp32 + x bf16 + sum fp32 ----------------
__global__ __launch_bounds__(256) void ln_add_kernel(
    const float* __restrict__ a, const float* __restrict__ b,
    const float* __restrict__ g, const float* __restrict__ be,
    float* __restrict__ xout, ushort* __restrict__ xbout, float* __restrict__ sout) {
    int row = blockIdx.x * 4 + (threadIdx.x >> 6);
    int lane = threadIdx.x & 63;
    size_t base = (size_t)row * 256 + lane * 4;
    float4 av = *(const float4*)(a + base);
    float4 bv = *(const float4*)(b + base);
    float s0 = av.x + bv.x, s1 = av.y + bv.y, s2 = av.z + bv.z, s3 = av.w + bv.w;
    float sum = wave_sum64(s0 + s1 + s2 + s3);
    float mean = sum * (1.f / 256.f);
    float d0 = s0 - mean, d1 = s1 - mean, d2 = s2 - mean, d3 = s3 - mean;
    float v = wave_sum64(d0 * d0 + d1 * d1 + d2 * d2 + d3 * d3);
    float rs = rsqrtf(v * (1.f / 256.f) + 1e-5f);
    float4 gv = *(const float4*)(g + lane * 4);
    float4 bev = *(const float4*)(be + lane * 4);
    float4 xo;
    xo.x = d0 * rs * gv.x + bev.x;
    xo.y = d1 * rs * gv.y + bev.y;
    xo.z = d2 * rs * gv.z + bev.z;
    xo.w = d3 * rs * gv.w + bev.w;
    *(float4*)(xout + base) = xo;
    *(uint2*)(xbout + base) = make_uint2(pk2(xo.x, xo.y), pk2(xo.z, xo.w));
    float4 so; so.x = s0; so.y = s1; so.z = s2; so.w = s3;
    *(float4*)(sout + base) = so;
}

// ---------------- segment means ----------------
__global__ __launch_bounds__(256) void seg_partial_kernel(
    const ushort* __restrict__ up, const int* __restrict__ batch, const int* __restrict__ chain,
    float* __restrict__ mb_acc, float* __restrict__ mc_acc) {
    int r0 = blockIdx.x * 32;
    int t = threadIdx.x;
    float ab0 = 0.f, ab1 = 0.f, ac0 = 0.f, ac1 = 0.f;
    int curb = batch[r0], curc = chain[r0];
    for (int r = r0; r < r0 + 32; r++) {
        int b = batch[r], c = chain[r];
        if (b != curb) {
            atomicAdd(&mb_acc[curb * 512 + t], ab0);
            atomicAdd(&mb_acc[curb * 512 + 256 + t], ab1);
            ab0 = ab1 = 0.f; curb = b;
        }
        if (c != curc) {
            atomicAdd(&mc_acc[curc * 512 + t], ac0);
            atomicAdd(&mc_acc[curc * 512 + 256 + t], ac1);
            ac0 = ac1 = 0.f; curc = c;
        }
        float v0 = bf2f(up[(size_t)r * 512 + t]);
        float v1 = bf2f(up[(size_t)r * 512 + 256 + t]);
        ab0 += v0; ab1 += v1; ac0 += v0; ac1 += v1;
    }
    atomicAdd(&mb_acc[curb * 512 + t], ab0);
    atomicAdd(&mb_acc[curb * 512 + 256 + t], ab1);
    atomicAdd(&mc_acc[curc * 512 + t], ac0);
    atomicAdd(&mc_acc[curc * 512 + 256 + t], ac1);
}

__device__ __forceinline__ int lower_bound_i(const int* a, int n, int v) {
    int lo = 0, hi = n;
    while (lo < hi) { int mid = (lo + hi) >> 1; if (a[mid] < v) lo = mid + 1; else hi = mid; }
    return lo;
}

__global__ __launch_bounds__(256) void seg_final_kernel(
    float* __restrict__ mb, float* __restrict__ mc,
    const int* __restrict__ batch, const int* __restrict__ chain) {
    int idx = blockIdx.x * 256 + threadIdx.x;
    if (idx < NBATCH * 512) {
        int seg = idx >> 9;
        int lo = lower_bound_i(batch, NN, seg);
        int hi = lower_bound_i(batch, NN, seg + 1);
        mb[idx] *= 1.f / fmaxf((float)(hi - lo), 1.f);
    } else {
        int i2 = idx - NBATCH * 512;
        int seg = i2 >> 9;
        int lo = lower_bound_i(chain, NN, seg);
        int hi = lower_bound_i(chain, NN, seg + 1);
        mc[i2] *= 1.f / fmaxf((float)(hi - lo), 1.f);
    }
}

// ---------------- hidden combine (bf16 in/out, x4) ----------------
__global__ __launch_bounds__(256) void hidden_kernel(
    const ushort* __restrict__ up, const ushort* __restrict__ cg, const ushort* __restrict__ bg,
    ushort* __restrict__ lg, const float* __restrict__ mb, const float* __restrict__ mc,
    const int* __restrict__ batch, const int* __restrict__ chain) {
    size_t e4 = ((size_t)blockIdx.x * 256 + threadIdx.x) * 4;
    int n = (int)(e4 >> 9), d = (int)(e4 & 511);
    float4 mbv = *(const float4*)&mb[batch[n] * 512 + d];
    float4 mcv = *(const float4*)&mc[chain[n] * 512 + d];
    uint2 u_up = *(const uint2*)&up[e4];
    uint2 u_cg = *(const uint2*)&cg[e4];
    uint2 u_bg = *(const uint2*)&bg[e4];
    uint2 u_lg = *(const uint2*)&lg[e4];
    float h0 = bf2f((ushort)u_bg.x) * mbv.x + bf2f((ushort)u_cg.x) * mcv.x
             + bf2f((ushort)u_lg.x) * bf2f((ushort)u_up.x);
    float h1 = bf2f((ushort)(u_bg.x >> 16)) * mbv.y + bf2f((ushort)(u_cg.x >> 16)) * mcv.y
             + bf2f((ushort)(u_lg.x >> 16)) * bf2f((ushort)(u_up.x >> 16));
    float h2 = bf2f((ushort)u_bg.y) * mbv.z + bf2f((ushort)u_cg.y) * mcv.z
             + bf2f((ushort)u_lg.y) * bf2f((ushort)u_up.y);
    float h3 = bf2f((ushort)(u_bg.y >> 16)) * mbv.w + bf2f((ushort)(u_cg.y >> 16)) * mcv.w
             + bf2f((ushort)(u_lg.y >> 16)) * bf2f((ushort)(u_up.y >> 16));
    *(uint2*)&lg[e4] = make_uint2(pk2(h0, h1), pk2(h2, h3));
}

// ---------------- final ----------------
__global__ __launch_bounds__(256) void final_kernel(
    const float* __restrict__ x1, const float* __restrict__ y2, const float* __restrict__ inc1,
    const float* __restrict__ ug, const float* __restrict__ ub,
    const float* __restrict__ fg, const float* __restrict__ fb, float* __restrict__ out) {
    int row = blockIdx.x * 4 + (threadIdx.x >> 6);
    int lane = threadIdx.x & 63;
    size_t base = (size_t)row * 256 + lane * 4;
    float4 xv = *(const float4*)(x1 + base);
    float4 yv = *(const float4*)(y2 + base);
    float4 iv = *(const float4*)(inc1 + base);
    float s0 = xv.x + yv.x, s1 = xv.y + yv.y, s2 = xv.z + yv.z, s3 = xv.w + yv.w;
    float t0 = iv.x + yv.x, t1 = iv.y + yv.y, t2 = iv.z + yv.z, t3 = iv.w + yv.w;
    float sums = wave_sum64(s0 + s1 + s2 + s3);
    float means = sums * (1.f / 256.f);
    float sd0 = s0 - means, sd1 = s1 - means, sd2 = s2 - means, sd3 = s3 - means;
    float vs = wave_sum64(sd0 * sd0 + sd1 * sd1 + sd2 * sd2 + sd3 * sd3);
    float rss = rsqrtf(vs * (1.f / 256.f) + 1e-5f);
    float sumt = wave_sum64(t0 + t1 + t2 + t3);
    float meant = sumt * (1.f / 256.f);
    float td0 = t0 - meant, td1 = t1 - meant, td2 = t2 - meant, td3 = t3 - meant;
    float vt = wave_sum64(td0 * td0 + td1 * td1 + td2 * td2 + td3 * td3);
    float rst = rsqrtf(vt * (1.f / 256.f) + 1e-5f);
    float4 ugv = *(const float4*)(ug + lane * 4);
    float4 ubv = *(const float4*)(ub + lane * 4);
    float4 fgv = *(const float4*)(fg + lane * 4);
    float4 fbv = *(const float4*)(fb + lane * 4);
    float4 ov;
    ov.x = (sd0 * rss * ugv.x + ubv.x) + (td0 * rst * fgv.x + fbv.x);
    ov.y = (sd1 * rss * ugv.y + ubv.y) + (td1 * rst * fgv.y + fbv.y);
    ov.z = (sd2 * rss * ugv.z + ubv.z) + (td2 * rst * fgv.z + fbv.z);
    ov.w = (sd3 * rss * ugv.w + ubv.w) + (td3 * rst * fgv.w + fbv.w);
    *(float4*)(out + base) = ov;
}

// ---------------- launch ----------------
extern "C" void kernel_launch(void* const* d_in, const int* in_sizes, int n_in,
                              void* d_out, int out_size, void* d_ws, size_t ws_size,
                              hipStream_t stream) {
    const float* local    = (const float*)d_in[0];
    const float* pos      = (const float*)d_in[1];
    const int*   nbr      = (const int*)d_in[2];
    const int*   resi     = (const int*)d_in[3];
    const int*   chain    = (const int*)d_in[4];
    const int*   batch    = (const int*)d_in[5];
    const float* w_relpos = (const float*)d_in[7];
    const float* w_dist   = (const float*)d_in[8];
    const float* w_dir    = (const float*)d_in[9];
    const float* w_rot    = (const float*)d_in[10];
    const float* ln_pair_g = (const float*)d_in[11];
    const float* ln_pair_b = (const float*)d_in[12];
    const float* w_p1     = (const float*)d_in[13];
    const float* b_p1     = (const float*)d_in[14];
    const float* w_p2     = (const float*)d_in[15];
    const float* b_p2     = (const float*)d_in[16];
    const float* wq       = (const float*)d_in[17];
    const float* wk       = (const float*)d_in[18];
    const float* wv       = (const float*)d_in[19];
    const float* wb       = (const float*)d_in[20];
    const float* wo       = (const float*)d_in[21];
    const float* ln_a_g   = (const float*)d_in[22];
    const float* ln_a_b   = (const float*)d_in[23];
    const float* w_t1     = (const float*)d_in[24];
    const float* w_t2     = (const float*)d_in[25];
    const float* w_up     = (const float*)d_in[26];
    const float* w_lg     = (const float*)d_in[27];
    const float* w_cg     = (const float*)d_in[28];
    const float* w_bg     = (const float*)d_in[29];
    const float* w_out    = (const float*)d_in[30];
    const float* b_out    = (const float*)d_in[31];
    const float* ln_u_g   = (const float*)d_in[32];
    const float* ln_u_b   = (const float*)d_in[33];
    const float* ln_f_g   = (const float*)d_in[34];
    const float* ln_f_b   = (const float*)d_in[35];

    float* ws = (float*)d_ws;
    float* R         = ws + 0;             // 73728
    float* biasb     = ws + 73728;         // N*256 -> 2170880
    float* tfeat_out = ws + 2170880;       // N*256 fp32 -> 4268032
    float* x1        = ws + 4268032;       // -> 6365184
    float* inc1      = ws + 6365184;       // -> 8462336
    ushort* featb    = (ushort*)(ws + 8462336);  // N*K*64 bf16 -> 16850944
    int* relidx      = (int*)(ws + 16850944);    // -> 17113088
    ushort* tfb      = (ushort*)(ws + 17113088); // N*608 bf16 -> 19603456
    ushort* wt       = (ushort*)(ws + 19603456); // 1359872 ushorts -> 20283392
    ushort* x1b      = (ushort*)(ws + 20283392); // N*256 bf16 -> 21331968
    ushort* localb   = (ushort*)(ws + 21331968); // N*256 bf16 -> 22380544
    ushort* tmp512u  = (ushort*)(ws + 22380544); // N*512 bf16 -> 24477696
    float* y2        = ws + 22380544;      // N*256 fp32 (over tmp512u, after t2 consumed)
    float* yb        = ws + 17113088;      // N*256 fp32 (over tfb, after t1 consumed)
    float* qb        = ws + 8462336;       // N*256 fp32 (phase 2, over featb)
    ushort* kbu      = (ushort*)(ws + 10559488);
    ushort* vbu      = (ushort*)(ws + 11608064);
    ushort* obu      = (ushort*)(ws + 12656640);
    ushort* upbu     = (ushort*)(ws + 8462336);  // N*512 bf16 (phase 3)
    ushort* lgbu     = (ushort*)(ws + 10559488);
    ushort* cgbu     = (ushort*)(ws + 12656640);
    ushort* bgbu     = (ushort*)(ws + 14753792); // -> 16850944
    float* mb        = ws + 24477696;      // 32*512
    float* mc        = ws + 24494080;      // 64*512 -> 24526848
    ushort* pfmt     = (ushort*)(ws + 24526848); // 14336 ushorts -> 24534016
    float* w2b       = ws + 24534016;      // 1024 -> 24535040
    float* b2b       = ws + 24535040;      // 8

    frames_kernel<<<NN / 256, 256, 0, stream>>>(pos, R);
    w2b_kernel<<<4, 256, 0, stream>>>(w_p2, b_p2, wb, w2b, b2b);
    fmt_kernel<<<28, 256, 0, stream>>>(w_p1, w_dist, w_dir, w_rot, w2b, pfmt);
    fmt_wt_kernel<<<dim3(16, 19, 11), 256, 0, stream>>>(w_up, w_lg, w_cg, w_bg, wq, wk, wv,
                                                        w_t1, w_t2, wo, w_out, wt);
    convb_kernel<<<NN * 256 / 1024, 256, 0, stream>>>(local, localb);
    pair_raw_kernel<<<NN * KK / 256, 256, 0, stream>>>(pos, nbr, resi, chain, R,
                                                       featb, relidx, tfb);
    pair_pre_kernel<<<4096, 256, 0, stream>>>(featb, relidx, w_relpos, pfmt,
                                              ln_pair_g, ln_pair_b);
    pair_mlp2_kernel<<<4096, 256, 0, stream>>>(featb, pfmt, b_p1, b2b, biasb);
    // tfeat MLP
    gemm_t1T<<<dim3(4, 64), 256, 0, stream>>>(tfb, wt + 720896, tmp512u, 608, 512);
    gemm_n64T<<<dim3(4, 64), 256, 0, stream>>>(tmp512u, wt + 1032192, tfeat_out, 512, 256,
                                               nullptr, nullptr);
    // qkv
    gemm_qkvT<<<dim3(6, 64), 256, 0, stream>>>(localb, wt + 524288, qb, kbu, vbu);
    attn_kernel<<<NN, 256, 0, stream>>>(qb, kbu, vbu, biasb, nbr, obu);
    gemm_n64T<<<dim3(4, 64), 256, 0, stream>>>(obu, wt + 1163264, yb, 256, 256,
                                               nullptr, nullptr);
    ln_add_kernel<<<NN / 4, 256, 0, stream>>>(local, yb, ln_a_g, ln_a_b, x1, x1b, inc1);
    // FFN
    gemm_ffnT<<<dim3(16, 64), 256, 0, stream>>>(x1b, wt, upbu, lgbu, cgbu, bgbu);
    (void)hipMemsetAsync(mb, 0, (NBATCH + NCHAIN) * 512 * sizeof(float), stream);
    seg_partial_kernel<<<NN / 32, 256, 0, stream>>>(upbu, batch, chain, mb, mc);
    seg_final_kernel<<<(NBATCH + NCHAIN) * 512 / 256, 256, 0, stream>>>(mb, mc, batch, chain);
    hidden_kernel<<<NN * 512 / 1024, 256, 0, stream>>>(upbu, cgbu, bgbu, lgbu, mb, mc, batch, chain);
    gemm_n64T<<<dim3(4, 64), 256, 0, stream>>>(lgbu, wt + 1228800, y2, 512, 256,
                                               b_out, tfeat_out);
    final_kernel<<<NN / 4, 256, 0, stream>>>(x1, y2, inc1, ln_u_g, ln_u_b, ln_f_g, ln_f_b, (float*)d_out);
}

// Round 14
// 260.487 us; speedup vs baseline: 1.5364x; 1.0338x over previous
//
#include <hip/hip_runtime.h>
#include <math.h>

#define NN 8192
#define KK 32
#define DD 256
#define PP 64
#define HH 8
#define DHH 32
#define NBATCH 32
#define NCHAIN 64

typedef __attribute__((ext_vector_type(8))) short bf16x8;
typedef __attribute__((ext_vector_type(4))) float f32x4;

// ---------------- helpers ----------------
__device__ __forceinline__ float gelu_f(float x) {
    float x3 = x * x * x;
    float e = __expf(fmaf(x3, -0.07135481f, x * -1.59576912f));
    return __fdividef(x, 1.f + e);
}

__device__ __forceinline__ float wave_sum64(float v) {
    #pragma unroll
    for (int m = 32; m > 0; m >>= 1) v += __shfl_xor(v, m);
    return v;
}

__device__ __forceinline__ ushort f2bf(float x) {
    union { float f; unsigned int u; } v; v.f = x;
    unsigned int r = v.u + 0x7fffu + ((v.u >> 16) & 1u);
    return (ushort)(r >> 16);
}

__device__ __forceinline__ float bf2f(ushort u) {
    union { unsigned int u; float f; } v; v.u = ((unsigned int)u) << 16;
    return v.f;
}

__device__ __forceinline__ uint pk2(float a, float b) {
    return (uint)f2bf(a) | ((uint)f2bf(b) << 16);
}

// ---------------- frames ----------------
__global__ __launch_bounds__(256) void frames_kernel(const float* __restrict__ pos,
                                                     float* __restrict__ R) {
    int n = blockIdx.x * 256 + threadIdx.x;
    if (n >= NN) return;
    const float* p = pos + n * 15;
    float nx = p[0], ny = p[1], nz = p[2];
    float cax = p[3], cay = p[4], caz = p[5];
    float cx = p[6], cy = p[7], cz = p[8];
    float e1x = cx - cax, e1y = cy - cay, e1z = cz - caz;
    float inv = rsqrtf(e1x * e1x + e1y * e1y + e1z * e1z + 1e-8f);
    e1x *= inv; e1y *= inv; e1z *= inv;
    float ux = nx - cax, uy = ny - cay, uz = nz - caz;
    float dt = ux * e1x + uy * e1y + uz * e1z;
    float e2x = ux - dt * e1x, e2y = uy - dt * e1y, e2z = uz - dt * e1z;
    inv = rsqrtf(e2x * e2x + e2y * e2y + e2z * e2z + 1e-8f);
    e2x *= inv; e2y *= inv; e2z *= inv;
    float e3x = e1y * e2z - e1z * e2y;
    float e3y = e1z * e2x - e1x * e2z;
    float e3z = e1x * e2y - e1y * e2x;
    float* r = R + n * 9;
    r[0] = e1x; r[1] = e2x; r[2] = e3x;
    r[3] = e1y; r[4] = e2y; r[5] = e3y;
    r[6] = e1z; r[7] = e2z; r[8] = e3z;
}

// ---------------- raw pair features ----------------
__global__ __launch_bounds__(256) void pair_raw_kernel(
    const float* __restrict__ pos, const int* __restrict__ nbr,
    const int* __restrict__ resi, const int* __restrict__ chain,
    const float* __restrict__ R,
    ushort* __restrict__ feat, int* __restrict__ relidx, ushort* __restrict__ tfb) {
    int p = blockIdx.x * 256 + threadIdx.x;
    int n = p >> 5, k = p & 31;
    int j = nbr[p];
    int same = (chain[j] == chain[n]);
    int off = min(max(resi[j] - resi[n], -32), 32) + 32;
    relidx[p] = same ? off : -1;

    float can0 = pos[n * 15 + 3], can1 = pos[n * 15 + 4], can2 = pos[n * 15 + 5];
    float cbn0 = pos[n * 15 + 12], cbn1 = pos[n * 15 + 13], cbn2 = pos[n * 15 + 14];
    float Rn[9], Rj[9];
    #pragma unroll
    for (int i = 0; i < 9; i++) Rn[i] = R[n * 9 + i];
    #pragma unroll
    for (int i = 0; i < 9; i++) Rj[i] = R[j * 9 + i];
    float pj[15];
    #pragma unroll
    for (int i = 0; i < 15; i++) pj[i] = pos[j * 15 + i];

    float fe[43];
    float d0 = pj[12] - cbn0, d1 = pj[13] - cbn1, d2 = pj[14] - cbn2;
    float dcb = sqrtf(d0 * d0 + d1 * d1 + d2 * d2 + 1e-8f);
    #pragma unroll
    for (int i = 0; i < 16; i++) {
        float c = (22.f / 15.f) * (float)i;
        float z = (dcb - c) * (1.f / 1.375f);
        fe[i] = __expf(-z * z);
    }
    #pragma unroll
    for (int a = 0; a < 5; a++) {
        float vx = pj[a * 3 + 0] - can0;
        float vy = pj[a * 3 + 1] - can1;
        float vz = pj[a * 3 + 2] - can2;
        float invv = rsqrtf(vx * vx + vy * vy + vz * vz + 1e-8f);
        fe[16 + a * 3 + 0] = vx * invv;
        fe[16 + a * 3 + 1] = vy * invv;
        fe[16 + a * 3 + 2] = vz * invv;
    }
    #pragma unroll
    for (int b = 0; b < 3; b++)
        #pragma unroll
        for (int c2 = 0; c2 < 3; c2++)
            fe[31 + b * 3 + c2] = Rn[0 + b] * Rj[0 + c2] + Rn[3 + b] * Rj[3 + c2] + Rn[6 + b] * Rj[6 + c2];
    float t0 = pj[3] - can0, t1 = pj[4] - can1, t2 = pj[5] - can2;
    #pragma unroll
    for (int b = 0; b < 3; b++)
        fe[40 + b] = Rn[0 + b] * t0 + Rn[3 + b] * t1 + Rn[6 + b] * t2;

    #pragma unroll
    for (int q = 0; q < 8; q++) {
        uint4 w;
        float v0 = (q * 8 + 0 < 43) ? fe[q * 8 + 0] : 0.f;
        float v1 = (q * 8 + 1 < 43) ? fe[q * 8 + 1] : 0.f;
        float v2 = (q * 8 + 2 < 43) ? fe[q * 8 + 2] : 0.f;
        float v3 = (q * 8 + 3 < 43) ? fe[q * 8 + 3] : 0.f;
        float v4 = (q * 8 + 4 < 43) ? fe[q * 8 + 4] : 0.f;
        float v5 = (q * 8 + 5 < 43) ? fe[q * 8 + 5] : 0.f;
        float v6 = (q * 8 + 6 < 43) ? fe[q * 8 + 6] : 0.f;
        float v7 = (q * 8 + 7 < 43) ? fe[q * 8 + 7] : 0.f;
        w.x = pk2(v0, v1); w.y = pk2(v2, v3); w.z = pk2(v4, v5); w.w = pk2(v6, v7);
        *(uint4*)&feat[(size_t)p * 64 + q * 8] = w;
    }
    float rt0 = fe[40], rt1 = fe[41], rt2 = fe[42];
    float dr2 = rt0 * rt0 + rt1 * rt1 + rt2 * rt2 + 1e-8f;
    float invdr = rsqrtf(dr2);
    float drel = dr2 * invdr;
    ushort* tf = tfb + (size_t)n * 608 + k * 19;
    #pragma unroll
    for (int i = 0; i < 16; i++) {
        float c = (22.f / 15.f) * (float)i;
        float z = (drel - c) * (1.f / 1.375f);
        tf[i] = f2bf(__expf(-z * z));
    }
    tf[16] = f2bf(rt0 * invdr);
    tf[17] = f2bf(rt1 * invdr);
    tf[18] = f2bf(rt2 * invdr);
}

// ---------------- W2B ----------------
__global__ __launch_bounds__(256) void w2b_kernel(
    const float* __restrict__ w_p2, const float* __restrict__ b_p2,
    const float* __restrict__ wb, float* __restrict__ w2b, float* __restrict__ b2b) {
    int idx = blockIdx.x * 256 + threadIdx.x;
    if (idx < 1024) {
        int c = idx >> 3, h = idx & 7;
        float s = 0.f;
        for (int q = 0; q < 64; q++) s += w_p2[c * 64 + q] * wb[q * 8 + h];
        w2b[idx] = s;
    }
    if (idx < 8) {
        float s = 0.f;
        for (int q = 0; q < 64; q++) s += b_p2[q] * wb[q * 8 + idx];
        b2b[idx] = s;
    }
}

// ---------------- fmt: pair MFMA weight fragments ----------------
__global__ __launch_bounds__(256) void fmt_kernel(
    const float* __restrict__ w_p1,
    const float* __restrict__ w_dist, const float* __restrict__ w_dir,
    const float* __restrict__ w_rot, const float* __restrict__ w2b,
    ushort* __restrict__ pf) {
    int u = blockIdx.x * 256 + threadIdx.x;
    uint* pfu = (uint*)pf;
    if (u < 4096) {
        int fs = u >> 8, rem = u & 255, lane = rem >> 2, jj = rem & 3;
        int hi = lane >> 4, lo = lane & 15;
        int f = fs >> 1, s = fs & 1;
        int k0 = 32 * s + hi * 8 + 2 * jj;
        int c = 16 * f + lo;
        pfu[u] = pk2(w_p1[k0 * 128 + c], w_p1[(k0 + 1) * 128 + c]);
    } else if (u < 5120) {
        int u2 = u - 4096;
        int s2 = u2 >> 8, rem = u2 & 255, lane = rem >> 2, jj = rem & 3;
        int hi = lane >> 4, lo = lane & 15;
        int c0 = 32 * s2 + 8 * hi + 2 * jj;
        float v0 = (lo < 8) ? w2b[c0 * 8 + lo] : 0.f;
        float v1 = (lo < 8) ? w2b[(c0 + 1) * 8 + lo] : 0.f;
        pfu[u] = pk2(v0, v1);
    } else if (u < 7168) {
        int u2 = u - 5120;
        int fs = u2 >> 8, rem = u2 & 255, lane = rem >> 2, jj = rem & 3;
        int hi = lane >> 4, lo = lane & 15;
        int f = fs >> 1, s = fs & 1;
        int k0 = 32 * s + hi * 8 + 2 * jj;
        int c = 16 * f + lo;
        float v0 = (k0 < 16) ? w_dist[k0 * 64 + c] : (k0 < 31) ? w_dir[(k0 - 16) * 64 + c]
                 : (k0 < 43) ? w_rot[(k0 - 31) * 64 + c] : 0.f;
        int k1 = k0 + 1;
        float v1 = (k1 < 16) ? w_dist[k1 * 64 + c] : (k1 < 31) ? w_dir[(k1 - 16) * 64 + c]
                 : (k1 < 43) ? w_rot[(k1 - 31) * 64 + c] : 0.f;
        pfu[u] = pk2(v0, v1);
    }
}

// ---------------- fmt_wt: all GEMM weights -> bf16 transposed Wt[n][k] ----------------
__global__ __launch_bounds__(256) void fmt_wt_kernel(
    const float* __restrict__ w0, const float* __restrict__ w1,
    const float* __restrict__ w2, const float* __restrict__ w3,
    const float* __restrict__ w4, const float* __restrict__ w5,
    const float* __restrict__ w6, const float* __restrict__ w7,
    const float* __restrict__ w8, const float* __restrict__ w9,
    const float* __restrict__ w10, ushort* __restrict__ wt) {
    __shared__ ushort tile[32][33];
    int z = blockIdx.z;
    const float* W; int K, N; size_t off;
    switch (z) {
        case 0:  W = w0;  K = 256; N = 512; off = 0;       break;
        case 1:  W = w1;  K = 256; N = 512; off = 131072;  break;
        case 2:  W = w2;  K = 256; N = 512; off = 262144;  break;
        case 3:  W = w3;  K = 256; N = 512; off = 393216;  break;
        case 4:  W = w4;  K = 256; N = 256; off = 524288;  break;
        case 5:  W = w5;  K = 256; N = 256; off = 589824;  break;
        case 6:  W = w6;  K = 256; N = 256; off = 655360;  break;
        case 7:  W = w7;  K = 608; N = 512; off = 720896;  break;
        case 8:  W = w8;  K = 512; N = 256; off = 1032192; break;
        case 9:  W = w9;  K = 256; N = 256; off = 1163264; break;
        default: W = w10; K = 512; N = 256; off = 1228800; break;
    }
    int bk = blockIdx.y * 32, bn = blockIdx.x * 32;
    if (bk >= K || bn >= N) return;
    int tx = threadIdx.x & 31, ty = threadIdx.x >> 5;
    #pragma unroll
    for (int i = 0; i < 32; i += 8)
        tile[ty + i][tx] = f2bf(W[(size_t)(bk + ty + i) * N + bn + tx]);
    __syncthreads();
    #pragma unroll
    for (int i = 0; i < 32; i += 8)
        wt[off + (size_t)(bn + ty + i) * K + bk + tx] = tile[tx][ty + i];
}

// ---------------- convert fp32 -> bf16 (x4) ----------------
__global__ __launch_bounds__(256) void convb_kernel(const float* __restrict__ src,
                                                    ushort* __restrict__ dst) {
    size_t i4 = ((size_t)blockIdx.x * 256 + threadIdx.x) * 4;
    float4 v = *(const float4*)&src[i4];
    *(uint2*)&dst[i4] = make_uint2(pk2(v.x, v.y), pk2(v.z, v.w));
}

// ---------------- pair stage0 ----------------
__global__ __launch_bounds__(256) void pair_pre_kernel(
    ushort* feat, const int* __restrict__ relidx,
    const float* __restrict__ w_relpos, const ushort* __restrict__ pf,
    const float* __restrict__ lng, const float* __restrict__ lnb) {
    int tid = threadIdx.x;
    int wid = tid >> 6, lane = tid & 63, hi = lane >> 4, lo = lane & 15;
    bf16x8 wf[8];
    #pragma unroll
    for (int fs = 0; fs < 8; fs++) wf[fs] = *(const bf16x8*)&pf[10240 + fs * 512 + lane * 8];
    float sg_r[4][4], sbt_r[4][4];
    #pragma unroll
    for (int f = 0; f < 4; f++)
        #pragma unroll
        for (int r = 0; r < 4; r++) {
            int c = 16 * f + 4 * hi + r;
            sg_r[f][r] = lng[c];
            sbt_r[f][r] = lnb[c];
        }
    const f32x4 zz = {0.f, 0.f, 0.f, 0.f};
    for (int t = blockIdx.x * 4 + wid; t < (NN * KK / 16); t += 16384) {
        int r0 = t << 4;
        bf16x8 bp0 = *(const bf16x8*)(feat + (size_t)(r0 + lo) * 64 + hi * 8);
        bf16x8 bp1 = *(const bf16x8*)(feat + (size_t)(r0 + lo) * 64 + 32 + hi * 8);
        f32x4 a0f[4];
        #pragma unroll
        for (int f = 0; f < 4; f++) {
            a0f[f] = __builtin_amdgcn_mfma_f32_16x16x32_bf16(wf[f * 2 + 0], bp0, zz, 0, 0, 0);
            a0f[f] = __builtin_amdgcn_mfma_f32_16x16x32_bf16(wf[f * 2 + 1], bp1, a0f[f], 0, 0, 0);
        }
        int ridx = relidx[r0 + lo];
        float val[4][4];
        float part = 0.f;
        #pragma unroll
        for (int f = 0; f < 4; f++)
            #pragma unroll
            for (int r = 0; r < 4; r++) {
                int c = 16 * f + 4 * hi + r;
                float rv = (ridx >= 0) ? w_relpos[ridx * 64 + c] : 0.f;
                float v = a0f[f][r] + rv;
                val[f][r] = v;
                part += v;
            }
        part += __shfl_xor(part, 16);
        part += __shfl_xor(part, 32);
        float mean = part * (1.f / 64.f);
        float v2 = 0.f;
        #pragma unroll
        for (int f = 0; f < 4; f++)
            #pragma unroll
            for (int r = 0; r < 4; r++) {
                float dv = val[f][r] - mean;
                val[f][r] = dv;
                v2 += dv * dv;
            }
        v2 += __shfl_xor(v2, 16);
        v2 += __shfl_xor(v2, 32);
        float rs = rsqrtf(v2 * (1.f / 64.f) + 1e-5f);
        #pragma unroll
        for (int f = 0; f < 4; f++) {
            float v0 = val[f][0] * rs * sg_r[f][0] + sbt_r[f][0];
            float v1 = val[f][1] * rs * sg_r[f][1] + sbt_r[f][1];
            float v2b = val[f][2] * rs * sg_r[f][2] + sbt_r[f][2];
            float v3 = val[f][3] * rs * sg_r[f][3] + sbt_r[f][3];
            *(uint2*)(feat + (size_t)(r0 + lo) * 64 + 16 * f + 4 * hi) =
                make_uint2(pk2(v0, v1), pk2(v2b, v3));
        }
    }
}

// ---------------- pair MLP ----------------
__global__ __launch_bounds__(256) void pair_mlp2_kernel(
    const ushort* __restrict__ pln, const ushort* __restrict__ pf,
    const float* __restrict__ b_p1, const float* __restrict__ b2b,
    float* __restrict__ bias) {
    __shared__ __align__(16) ushort hx[4 * 2048];
    int tid = threadIdx.x;
    int wid = tid >> 6, lane = tid & 63, hi = lane >> 4, lo = lane & 15;
    bf16x8 w1f[16];
    #pragma unroll
    for (int fs = 0; fs < 16; fs++) w1f[fs] = *(const bf16x8*)&pf[fs * 512 + lane * 8];
    bf16x8 w2f[4];
    #pragma unroll
    for (int s2 = 0; s2 < 4; s2++) w2f[s2] = *(const bf16x8*)&pf[8192 + s2 * 512 + lane * 8];
    float b2b_r[4];
    #pragma unroll
    for (int r = 0; r < 4; r++) b2b_r[r] = (hi < 2) ? b2b[4 * hi + r] : 0.f;
    float sb1_r[8][4];
    #pragma unroll
    for (int f = 0; f < 8; f++)
        #pragma unroll
        for (int r = 0; r < 4; r++) sb1_r[f][r] = b_p1[16 * f + 4 * hi + r];

    ushort* hxw = &hx[wid * 2048];
    const f32x4 zz = {0.f, 0.f, 0.f, 0.f};
    for (int t = blockIdx.x * 4 + wid; t < (NN * KK / 16); t += 16384) {
        int r0 = t << 4;
        bf16x8 bh0 = *(const bf16x8*)(pln + (size_t)(r0 + lo) * 64 + hi * 8);
        bf16x8 bh1 = *(const bf16x8*)(pln + (size_t)(r0 + lo) * 64 + 32 + hi * 8);
        #pragma unroll
        for (int f = 0; f < 8; f++) {
            f32x4 acch = __builtin_amdgcn_mfma_f32_16x16x32_bf16(w1f[f * 2 + 0], bh0, zz, 0, 0, 0);
            acch = __builtin_amdgcn_mfma_f32_16x16x32_bf16(w1f[f * 2 + 1], bh1, acch, 0, 0, 0);
            int c0 = 16 * f + 4 * hi;
            float v0 = gelu_f(acch[0] + sb1_r[f][0]);
            float v1 = gelu_f(acch[1] + sb1_r[f][1]);
            float v2b = gelu_f(acch[2] + sb1_r[f][2]);
            float v3 = gelu_f(acch[3] + sb1_r[f][3]);
            int idx = (lo * 128 + c0) ^ ((lo & 7) << 3);
            *(uint2*)&hxw[idx] = make_uint2(pk2(v0, v1), pk2(v2b, v3));
        }
        f32x4 acc = zz;
        #pragma unroll
        for (int s2 = 0; s2 < 4; s2++) {
            int idx = (lo * 128 + 32 * s2 + 8 * hi) ^ ((lo & 7) << 3);
            bf16x8 bh = *(const bf16x8*)&hxw[idx];
            acc = __builtin_amdgcn_mfma_f32_16x16x32_bf16(w2f[s2], bh, acc, 0, 0, 0);
        }
        if (hi < 2) {
            int n = r0 >> 5, kb = (r0 & 31) + lo;
            #pragma unroll
            for (int r = 0; r < 4; r++)
                bias[(size_t)n * 256 + (4 * hi + r) * 32 + kb] = acc[r] + b2b_r[r];
        }
    }
}

// ---------------- GEMM core T (BM=128, BN=128) ----------------
__device__ __forceinline__ void gemm_coreT(
    const ushort* __restrict__ A, const ushort* __restrict__ Wt,
    int K, int row0, int colW0, int tid,
    ushort* sA, ushort* sB, f32x4 acc[4][4]) {
    int wid = tid >> 6, lane = tid & 63, lo = lane & 15, hi = lane >> 4;
    int wr = wid >> 1, wc = wid & 1;
    int ar = tid >> 1, akh = (tid & 1) * 16;
    for (int kt = 0; kt < K; kt += 32) {
        const ushort* ap = &A[(size_t)(row0 + ar) * K + kt + akh];
        uint4 a01 = *(const uint4*)ap;
        uint4 a23 = *(const uint4*)(ap + 8);
        const ushort* bp = &Wt[(size_t)(colW0 + ar) * K + kt + akh];
        uint4 b01 = *(const uint4*)bp;
        uint4 b23 = *(const uint4*)(bp + 8);
        __syncthreads();
        *(uint4*)&sA[ar * 40 + akh] = a01;
        *(uint4*)&sA[ar * 40 + akh + 8] = a23;
        *(uint4*)&sB[ar * 40 + akh] = b01;
        *(uint4*)&sB[ar * 40 + akh + 8] = b23;
        __syncthreads();
        bf16x8 af[4], bfr[4];
        #pragma unroll
        for (int mi = 0; mi < 4; mi++) af[mi] = *(const bf16x8*)&sA[(wr * 64 + mi * 16 + lo) * 40 + hi * 8];
        #pragma unroll
        for (int ni = 0; ni < 4; ni++) bfr[ni] = *(const bf16x8*)&sB[(wc * 64 + ni * 16 + lo) * 40 + hi * 8];
        #pragma unroll
        for (int mi = 0; mi < 4; mi++)
            #pragma unroll
            for (int ni = 0; ni < 4; ni++)
                acc[mi][ni] = __builtin_amdgcn_mfma_f32_16x16x32_bf16(af[mi], bfr[ni], acc[mi][ni], 0, 0, 0);
    }
}

// ---------------- t1 GEMM ----------------
__global__ __launch_bounds__(256) void gemm_t1T(
    const ushort* __restrict__ A, const ushort* __restrict__ Wt, ushort* __restrict__ C,
    int K, int Nc) {
    __shared__ __align__(16) ushort sA[128 * 40];
    __shared__ __align__(16) ushort sB[128 * 40];
    int row0 = blockIdx.y * 128, col0 = blockIdx.x * 128;
    int tid = threadIdx.x;
    const f32x4 zz = {0.f, 0.f, 0.f, 0.f};
    f32x4 acc[4][4] = {{zz, zz, zz, zz}, {zz, zz, zz, zz}, {zz, zz, zz, zz}, {zz, zz, zz, zz}};
    gemm_coreT(A, Wt, K, row0, col0, tid, sA, sB, acc);
    int wid = tid >> 6, lane = tid & 63, lo = lane & 15, hi = lane >> 4;
    int wr = wid >> 1, wc = wid & 1;
    #pragma unroll
    for (int ni = 0; ni < 4; ni++) {
        int col = col0 + wc * 64 + ni * 16 + lo;
        #pragma unroll
        for (int mi = 0; mi < 4; mi++) {
            #pragma unroll
            for (int r = 0; r < 4; r++) {
                int row = row0 + wr * 64 + mi * 16 + hi * 4 + r;
                C[(size_t)row * Nc + col] = f2bf(gelu_f(acc[mi][ni][r]));
            }
        }
    }
}

// ---------------- small-tile GEMM (BM=64, BN=64): 2 blocks/CU ----------------
__global__ __launch_bounds__(256) void gemm_n64s(
    const ushort* __restrict__ A, const ushort* __restrict__ Wt, float* __restrict__ C,
    int K, int Nc, const float* __restrict__ bias, const float* __restrict__ addp) {
    __shared__ __align__(16) ushort sA[64 * 40];
    __shared__ __align__(16) ushort sB[64 * 40];
    int row0 = blockIdx.y * 64, col0 = blockIdx.x * 64;
    int tid = threadIdx.x;
    int wid = tid >> 6, lane = tid & 63, lo = lane & 15, hi = lane >> 4;
    int wr = wid >> 1, wc = wid & 1;              // 2x2 waves, each 32x32
    int ar = tid >> 2, akh = (tid & 3) * 8;
    const f32x4 zz = {0.f, 0.f, 0.f, 0.f};
    f32x4 acc[2][2] = {{zz, zz}, {zz, zz}};
    for (int kt = 0; kt < K; kt += 32) {
        uint4 a0 = *(const uint4*)&A[(size_t)(row0 + ar) * K + kt + akh];
        uint4 b0 = *(const uint4*)&Wt[(size_t)(col0 + ar) * K + kt + akh];
        __syncthreads();
        *(uint4*)&sA[ar * 40 + akh] = a0;
        *(uint4*)&sB[ar * 40 + akh] = b0;
        __syncthreads();
        bf16x8 af[2], bfr[2];
        #pragma unroll
        for (int mi = 0; mi < 2; mi++) af[mi] = *(const bf16x8*)&sA[(wr * 32 + mi * 16 + lo) * 40 + hi * 8];
        #pragma unroll
        for (int ni = 0; ni < 2; ni++) bfr[ni] = *(const bf16x8*)&sB[(wc * 32 + ni * 16 + lo) * 40 + hi * 8];
        #pragma unroll
        for (int mi = 0; mi < 2; mi++)
            #pragma unroll
            for (int ni = 0; ni < 2; ni++)
                acc[mi][ni] = __builtin_amdgcn_mfma_f32_16x16x32_bf16(af[mi], bfr[ni], acc[mi][ni], 0, 0, 0);
    }
    #pragma unroll
    for (int ni = 0; ni < 2; ni++) {
        int col = col0 + wc * 32 + ni * 16 + lo;
        float bc = bias ? bias[col] : 0.f;
        #pragma unroll
        for (int mi = 0; mi < 2; mi++) {
            #pragma unroll
            for (int r = 0; r < 4; r++) {
                int row = row0 + wr * 32 + mi * 16 + hi * 4 + r;
                float v = acc[mi][ni][r] + bc;
                if (addp) v += addp[(size_t)row * Nc + col];
                C[(size_t)row * Nc + col] = v;
            }
        }
    }
}

// ---------------- fused QKV GEMM T ----------------
__global__ __launch_bounds__(256) void gemm_qkvT(
    const ushort* __restrict__ A, const ushort* __restrict__ Wt3,
    float* __restrict__ qb, ushort* __restrict__ kb, ushort* __restrict__ vb) {
    __shared__ __align__(16) ushort sA[128 * 40];
    __shared__ __align__(16) ushort sB[128 * 40];
    int row0 = blockIdx.y * 128, col0 = blockIdx.x * 128;
    int wsel = col0 >> 8, colW = col0 & 255;
    int tid = threadIdx.x;
    const f32x4 zz = {0.f, 0.f, 0.f, 0.f};
    f32x4 acc[4][4] = {{zz, zz, zz, zz}, {zz, zz, zz, zz}, {zz, zz, zz, zz}, {zz, zz, zz, zz}};
    gemm_coreT(A, Wt3, 256, row0, col0, tid, sA, sB, acc);
    int wid = tid >> 6, lane = tid & 63, lo = lane & 15, hi = lane >> 4;
    int wr = wid >> 1, wc = wid & 1;
    #pragma unroll
    for (int ni = 0; ni < 4; ni++) {
        int colo = colW + wc * 64 + ni * 16 + lo;
        #pragma unroll
        for (int mi = 0; mi < 4; mi++) {
            #pragma unroll
            for (int r = 0; r < 4; r++) {
                int row = row0 + wr * 64 + mi * 16 + hi * 4 + r;
                float v = acc[mi][ni][r];
                if (wsel == 0) qb[(size_t)row * 256 + colo] = v;
                else if (wsel == 1) kb[(size_t)row * 256 + colo] = f2bf(v);
                else vb[(size_t)row * 256 + colo] = f2bf(v);
            }
        }
    }
}

// ---------------- fused FFN GEMM T ----------------
__global__ __launch_bounds__(256) void gemm_ffnT(
    const ushort* __restrict__ A, const ushort* __restrict__ Wt4,
    ushort* __restrict__ o0, ushort* __restrict__ o1,
    ushort* __restrict__ o2, ushort* __restrict__ o3) {
    __shared__ __align__(16) ushort sA[128 * 40];
    __shared__ __align__(16) ushort sB[128 * 40];
    int row0 = blockIdx.y * 128, col0 = blockIdx.x * 128;
    int wsel = col0 >> 9, colW = col0 & 511;
    ushort* O = (wsel == 0) ? o0 : (wsel == 1) ? o1 : (wsel == 2) ? o2 : o3;
    int tid = threadIdx.x;
    const f32x4 zz = {0.f, 0.f, 0.f, 0.f};
    f32x4 acc[4][4] = {{zz, zz, zz, zz}, {zz, zz, zz, zz}, {zz, zz, zz, zz}, {zz, zz, zz, zz}};
    gemm_coreT(A, Wt4, 256, row0, col0, tid, sA, sB, acc);
    int wid = tid >> 6, lane = tid & 63, lo = lane & 15, hi = lane >> 4;
    int wr = wid >> 1, wc = wid & 1;
    #pragma unroll
    for (int ni = 0; ni < 4; ni++) {
        int colo = colW + wc * 64 + ni * 16 + lo;
        #pragma unroll
        for (int mi = 0; mi < 4; mi++) {
            #pragma unroll
            for (int r = 0; r < 4; r++) {
                int row = row0 + wr * 64 + mi * 16 + hi * 4 + r;
                float v = acc[mi][ni][r];
                if (wsel > 0) v = gelu_f(v);
                O[(size_t)row * 512 + colo] = f2bf(v);
            }
        }
    }
}

// ---------------- attention ----------------
__global__ __launch_bounds__(256) void attn_kernel(
    const float* __restrict__ q, const ushort* __restrict__ kp, const ushort* __restrict__ vp,
    const float* __restrict__ bias, const int* __restrict__ nbr, ushort* __restrict__ o) {
    int n = blockIdx.x;
    __shared__ float qs[256];
    __shared__ int js[32];
    __shared__ float ls[256];
    __shared__ __align__(16) uint4 vs[32 * 33];
    int t = threadIdx.x;
    qs[t] = q[(size_t)n * 256 + t];
    if (t < 32) js[t] = nbr[n * 32 + t];
    __syncthreads();
    int vrow = t >> 3, vseg = t & 7;
    const uint4* vsrc = (const uint4*)(vp + (size_t)js[vrow] * 256);
    uint4 vr0 = vsrc[vseg * 4 + 0];
    uint4 vr1 = vsrc[vseg * 4 + 1];
    uint4 vr2 = vsrc[vseg * 4 + 2];
    uint4 vr3 = vsrc[vseg * 4 + 3];
    int h = t >> 5, k = t & 31;
    int j = js[k];
    const bf16x8* kr = (const bf16x8*)(kp + (size_t)j * 256 + h * 32);
    bf16x8 kv0 = kr[0], kv1 = kr[1], kv2 = kr[2], kv3 = kr[3];
    const float* qh = qs + h * 32;
    float dot = 0.f;
    #pragma unroll
    for (int i = 0; i < 8; i++) dot += qh[i] * bf2f((ushort)kv0[i]);
    #pragma unroll
    for (int i = 0; i < 8; i++) dot += qh[8 + i] * bf2f((ushort)kv1[i]);
    #pragma unroll
    for (int i = 0; i < 8; i++) dot += qh[16 + i] * bf2f((ushort)kv2[i]);
    #pragma unroll
    for (int i = 0; i < 8; i++) dot += qh[24 + i] * bf2f((ushort)kv3[i]);
    float l = dot * 0.17677669529663687f + bias[(size_t)n * 256 + t];
    float mx = l;
    #pragma unroll
    for (int m = 16; m > 0; m >>= 1) mx = fmaxf(mx, __shfl_xor(mx, m));
    float e = __expf(l - mx);
    float sum = e;
    #pragma unroll
    for (int m = 16; m > 0; m >>= 1) sum += __shfl_xor(sum, m);
    ls[t] = e / sum;
    vs[vrow * 33 + vseg * 4 + 0] = vr0;
    vs[vrow * 33 + vseg * 4 + 1] = vr1;
    vs[vrow * 33 + vseg * 4 + 2] = vr2;
    vs[vrow * 33 + vseg * 4 + 3] = vr3;
    __syncthreads();
    const ushort* vsu = (const ushort*)vs;
    const float* lh = ls + h * 32;
    float acc = 0.f;
    #pragma unroll
    for (int kk = 0; kk < 32; kk++)
        acc += lh[kk] * bf2f(vsu[kk * 264 + h * 32 + k]);
    o[(size_t)n * 256 + t] = f2bf(acc);
}

// ---------------- LN(a+b): x fp32 + x bf16 + sum fp32 ----------------
__global__ __launch_bounds__(256) void ln_add_kernel(
    const float* __restrict__ a, const float* __restrict__ b,
    const float* __restrict__ g, const float* __restrict__ be,
    float* __restrict__ xout, ushort* __restrict__ xbout, float* __restrict__ sout) {
    int row = blockIdx.x * 4 + (threadIdx.x >> 6);
    int lane = threadIdx.x & 63;
    size_t base = (size_t)row * 256 + lane * 4;
    float4 av = *(const float4*)(a + base);
    float4 bv = *(const float4*)(b + base);
    float s0 = av.x + bv.x, s1 = av.y + bv.y, s2 = av.z + bv.z, s3 = av.w + bv.w;
    float sum = wave_sum64(s0 + s1 + s2 + s3);
    float mean = sum * (1.f / 256.f);
    float d0 = s0 - mean, d1 = s1 - mean, d2 = s2 - mean, d3 = s3 - mean;
    float v = wave_sum64(d0 * d0 + d1 * d1 + d2 * d2 + d3 * d3);
    float rs = rsqrtf(v * (1.f / 256.f) + 1e-5f);
    float4 gv = *(const float4*)(g + lane * 4);
    float4 bev = *(const float4*)(be + lane * 4);
    float4 xo;
    xo.x = d0 * rs * gv.x + bev.x;
    xo.y = d1 * rs * gv.y + bev.y;
    xo.z = d2 * rs * gv.z + bev.z;
    xo.w = d3 * rs * gv.w + bev.w;
    *(float4*)(xout + base) = xo;
    *(uint2*)(xbout + base) = make_uint2(pk2(xo.x, xo.y), pk2(xo.z, xo.w));
    float4 so; so.x = s0; so.y = s1; so.z = s2; so.w = s3;
    *(float4*)(sout + base) = so;
}

// ---------------- segment means ----------------
__global__ __launch_bounds__(256) void seg_partial_kernel(
    const ushort* __restrict__ up, const int* __restrict__ batch, const int* __restrict__ chain,
    float* __restrict__ mb_acc, float* __restrict__ mc_acc) {
    int r0 = blockIdx.x * 32;
    int t = threadIdx.x;
    float ab0 = 0.f, ab1 = 0.f, ac0 = 0.f, ac1 = 0.f;
    int curb = batch[r0], curc = chain[r0];
    for (int r = r0; r < r0 + 32; r++) {
        int b = batch[r], c = chain[r];
        if (b != curb) {
            atomicAdd(&mb_acc[curb * 512 + t], ab0);
            atomicAdd(&mb_acc[curb * 512 + 256 + t], ab1);
            ab0 = ab1 = 0.f; curb = b;
        }
        if (c != curc) {
            atomicAdd(&mc_acc[curc * 512 + t], ac0);
            atomicAdd(&mc_acc[curc * 512 + 256 + t], ac1);
            ac0 = ac1 = 0.f; curc = c;
        }
        float v0 = bf2f(up[(size_t)r * 512 + t]);
        float v1 = bf2f(up[(size_t)r * 512 + 256 + t]);
        ab0 += v0; ab1 += v1; ac0 += v0; ac1 += v1;
    }
    atomicAdd(&mb_acc[curb * 512 + t], ab0);
    atomicAdd(&mb_acc[curb * 512 + 256 + t], ab1);
    atomicAdd(&mc_acc[curc * 512 + t], ac0);
    atomicAdd(&mc_acc[curc * 512 + 256 + t], ac1);
}

__device__ __forceinline__ int lower_bound_i(const int* a, int n, int v) {
    int lo = 0, hi = n;
    while (lo < hi) { int mid = (lo + hi) >> 1; if (a[mid] < v) lo = mid + 1; else hi = mid; }
    return lo;
}

__global__ __launch_bounds__(256) void seg_final_kernel(
    float* __restrict__ mb, float* __restrict__ mc,
    const int* __restrict__ batch, const int* __restrict__ chain) {
    int idx = blockIdx.x * 256 + threadIdx.x;
    if (idx < NBATCH * 512) {
        int seg = idx >> 9;
        int lo = lower_bound_i(batch, NN, seg);
        int hi = lower_bound_i(batch, NN, seg + 1);
        mb[idx] *= 1.f / fmaxf((float)(hi - lo), 1.f);
    } else {
        int i2 = idx - NBATCH * 512;
        int seg = i2 >> 9;
        int lo = lower_bound_i(chain, NN, seg);
        int hi = lower_bound_i(chain, NN, seg + 1);
        mc[i2] *= 1.f / fmaxf((float)(hi - lo), 1.f);
    }
}

// ---------------- hidden combine ----------------
__global__ __launch_bounds__(256) void hidden_kernel(
    const ushort* __restrict__ up, const ushort* __restrict__ cg, const ushort* __restrict__ bg,
    ushort* __restrict__ lg, const float* __restrict__ mb, const float* __restrict__ mc,
    const int* __restrict__ batch, const int* __restrict__ chain) {
    size_t e4 = ((size_t)blockIdx.x * 256 + threadIdx.x) * 4;
    int n = (int)(e4 >> 9), d = (int)(e4 & 511);
    float4 mbv = *(const float4*)&mb[batch[n] * 512 + d];
    float4 mcv = *(const float4*)&mc[chain[n] * 512 + d];
    uint2 u_up = *(const uint2*)&up[e4];
    uint2 u_cg = *(const uint2*)&cg[e4];
    uint2 u_bg = *(const uint2*)&bg[e4];
    uint2 u_lg = *(const uint2*)&lg[e4];
    float h0 = bf2f((ushort)u_bg.x) * mbv.x + bf2f((ushort)u_cg.x) * mcv.x
             + bf2f((ushort)u_lg.x) * bf2f((ushort)u_up.x);
    float h1 = bf2f((ushort)(u_bg.x >> 16)) * mbv.y + bf2f((ushort)(u_cg.x >> 16)) * mcv.y
             + bf2f((ushort)(u_lg.x >> 16)) * bf2f((ushort)(u_up.x >> 16));
    float h2 = bf2f((ushort)u_bg.y) * mbv.z + bf2f((ushort)u_cg.y) * mcv.z
             + bf2f((ushort)u_lg.y) * bf2f((ushort)u_up.y);
    float h3 = bf2f((ushort)(u_bg.y >> 16)) * mbv.w + bf2f((ushort)(u_cg.y >> 16)) * mcv.w
             + bf2f((ushort)(u_lg.y >> 16)) * bf2f((ushort)(u_up.y >> 16));
    *(uint2*)&lg[e4] = make_uint2(pk2(h0, h1), pk2(h2, h3));
}

// ---------------- final ----------------
__global__ __launch_bounds__(256) void final_kernel(
    const float* __restrict__ x1, const float* __restrict__ y2, const float* __restrict__ inc1,
    const float* __restrict__ ug, const float* __restrict__ ub,
    const float* __restrict__ fg, const float* __restrict__ fb, float* __restrict__ out) {
    int row = blockIdx.x * 4 + (threadIdx.x >> 6);
    int lane = threadIdx.x & 63;
    size_t base = (size_t)row * 256 + lane * 4;
    float4 xv = *(const float4*)(x1 + base);
    float4 yv = *(const float4*)(y2 + base);
    float4 iv = *(const float4*)(inc1 + base);
    float s0 = xv.x + yv.x, s1 = xv.y + yv.y, s2 = xv.z + yv.z, s3 = xv.w + yv.w;
    float t0 = iv.x + yv.x, t1 = iv.y + yv.y, t2 = iv.z + yv.z, t3 = iv.w + yv.w;
    float sums = wave_sum64(s0 + s1 + s2 + s3);
    float means = sums * (1.f / 256.f);
    float sd0 = s0 - means, sd1 = s1 - means, sd2 = s2 - means, sd3 = s3 - means;
    float vs = wave_sum64(sd0 * sd0 + sd1 * sd1 + sd2 * sd2 + sd3 * sd3);
    float rss = rsqrtf(vs * (1.f / 256.f) + 1e-5f);
    float sumt = wave_sum64(t0 + t1 + t2 + t3);
    float meant = sumt * (1.f / 256.f);
    float td0 = t0 - meant, td1 = t1 - meant, td2 = t2 - meant, td3 = t3 - meant;
    float vt = wave_sum64(td0 * td0 + td1 * td1 + td2 * td2 + td3 * td3);
    float rst = rsqrtf(vt * (1.f / 256.f) + 1e-5f);
    float4 ugv = *(const float4*)(ug + lane * 4);
    float4 ubv = *(const float4*)(ub + lane * 4);
    float4 fgv = *(const float4*)(fg + lane * 4);
    float4 fbv = *(const float4*)(fb + lane * 4);
    float4 ov;
    ov.x = (sd0 * rss * ugv.x + ubv.x) + (td0 * rst * fgv.x + fbv.x);
    ov.y = (sd1 * rss * ugv.y + ubv.y) + (td1 * rst * fgv.y + fbv.y);
    ov.z = (sd2 * rss * ugv.z + ubv.z) + (td2 * rst * fgv.z + fbv.z);
    ov.w = (sd3 * rss * ugv.w + ubv.w) + (td3 * rst * fgv.w + fbv.w);
    *(float4*)(out + base) = ov;
}

// ---------------- launch ----------------
extern "C" void kernel_launch(void* const* d_in, const int* in_sizes, int n_in,
                              void* d_out, int out_size, void* d_ws, size_t ws_size,
                              hipStream_t stream) {
    const float* local    = (const float*)d_in[0];
    const float* pos      = (const float*)d_in[1];
    const int*   nbr      = (const int*)d_in[2];
    const int*   resi     = (const int*)d_in[3];
    const int*   chain    = (const int*)d_in[4];
    const int*   batch    = (const int*)d_in[5];
    const float* w_relpos = (const float*)d_in[7];
    const float* w_dist   = (const float*)d_in[8];
    const float* w_dir    = (const float*)d_in[9];
    const float* w_rot    = (const float*)d_in[10];
    const float* ln_pair_g = (const float*)d_in[11];
    const float* ln_pair_b = (const float*)d_in[12];
    const float* w_p1     = (const float*)d_in[13];
    const float* b_p1     = (const float*)d_in[14];
    const float* w_p2     = (const float*)d_in[15];
    const float* b_p2     = (const float*)d_in[16];
    const float* wq       = (const float*)d_in[17];
    const float* wk       = (const float*)d_in[18];
    const float* wv       = (const float*)d_in[19];
    const float* wb       = (const float*)d_in[20];
    const float* wo       = (const float*)d_in[21];
    const float* ln_a_g   = (const float*)d_in[22];
    const float* ln_a_b   = (const float*)d_in[23];
    const float* w_t1     = (const float*)d_in[24];
    const float* w_t2     = (const float*)d_in[25];
    const float* w_up     = (const float*)d_in[26];
    const float* w_lg     = (const float*)d_in[27];
    const float* w_cg     = (const float*)d_in[28];
    const float* w_bg     = (const float*)d_in[29];
    const float* w_out    = (const float*)d_in[30];
    const float* b_out    = (const float*)d_in[31];
    const float* ln_u_g   = (const float*)d_in[32];
    const float* ln_u_b   = (const float*)d_in[33];
    const float* ln_f_g   = (const float*)d_in[34];
    const float* ln_f_b   = (const float*)d_in[35];

    float* ws = (float*)d_ws;
    float* R         = ws + 0;             // 73728
    float* biasb     = ws + 73728;         // -> 2170880
    float* tfeat_out = ws + 2170880;       // -> 4268032
    float* x1        = ws + 4268032;       // -> 6365184
    float* inc1      = ws + 6365184;       // -> 8462336
    ushort* featb    = (ushort*)(ws + 8462336);  // -> 16850944
    int* relidx      = (int*)(ws + 16850944);    // -> 17113088
    ushort* tfb      = (ushort*)(ws + 17113088); // -> 19603456
    ushort* wt       = (ushort*)(ws + 19603456); // -> 20283392
    ushort* x1b      = (ushort*)(ws + 20283392); // -> 21331968
    ushort* localb   = (ushort*)(ws + 21331968); // -> 22380544
    ushort* tmp512u  = (ushort*)(ws + 22380544); // -> 24477696
    float* y2        = ws + 22380544;      // over tmp512u after t2 consumed
    float* yb        = ws + 17113088;      // over tfb after t1 consumed
    float* qb        = ws + 8462336;       // phase 2 over featb
    ushort* kbu      = (ushort*)(ws + 10559488);
    ushort* vbu      = (ushort*)(ws + 11608064);
    ushort* obu      = (ushort*)(ws + 12656640);
    ushort* upbu     = (ushort*)(ws + 8462336);  // phase 3
    ushort* lgbu     = (ushort*)(ws + 10559488);
    ushort* cgbu     = (ushort*)(ws + 12656640);
    ushort* bgbu     = (ushort*)(ws + 14753792);
    float* mb        = ws + 24477696;
    float* mc        = ws + 24494080;
    ushort* pfmt     = (ushort*)(ws + 24526848);
    float* w2b       = ws + 24534016;
    float* b2b       = ws + 24535040;

    frames_kernel<<<NN / 256, 256, 0, stream>>>(pos, R);
    w2b_kernel<<<4, 256, 0, stream>>>(w_p2, b_p2, wb, w2b, b2b);
    fmt_kernel<<<28, 256, 0, stream>>>(w_p1, w_dist, w_dir, w_rot, w2b, pfmt);
    fmt_wt_kernel<<<dim3(16, 19, 11), 256, 0, stream>>>(w_up, w_lg, w_cg, w_bg, wq, wk, wv,
                                                        w_t1, w_t2, wo, w_out, wt);
    convb_kernel<<<NN * 256 / 1024, 256, 0, stream>>>(local, localb);
    pair_raw_kernel<<<NN * KK / 256, 256, 0, stream>>>(pos, nbr, resi, chain, R,
                                                       featb, relidx, tfb);
    pair_pre_kernel<<<4096, 256, 0, stream>>>(featb, relidx, w_relpos, pfmt,
                                              ln_pair_g, ln_pair_b);
    pair_mlp2_kernel<<<4096, 256, 0, stream>>>(featb, pfmt, b_p1, b2b, biasb);
    // tfeat MLP
    gemm_t1T<<<dim3(4, 64), 256, 0, stream>>>(tfb, wt + 720896, tmp512u, 608, 512);
    gemm_n64s<<<dim3(4, 128), 256, 0, stream>>>(tmp512u, wt + 1032192, tfeat_out, 512, 256,
                                                nullptr, nullptr);
    // qkv
    gemm_qkvT<<<dim3(6, 64), 256, 0, stream>>>(localb, wt + 524288, qb, kbu, vbu);
    attn_kernel<<<NN, 256, 0, stream>>>(qb, kbu, vbu, biasb, nbr, obu);
    gemm_n64s<<<dim3(4, 128), 256, 0, stream>>>(obu, wt + 1163264, yb, 256, 256,
                                                nullptr, nullptr);
    ln_add_kernel<<<NN / 4, 256, 0, stream>>>(local, yb, ln_a_g, ln_a_b, x1, x1b, inc1);
    // FFN
    gemm_ffnT<<<dim3(16, 64), 256, 0, stream>>>(x1b, wt, upbu, lgbu, cgbu, bgbu);
    (void)hipMemsetAsync(mb, 0, (NBATCH + NCHAIN) * 512 * sizeof(float), stream);
    seg_partial_kernel<<<NN / 32, 256, 0, stream>>>(upbu, batch, chain, mb, mc);
    seg_final_kernel<<<(NBATCH + NCHAIN) * 512 / 256, 256, 0, stream>>>(mb, mc, batch, chain);
    hidden_kernel<<<NN * 512 / 1024, 256, 0, stream>>>(upbu, cgbu, bgbu, lgbu, mb, mc, batch, chain);
    gemm_n64s<<<dim3(4, 128), 256, 0, stream>>>(lgbu, wt + 1228800, y2, 512, 256,
                                                b_out, tfeat_out);
    final_kernel<<<NN / 4, 256, 0, stream>>>(x1, y2, inc1, ln_u_g, ln_u_b, ln_f_g, ln_f_b, (float*)d_out);
}